// Round 2
// baseline (523.582 us; speedup 1.0000x reference)
//
#include <hip/hip_runtime.h>
#include <math.h>

#define DEVI __device__ __forceinline__

typedef unsigned int u32;
typedef unsigned short u16;
typedef __attribute__((ext_vector_type(8))) __bf16 bf16x8;
typedef __attribute__((ext_vector_type(8))) u16 u16x8;
typedef __attribute__((ext_vector_type(4))) float f32x4;

DEVI float silu_f(float x) { return x * (1.0f / (1.0f + __expf(-x))); }
DEVI float softplus_f(float x) {
  return x > 0.0f ? x + log1pf(__expf(-x)) : log1pf(__expf(x));
}

DEVI u32 bf16_rne(float f) {
  u32 u = __float_as_uint(f);
  return (u + 0x7fffu + ((u >> 16) & 1u)) >> 16;
}
// packed split: high 16 bits = bf16(f), low 16 bits = bf16(f - hi)
DEVI u32 pack_hl(float f) {
  u32 h = bf16_rne(f);
  float hf = __uint_as_float(h << 16);
  u32 l = bf16_rne(f - hf);
  return (h << 16) | l;
}

DEVI void load16(float* r, const float* __restrict__ p) {
  const float4* q = (const float4*)p;
  float4 a = q[0], b = q[1], c = q[2], d = q[3];
  r[0]=a.x; r[1]=a.y; r[2]=a.z; r[3]=a.w;
  r[4]=b.x; r[5]=b.y; r[6]=b.z; r[7]=b.w;
  r[8]=c.x; r[9]=c.y; r[10]=c.z; r[11]=c.w;
  r[12]=d.x; r[13]=d.y; r[14]=d.z; r[15]=d.w;
}
DEVI void store16(float* __restrict__ p, const float* r) {
  float4* q = (float4*)p;
  q[0] = make_float4(r[0],r[1],r[2],r[3]);
  q[1] = make_float4(r[4],r[5],r[6],r[7]);
  q[2] = make_float4(r[8],r[9],r[10],r[11]);
  q[3] = make_float4(r[12],r[13],r[14],r[15]);
}

// split 8 packed u32 into hi/lo bf16 chunks and store 16B each to LDS
DEVI void stage_chunk(u16* __restrict__ ph, u16* __restrict__ pl, uint4 a, uint4 b) {
  u16x8 h, l;
  h[0] = (u16)(a.x >> 16); l[0] = (u16)a.x;
  h[1] = (u16)(a.y >> 16); l[1] = (u16)a.y;
  h[2] = (u16)(a.z >> 16); l[2] = (u16)a.z;
  h[3] = (u16)(a.w >> 16); l[3] = (u16)a.w;
  h[4] = (u16)(b.x >> 16); l[4] = (u16)b.x;
  h[5] = (u16)(b.y >> 16); l[5] = (u16)b.y;
  h[6] = (u16)(b.z >> 16); l[6] = (u16)b.z;
  h[7] = (u16)(b.w >> 16); l[7] = (u16)b.w;
  *(u16x8*)ph = h; *(u16x8*)pl = l;
}

// ---------------------------------------------------------------------------
// Weight prep: convert 5 fp32 weight matrices to packed hi/lo bf16 (u32).
// ---------------------------------------------------------------------------
constexpr int WN1 = 32768, WNO1 = 16384, WNL = 32768, WN2 = 131072, WNO2 = 65536;
constexpr int WOFF1 = 0, WOFFO1 = 32768, WOFFL = 49152, WOFF2 = 81920, WOFFO2 = 212992;
constexpr int WTOT = 278528;

__global__ __launch_bounds__(256) void wprep_kernel(
    const float* __restrict__ w1, const float* __restrict__ wo1,
    const float* __restrict__ wl, const float* __restrict__ w2,
    const float* __restrict__ wo2, u32* __restrict__ dst)
{
  int i = blockIdx.x * 256 + threadIdx.x;
  float v;
  if (i < WOFFO1)       v = w1[i];
  else if (i < WOFFL)   v = wo1[i - WOFFO1];
  else if (i < WOFF2)   v = wl[i - WOFFL];
  else if (i < WOFFO2)  v = w2[i - WOFF2];
  else                  v = wo2[i - WOFFO2];
  dst[i] = pack_hl(v);
}

// ---------------------------------------------------------------------------
// Transpose: fp32 (b, C, L) -> packed u32 (b*L, C)
// ---------------------------------------------------------------------------
__global__ __launch_bounds__(256) void tpose_kernel(
    const float* __restrict__ in, u32* __restrict__ out, int C, int L)
{
  __shared__ float t[32][33];
  const int l0 = blockIdx.x * 32, c0 = blockIdx.y * 32, b = blockIdx.z;
  const int tx = threadIdx.x & 31, ty = threadIdx.x >> 5;
  const float* src = in + ((long)b * C + c0) * L + l0;
  #pragma unroll
  for (int r = 0; r < 32; r += 8) t[ty + r][tx] = src[(long)(ty + r) * L + tx];
  __syncthreads();
  u32* dst = out + ((long)b * L + l0) * C + c0;
  #pragma unroll
  for (int r = 0; r < 32; r += 8) dst[(long)(ty + r) * C + tx] = pack_hl(t[tx][ty + r]);
}

// ---------------------------------------------------------------------------
// MFMA GEMM (bf16x3 split): C[m,n] = sum_k A[m,k]*W[n,k] (+bias)
// ---------------------------------------------------------------------------
template<int EPI>
__global__ __launch_bounds__(256) void mgemm_kernel(
    const u32* __restrict__ Ap, const u32* __restrict__ Wp,
    const float* __restrict__ bias, int M, int N, int K,
    float* __restrict__ out0, float* __restrict__ out1,
    u32* __restrict__ outp, int di, int L)
{
  __shared__ u16 Ah[128][40], Al[128][40], Bh[128][40], Bl[128][40];
  const int tid = threadIdx.x;
  const int wid = tid >> 6, lane = tid & 63;
  const int lm = lane & 15, lq = lane >> 4;
  const int m0 = blockIdx.y * 128, n0 = blockIdx.x * 128;
  const int wr = (wid >> 1) * 64, wn = (wid & 1) * 64;
  const int sr = tid >> 1;
  const int sc = (tid & 1) * 2;
  const int o0 = (((sc + 0) ^ (sr & 3)) * 8);
  const int o1 = (((sc + 1) ^ (sr & 3)) * 8);

  f32x4 acc[4][4];
  #pragma unroll
  for (int i = 0; i < 4; ++i)
    #pragma unroll
    for (int j = 0; j < 4; ++j)
      #pragma unroll
      for (int r = 0; r < 4; ++r) acc[i][j][r] = 0.0f;

  const u32* ga = Ap + (long)(m0 + sr) * K + sc * 8;
  const u32* gb = Wp + (long)(n0 + sr) * K + sc * 8;
  const int co = (lq ^ (lm & 3)) * 8;

  for (int k0 = 0; k0 < K; k0 += 32) {
    uint4 a0 = *(const uint4*)(ga + k0);
    uint4 a1 = *(const uint4*)(ga + k0 + 4);
    uint4 a2 = *(const uint4*)(ga + k0 + 8);
    uint4 a3 = *(const uint4*)(ga + k0 + 12);
    uint4 b0 = *(const uint4*)(gb + k0);
    uint4 b1 = *(const uint4*)(gb + k0 + 4);
    uint4 b2 = *(const uint4*)(gb + k0 + 8);
    uint4 b3 = *(const uint4*)(gb + k0 + 12);
    stage_chunk(&Ah[sr][o0], &Al[sr][o0], a0, a1);
    stage_chunk(&Ah[sr][o1], &Al[sr][o1], a2, a3);
    stage_chunk(&Bh[sr][o0], &Bl[sr][o0], b0, b1);
    stage_chunk(&Bh[sr][o1], &Bl[sr][o1], b2, b3);
    __syncthreads();

    bf16x8 fah[4], fal[4];
    #pragma unroll
    for (int i = 0; i < 4; ++i) {
      fah[i] = *(const bf16x8*)&Ah[wr + 16 * i + lm][co];
      fal[i] = *(const bf16x8*)&Al[wr + 16 * i + lm][co];
    }
    #pragma unroll
    for (int j = 0; j < 4; ++j) {
      bf16x8 fbh = *(const bf16x8*)&Bh[wn + 16 * j + lm][co];
      bf16x8 fbl = *(const bf16x8*)&Bl[wn + 16 * j + lm][co];
      #pragma unroll
      for (int i = 0; i < 4; ++i) {
        acc[i][j] = __builtin_amdgcn_mfma_f32_16x16x32_bf16(fah[i], fbh, acc[i][j], 0, 0, 0);
        acc[i][j] = __builtin_amdgcn_mfma_f32_16x16x32_bf16(fah[i], fbl, acc[i][j], 0, 0, 0);
        acc[i][j] = __builtin_amdgcn_mfma_f32_16x16x32_bf16(fal[i], fbh, acc[i][j], 0, 0, 0);
      }
    }
    __syncthreads();
  }

  if constexpr (EPI == 0) {
    const int b = m0 >> 12;
    const int lb = (m0 & 4095) + wr;
    #pragma unroll
    for (int j = 0; j < 4; ++j) {
      const int n = n0 + wn + 16 * j + lm;
      const float bv = bias[n];
      float* base = (n < di) ? out0 + ((long)b * di + n) * L
                             : out1 + ((long)b * di + (n - di)) * L;
      #pragma unroll
      for (int i = 0; i < 4; ++i) {
        const int l = lb + 16 * i + lq * 4;
        *(float4*)(base + l) = make_float4(acc[i][j][0] + bv, acc[i][j][1] + bv,
                                           acc[i][j][2] + bv, acc[i][j][3] + bv);
      }
    }
  } else {
    #pragma unroll
    for (int j = 0; j < 4; ++j) {
      const int n = n0 + wn + 16 * j + lm;
      const float bv = bias[n];
      #pragma unroll
      for (int i = 0; i < 4; ++i) {
        const long mg = m0 + wr + 16 * i + lq * 4;
        #pragma unroll
        for (int r = 0; r < 4; ++r)
          outp[(mg + r) * N + n] = pack_hl(silu_f(acc[i][j][r] + bv));
      }
    }
  }
}

// ---------------------------------------------------------------------------
// MFMA GEMM + fused LayerNorm over full width BN.
// ---------------------------------------------------------------------------
template<int BN, int EPI>
__global__ __launch_bounds__(256) void lgemm_kernel(
    const u32* __restrict__ Ap, const u32* __restrict__ Wp,
    const float* __restrict__ lnw, const float* __restrict__ lnb,
    int M, int K, u32* __restrict__ outp, float* __restrict__ outf, int L)
{
  constexpr int NT = BN / 64;
  __shared__ u16 Ah[64][40], Al[64][40], Bh[BN][40], Bl[BN][40];
  __shared__ float red[4][64];
  __shared__ float muS[64], rsS[64];

  const int tid = threadIdx.x;
  const int wid = tid >> 6, lane = tid & 63;
  const int lm = lane & 15, lq = lane >> 4;
  const int m0 = blockIdx.x * 64;
  const int wn = wid * (BN / 4);
  const int sa_r = tid >> 2, sa_c = tid & 3;
  const int sa_o = ((sa_c ^ (sa_r & 3)) * 8);
  const int co = (lq ^ (lm & 3)) * 8;

  f32x4 acc[4][NT];
  #pragma unroll
  for (int i = 0; i < 4; ++i)
    #pragma unroll
    for (int j = 0; j < NT; ++j)
      #pragma unroll
      for (int r = 0; r < 4; ++r) acc[i][j][r] = 0.0f;

  const u32* ga = Ap + (long)(m0 + sa_r) * K + sa_c * 8;

  for (int k0 = 0; k0 < K; k0 += 32) {
    uint4 a0 = *(const uint4*)(ga + k0);
    uint4 a1 = *(const uint4*)(ga + k0 + 4);
    stage_chunk(&Ah[sa_r][sa_o], &Al[sa_r][sa_o], a0, a1);
    #pragma unroll
    for (int it = 0; it < NT; ++it) {
      const int idx = tid + it * 256;
      const int n = idx >> 2, c = idx & 3;
      const u32* gw = Wp + (long)n * K + k0 + c * 8;
      uint4 b0 = *(const uint4*)gw;
      uint4 b1 = *(const uint4*)(gw + 4);
      const int o = ((c ^ (n & 3)) * 8);
      stage_chunk(&Bh[n][o], &Bl[n][o], b0, b1);
    }
    __syncthreads();

    bf16x8 fah[4], fal[4];
    #pragma unroll
    for (int i = 0; i < 4; ++i) {
      fah[i] = *(const bf16x8*)&Ah[16 * i + lm][co];
      fal[i] = *(const bf16x8*)&Al[16 * i + lm][co];
    }
    #pragma unroll
    for (int j = 0; j < NT; ++j) {
      bf16x8 fbh = *(const bf16x8*)&Bh[wn + 16 * j + lm][co];
      bf16x8 fbl = *(const bf16x8*)&Bl[wn + 16 * j + lm][co];
      #pragma unroll
      for (int i = 0; i < 4; ++i) {
        acc[i][j] = __builtin_amdgcn_mfma_f32_16x16x32_bf16(fah[i], fbh, acc[i][j], 0, 0, 0);
        acc[i][j] = __builtin_amdgcn_mfma_f32_16x16x32_bf16(fah[i], fbl, acc[i][j], 0, 0, 0);
        acc[i][j] = __builtin_amdgcn_mfma_f32_16x16x32_bf16(fal[i], fbh, acc[i][j], 0, 0, 0);
      }
    }
    __syncthreads();
  }

  // ---- fused LayerNorm over BN ----
  float part[4][4];
  #pragma unroll
  for (int i = 0; i < 4; ++i)
    #pragma unroll
    for (int r = 0; r < 4; ++r) {
      float s = 0.0f;
      #pragma unroll
      for (int j = 0; j < NT; ++j) s += acc[i][j][r];
      part[i][r] = s;
    }
  #pragma unroll
  for (int off = 1; off < 16; off <<= 1)
    #pragma unroll
    for (int i = 0; i < 4; ++i)
      #pragma unroll
      for (int r = 0; r < 4; ++r) part[i][r] += __shfl_xor(part[i][r], off);
  if (lm == 0) {
    #pragma unroll
    for (int i = 0; i < 4; ++i)
      #pragma unroll
      for (int r = 0; r < 4; ++r) red[wid][16 * i + 4 * lq + r] = part[i][r];
  }
  __syncthreads();
  if (tid < 64)
    muS[tid] = (red[0][tid] + red[1][tid] + red[2][tid] + red[3][tid]) * (1.0f / BN);
  __syncthreads();
  float mu_l[4][4];
  #pragma unroll
  for (int i = 0; i < 4; ++i)
    #pragma unroll
    for (int r = 0; r < 4; ++r) mu_l[i][r] = muS[16 * i + 4 * lq + r];
  #pragma unroll
  for (int i = 0; i < 4; ++i)
    #pragma unroll
    for (int r = 0; r < 4; ++r) {
      float s = 0.0f;
      #pragma unroll
      for (int j = 0; j < NT; ++j) {
        float d = acc[i][j][r] - mu_l[i][r];
        s = fmaf(d, d, s);
      }
      part[i][r] = s;
    }
  #pragma unroll
  for (int off = 1; off < 16; off <<= 1)
    #pragma unroll
    for (int i = 0; i < 4; ++i)
      #pragma unroll
      for (int r = 0; r < 4; ++r) part[i][r] += __shfl_xor(part[i][r], off);
  if (lm == 0) {
    #pragma unroll
    for (int i = 0; i < 4; ++i)
      #pragma unroll
      for (int r = 0; r < 4; ++r) red[wid][16 * i + 4 * lq + r] = part[i][r];
  }
  __syncthreads();
  if (tid < 64)
    rsS[tid] = rsqrtf((red[0][tid] + red[1][tid] + red[2][tid] + red[3][tid]) * (1.0f / BN)
                      + 1e-5f);
  __syncthreads();
  float rs_l[4][4];
  #pragma unroll
  for (int i = 0; i < 4; ++i)
    #pragma unroll
    for (int r = 0; r < 4; ++r) rs_l[i][r] = rsS[16 * i + 4 * lq + r];

  if constexpr (EPI == 2) {
    #pragma unroll
    for (int j = 0; j < NT; ++j) {
      const int n = wn + 16 * j + lm;
      const float g = lnw[n], bb = lnb[n];
      #pragma unroll
      for (int i = 0; i < 4; ++i) {
        #pragma unroll
        for (int r = 0; r < 4; ++r) {
          const long mg = m0 + 16 * i + 4 * lq + r;
          outp[mg * BN + n] =
              pack_hl((acc[i][j][r] - mu_l[i][r]) * rs_l[i][r] * g + bb);
        }
      }
    }
  } else {
    const int b = m0 >> 12;
    const int lb = m0 & 4095;
    #pragma unroll
    for (int j = 0; j < NT; ++j) {
      const int n = wn + 16 * j + lm;
      const float g = lnw[n], bb = lnb[n];
      #pragma unroll
      for (int i = 0; i < 4; ++i) {
        const int l = lb + 16 * i + 4 * lq;
        float4 v;
        v.x = (acc[i][j][0] - mu_l[i][0]) * rs_l[i][0] * g + bb;
        v.y = (acc[i][j][1] - mu_l[i][1]) * rs_l[i][1] * g + bb;
        v.z = (acc[i][j][2] - mu_l[i][2]) * rs_l[i][2] * g + bb;
        v.w = (acc[i][j][3] - mu_l[i][3]) * rs_l[i][3] * g + bb;
        *(float4*)(outf + ((long)b * BN + n) * L + l) = v;
      }
    }
  }
}

// ---------------------------------------------------------------------------
// Fused: causal depthwise conv(4) + silu -> xc ; xdbl = xc @ wx^T (-> B,C) ;
// dt = softplus(xdbl[:r] @ wdt^T + bdt). All channel-major (b, di, L).
//
// v3: v2's vectorized data path at v1's occupancy.
//  - DI=256: LT=16, 2048 blocks. DI=128: LT=32, 1024 blocks (threads split
//    into two position-halves so all 256 threads work in conv/dt phases).
//  - LDS 17.4 KB: xcT[LT][DI] transposed conv output with add-rotate chunk
//    swizzle (conflict-free float4 reads), xds[R][LT].
//  - Phase 2 maps j = tid&(R-1), i = tid/R -> 256 threads cover the R*LT
//    xds outputs exactly (256/LT == R for both instances); per-wave LDS
//    address depends only on i -> few distinct addrs, broadcast the rest.
//    B/C rows via short second pass (tid < 4*LT). 4 partial accumulators,
//    float4 weight loads (L1-resident), no long dependent chain.
// ---------------------------------------------------------------------------
template<int DI, int R, int LT>
__global__ __launch_bounds__(256) void conv_proj_kernel(
    const float* __restrict__ xcpre_t,
    const float* __restrict__ cw, const float* __restrict__ cb,
    const float* __restrict__ wx, const float* __restrict__ wdt,
    const float* __restrict__ bdt,
    float* __restrict__ xc_t, float* __restrict__ dt_t,
    float* __restrict__ bc_t, int L)
{
  constexpr int NC = DI / 4;            // float4 chunks per position row
  static_assert(256 / LT == R, "main pass must cover xds rows exactly");
  static_assert(LT * DI == 256 * 16, "each thread convs exactly 16 positions");
  __shared__ float xcT[LT][DI];         // [pos][rot-swizzled ch]
  __shared__ float xds[R][LT];

  const int tid = threadIdx.x;
  const int l0 = blockIdx.x * LT;
  const int bz = blockIdx.y;

  // ---- phase 1: conv + silu -> xc_t global + transposed/swizzled LDS ----
  {
    const int ch = tid & (DI - 1);
    const int pb = (tid / DI) * 16;     // 0, or 16 for DI=128 upper half
    const long rowb = ((long)bz * DI + ch) * L;
    const float* __restrict__ src = xcpre_t + rowb + l0 + pb;
    const float w0 = cw[ch*4+0], w1 = cw[ch*4+1], w2 = cw[ch*4+2], w3 = cw[ch*4+3];
    const float cbc = cb[ch];
    float p0, p1, p2;
    if (l0 + pb >= 3) { p0 = src[-3]; p1 = src[-2]; p2 = src[-1]; }
    else              { p0 = 0.0f; p1 = 0.0f; p2 = 0.0f; }   // only l0==0,pb==0
    float cur[16], v[16];
    load16(cur, src);
    v[0] = silu_f(fmaf(cur[0], w3, fmaf(p2, w2, fmaf(p1, w1, fmaf(p0, w0, cbc)))));
    v[1] = silu_f(fmaf(cur[1], w3, fmaf(cur[0], w2, fmaf(p2, w1, fmaf(p1, w0, cbc)))));
    v[2] = silu_f(fmaf(cur[2], w3, fmaf(cur[1], w2, fmaf(cur[0], w1, fmaf(p2, w0, cbc)))));
    #pragma unroll
    for (int i2 = 3; i2 < 16; ++i2)
      v[i2] = silu_f(fmaf(cur[i2], w3, fmaf(cur[i2-1], w2,
                     fmaf(cur[i2-2], w1, fmaf(cur[i2-3], w0, cbc)))));
    store16(xc_t + rowb + l0 + pb, v);
    const int g = ch >> 2, c = ch & 3;
    #pragma unroll
    for (int i2 = 0; i2 < 16; ++i2) {
      const int i = pb + i2;
      xcT[i][(((g + i) & (NC - 1)) << 2) + c] = v[i2];
    }
  }
  __syncthreads();

  // ---- phase 2: xds[j][i] = sum_ch wx[j][ch] * xcT[i][ch]; B/C -> global ----
  {
    const int j = tid & (R - 1);
    const int i = tid / R;              // 0..LT-1
    f32x4 a;
    a[0] = a[1] = a[2] = a[3] = 0.0f;
    const float* __restrict__ wr = wx + (long)j * DI;
    #pragma unroll 8
    for (int g = 0; g < NC; ++g) {
      const float4 xv = *(const float4*)&xcT[i][((g + i) & (NC - 1)) << 2];
      const float4 wv = *(const float4*)(wr + (g << 2));
      a[0] = fmaf(xv.x, wv.x, a[0]);
      a[1] = fmaf(xv.y, wv.y, a[1]);
      a[2] = fmaf(xv.z, wv.z, a[2]);
      a[3] = fmaf(xv.w, wv.w, a[3]);
    }
    xds[j][i] = (a[0] + a[1]) + (a[2] + a[3]);

    if (tid < 4 * LT) {                 // B/C rows j = R..R+3
      const int j2 = R + (tid & 3);
      const int i2 = tid >> 2;          // 0..LT-1
      f32x4 b;
      b[0] = b[1] = b[2] = b[3] = 0.0f;
      const float* __restrict__ wr2 = wx + (long)j2 * DI;
      #pragma unroll 8
      for (int g = 0; g < NC; ++g) {
        const float4 xv = *(const float4*)&xcT[i2][((g + i2) & (NC - 1)) << 2];
        const float4 wv = *(const float4*)(wr2 + (g << 2));
        b[0] = fmaf(xv.x, wv.x, b[0]);
        b[1] = fmaf(xv.y, wv.y, b[1]);
        b[2] = fmaf(xv.z, wv.z, b[2]);
        b[3] = fmaf(xv.w, wv.w, b[3]);
      }
      bc_t[((long)bz * 4 + (j2 - R)) * L + l0 + i2] = (b[0] + b[1]) + (b[2] + b[3]);
    }
  }
  __syncthreads();

  // ---- phase 3: dt = softplus(xds^T @ wdt^T + bdt) ----
  {
    const int ch = tid & (DI - 1);
    const int pb = (tid / DI) * 16;
    const long rowb = ((long)bz * DI + ch) * L;
    float wr[R];
    #pragma unroll
    for (int j = 0; j < R; ++j) wr[j] = wdt[ch * R + j];
    const float bv = bdt[ch];
    float s[16];
    #pragma unroll
    for (int i2 = 0; i2 < 16; ++i2) s[i2] = bv;
    #pragma unroll
    for (int j = 0; j < R; ++j) {
      const float w = wr[j];
      const float4 x0 = *(const float4*)&xds[j][pb + 0];
      const float4 x1 = *(const float4*)&xds[j][pb + 4];
      const float4 x2 = *(const float4*)&xds[j][pb + 8];
      const float4 x3 = *(const float4*)&xds[j][pb + 12];
      s[0]  = fmaf(x0.x, w, s[0]);  s[1]  = fmaf(x0.y, w, s[1]);
      s[2]  = fmaf(x0.z, w, s[2]);  s[3]  = fmaf(x0.w, w, s[3]);
      s[4]  = fmaf(x1.x, w, s[4]);  s[5]  = fmaf(x1.y, w, s[5]);
      s[6]  = fmaf(x1.z, w, s[6]);  s[7]  = fmaf(x1.w, w, s[7]);
      s[8]  = fmaf(x2.x, w, s[8]);  s[9]  = fmaf(x2.y, w, s[9]);
      s[10] = fmaf(x2.z, w, s[10]); s[11] = fmaf(x2.w, w, s[11]);
      s[12] = fmaf(x3.x, w, s[12]); s[13] = fmaf(x3.y, w, s[13]);
      s[14] = fmaf(x3.z, w, s[14]); s[15] = fmaf(x3.w, w, s[15]);
    }
    float v[16];
    #pragma unroll
    for (int i2 = 0; i2 < 16; ++i2) v[i2] = softplus_f(s[i2]);
    store16(dt_t + rowb + l0 + pb, v);
  }
}

// ---------------------------------------------------------------------------
// Selective scan (n=2 states), block-parallel affine scan over L.
// ---------------------------------------------------------------------------
__global__ __launch_bounds__(256) void scan_kernel(
    const float* __restrict__ dt_t, const float* __restrict__ xc_t,
    const float* __restrict__ z_t, const float* __restrict__ bc_t,
    const float* __restrict__ alog, const float* __restrict__ dd,
    float* __restrict__ y_t, int di, int L)
{
  const int ch = blockIdx.x;
  const int bz = blockIdx.y;
  const int tid = threadIdx.x;
  const int lane = tid & 63;
  const int w = tid >> 6;
  const long rowb = ((long)bz * di + ch) * L;
  const long bcb = (long)bz * 4 * L;
  const int l0 = tid * 16;

  __shared__ float wsP0[4], wsQ0[4], wsP1[4], wsQ1[4];

  const float A0 = -__expf(alog[ch * 2 + 0]);
  const float A1 = -__expf(alog[ch * 2 + 1]);
  const float ddc = dd[ch];

  float dtv[16], xcv[16], t0[16], t1[16];
  load16(dtv, dt_t + rowb + l0);
  load16(xcv, xc_t + rowb + l0);
  load16(t0, bc_t + bcb + l0);
  load16(t1, bc_t + bcb + L + l0);

  float a0[16], a1[16], u0[16], u1[16];
  float P0 = 1.0f, Q0 = 0.0f, P1 = 1.0f, Q1 = 0.0f;
  #pragma unroll
  for (int i = 0; i < 16; ++i) {
    const float dt = dtv[i];
    const float dx = dt * xcv[i];
    a0[i] = __expf(dt * A0);
    a1[i] = __expf(dt * A1);
    u0[i] = dx * t0[i];
    u1[i] = dx * t1[i];
    Q0 = fmaf(a0[i], Q0, u0[i]); P0 *= a0[i];
    Q1 = fmaf(a1[i], Q1, u1[i]); P1 *= a1[i];
  }

  #pragma unroll
  for (int off = 1; off < 64; off <<= 1) {
    const float pp0 = __shfl_up(P0, off);
    const float qq0 = __shfl_up(Q0, off);
    const float pp1 = __shfl_up(P1, off);
    const float qq1 = __shfl_up(Q1, off);
    if (lane >= off) {
      Q0 = fmaf(P0, qq0, Q0); P0 *= pp0;
      Q1 = fmaf(P1, qq1, Q1); P1 *= pp1;
    }
  }
  if (lane == 63) { wsP0[w] = P0; wsQ0[w] = Q0; wsP1[w] = P1; wsQ1[w] = Q1; }
  __syncthreads();
  float eQ0 = 0.0f, eQ1 = 0.0f;
  for (int ww = 0; ww < w; ++ww) {
    eQ0 = fmaf(wsP0[ww], eQ0, wsQ0[ww]);
    eQ1 = fmaf(wsP1[ww], eQ1, wsQ1[ww]);
  }
  float pP0 = __shfl_up(P0, 1), pQ0 = __shfl_up(Q0, 1);
  float pP1 = __shfl_up(P1, 1), pQ1 = __shfl_up(Q1, 1);
  if (lane == 0) { pP0 = 1.0f; pQ0 = 0.0f; pP1 = 1.0f; pQ1 = 0.0f; }
  float h0 = fmaf(pP0, eQ0, pQ0);
  float h1 = fmaf(pP1, eQ1, pQ1);

  float c0[16], c1[16], zv[16], yv[16];
  load16(c0, bc_t + bcb + 2 * L + l0);
  load16(c1, bc_t + bcb + 3 * L + l0);
  load16(zv, z_t + rowb + l0);
  #pragma unroll
  for (int i = 0; i < 16; ++i) {
    h0 = fmaf(a0[i], h0, u0[i]);
    h1 = fmaf(a1[i], h1, u1[i]);
    const float y = fmaf(h0, c0[i], fmaf(h1, c1[i], ddc * xcv[i]));
    yv[i] = y * silu_f(zv[i]);
  }
  store16(y_t + rowb + l0, yv);
}

// ---------------------------------------------------------------------------
extern "C" void kernel_launch(void* const* d_in, const int* in_sizes, int n_in,
                              void* d_out, int out_size, void* d_ws, size_t ws_size,
                              hipStream_t stream)
{
  const float* x       = (const float*)d_in[0];
  const float* lin_w   = (const float*)d_in[1];
  const float* lin_b   = (const float*)d_in[2];
  const float* s1_win  = (const float*)d_in[3];
  const float* s1_bin  = (const float*)d_in[4];
  const float* s1_cw   = (const float*)d_in[5];
  const float* s1_cb   = (const float*)d_in[6];
  const float* s1_wx   = (const float*)d_in[7];
  const float* s1_wdt  = (const float*)d_in[8];
  const float* s1_bdt  = (const float*)d_in[9];
  const float* s1_alog = (const float*)d_in[10];
  const float* s1_dd   = (const float*)d_in[11];
  const float* s1_wout = (const float*)d_in[12];
  const float* s1_lnw  = (const float*)d_in[13];
  const float* s1_lnb  = (const float*)d_in[14];
  const float* s2_win  = (const float*)d_in[15];
  const float* s2_bin  = (const float*)d_in[16];
  const float* s2_cw   = (const float*)d_in[17];
  const float* s2_cb   = (const float*)d_in[18];
  const float* s2_wx   = (const float*)d_in[19];
  const float* s2_wdt  = (const float*)d_in[20];
  const float* s2_bdt  = (const float*)d_in[21];
  const float* s2_alog = (const float*)d_in[22];
  const float* s2_dd   = (const float*)d_in[23];
  const float* s2_wout = (const float*)d_in[24];
  const float* s2_lnw  = (const float*)d_in[25];
  const float* s2_lnb  = (const float*)d_in[26];
  float* out = (float*)d_out;

  const int B = 8, L = 4096, M = 32768;
  const long SLOT = 8L * 256 * 4096;   // 8388608 elems = 32 MB
  const long HALF = SLOT / 2;          // 16 MB
  float* ws = (float*)d_ws;
  float* S0f = ws;             u32* S0u = (u32*)S0f;
  float* S1f = ws + SLOT;      u32* S1u = (u32*)S1f;
  float* S2f = ws + 2 * SLOT;  u32* S2u = (u32*)S2f;
  float* S3f = ws + 3 * SLOT;
  float* SBf = ws + 4 * SLOT;                       // (B,4,L) = 131072
  u32*   WP  = (u32*)(ws + 4 * SLOT + 131072);      // packed weights

  // 1. pack weights
  wprep_kernel<<<WTOT / 256, 256, 0, stream>>>(s1_win, s1_wout, lin_w, s2_win, s2_wout, WP);
  // 2. x (b,128,L) -> packed xT (M,128) @ S0u
  tpose_kernel<<<dim3(128, 4, B), 256, 0, stream>>>(x, S0u, 128, L);
  // 3. stage1 in-proj: -> xcpre1 @ S1f, z1 @ S1f+HALF
  mgemm_kernel<0><<<dim3(2, 256), 256, 0, stream>>>(
      S0u, WP + WOFF1, s1_bin, M, 256, 128, S1f, S1f + HALF, nullptr, 128, L);
  // 4. conv1 -> xc1 @ S2f, dt1 @ S2f+HALF, B/C @ SBf
  conv_proj_kernel<128, 8, 32><<<dim3(128, B), 256, 0, stream>>>(
      S1f, s1_cw, s1_cb, s1_wx, s1_wdt, s1_bdt, S2f, S2f + HALF, SBf, L);
  // 5. scan1 -> y1 @ S0f
  scan_kernel<<<dim3(128, B), 256, 0, stream>>>(
      S2f + HALF, S2f, S1f + HALF, SBf, s1_alog, s1_dd, S0f, 128, L);
  // 6. y1 -> packed y1T @ S0u+HALF
  tpose_kernel<<<dim3(128, 4, B), 256, 0, stream>>>(S0f, S0u + HALF, 128, L);
  // 7. out-proj1 + LN -> act_mid packed @ S1u
  lgemm_kernel<128, 2><<<dim3(512), 256, 0, stream>>>(
      S0u + HALF, WP + WOFFO1, s1_lnw, s1_lnb, M, 128, S1u, nullptr, L);
  // 8. mid linear + silu -> act_lin packed @ S2u
  mgemm_kernel<1><<<dim3(2, 256), 256, 0, stream>>>(
      S1u, WP + WOFFL, lin_b, M, 256, 128, nullptr, nullptr, S2u, 0, L);
  // 9. stage2 in-proj: -> xcpre2 @ S0f, z2 @ S1f
  mgemm_kernel<0><<<dim3(4, 256), 256, 0, stream>>>(
      S2u, WP + WOFF2, s2_bin, M, 512, 256, S0f, S1f, nullptr, 256, L);
  // 10. conv2 -> xc2 @ S3f, dt2 @ S2f
  conv_proj_kernel<256, 16, 16><<<dim3(256, B), 256, 0, stream>>>(
      S0f, s2_cw, s2_cb, s2_wx, s2_wdt, s2_bdt, S3f, S2f, SBf, L);
  // 11. scan2 -> y2 @ S0f
  scan_kernel<<<dim3(256, B), 256, 0, stream>>>(
      S2f, S3f, S1f, SBf, s2_alog, s2_dd, S0f, 256, L);
  // 12. y2 -> packed y2T @ S1u
  tpose_kernel<<<dim3(128, 8, B), 256, 0, stream>>>(S0f, S1u, 256, L);
  // 13. out-proj2 + LN -> d_out fp32 (b,256,64,64)
  lgemm_kernel<256, 3><<<dim3(512), 256, 0, stream>>>(
      S1u, WP + WOFFO2, s2_lnw, s2_lnb, M, 256, nullptr, out, L);
}

// Round 3
// 415.489 us; speedup vs baseline: 1.2602x; 1.2602x over previous
//
#include <hip/hip_runtime.h>
#include <math.h>

#define DEVI __device__ __forceinline__

typedef unsigned int u32;
typedef unsigned short u16;
typedef __attribute__((ext_vector_type(8))) __bf16 bf16x8;
typedef __attribute__((ext_vector_type(8))) u16 u16x8;
typedef __attribute__((ext_vector_type(4))) float f32x4;

DEVI float silu_f(float x) { return x * (1.0f / (1.0f + __expf(-x))); }
DEVI float softplus_f(float x) {
  return x > 0.0f ? x + log1pf(__expf(-x)) : log1pf(__expf(x));
}

DEVI u32 bf16_rne(float f) {
  u32 u = __float_as_uint(f);
  return (u + 0x7fffu + ((u >> 16) & 1u)) >> 16;
}
// packed split: high 16 bits = bf16(f), low 16 bits = bf16(f - hi)
DEVI u32 pack_hl(float f) {
  u32 h = bf16_rne(f);
  float hf = __uint_as_float(h << 16);
  u32 l = bf16_rne(f - hf);
  return (h << 16) | l;
}

DEVI void load16(float* r, const float* __restrict__ p) {
  const float4* q = (const float4*)p;
  float4 a = q[0], b = q[1], c = q[2], d = q[3];
  r[0]=a.x; r[1]=a.y; r[2]=a.z; r[3]=a.w;
  r[4]=b.x; r[5]=b.y; r[6]=b.z; r[7]=b.w;
  r[8]=c.x; r[9]=c.y; r[10]=c.z; r[11]=c.w;
  r[12]=d.x; r[13]=d.y; r[14]=d.z; r[15]=d.w;
}
DEVI void store16(float* __restrict__ p, const float* r) {
  float4* q = (float4*)p;
  q[0] = make_float4(r[0],r[1],r[2],r[3]);
  q[1] = make_float4(r[4],r[5],r[6],r[7]);
  q[2] = make_float4(r[8],r[9],r[10],r[11]);
  q[3] = make_float4(r[12],r[13],r[14],r[15]);
}

// split 8 packed u32 into hi/lo bf16 chunks and store 16B each to LDS
DEVI void stage_chunk(u16* __restrict__ ph, u16* __restrict__ pl, uint4 a, uint4 b) {
  u16x8 h, l;
  h[0] = (u16)(a.x >> 16); l[0] = (u16)a.x;
  h[1] = (u16)(a.y >> 16); l[1] = (u16)a.y;
  h[2] = (u16)(a.z >> 16); l[2] = (u16)a.z;
  h[3] = (u16)(a.w >> 16); l[3] = (u16)a.w;
  h[4] = (u16)(b.x >> 16); l[4] = (u16)b.x;
  h[5] = (u16)(b.y >> 16); l[5] = (u16)b.y;
  h[6] = (u16)(b.z >> 16); l[6] = (u16)b.z;
  h[7] = (u16)(b.w >> 16); l[7] = (u16)b.w;
  *(u16x8*)ph = h; *(u16x8*)pl = l;
}

// ---------------------------------------------------------------------------
// Weight prep: convert 5 fp32 weight matrices to packed hi/lo bf16 (u32).
// ---------------------------------------------------------------------------
constexpr int WN1 = 32768, WNO1 = 16384, WNL = 32768, WN2 = 131072, WNO2 = 65536;
constexpr int WOFF1 = 0, WOFFO1 = 32768, WOFFL = 49152, WOFF2 = 81920, WOFFO2 = 212992;
constexpr int WTOT = 278528;

__global__ __launch_bounds__(256) void wprep_kernel(
    const float* __restrict__ w1, const float* __restrict__ wo1,
    const float* __restrict__ wl, const float* __restrict__ w2,
    const float* __restrict__ wo2, u32* __restrict__ dst)
{
  int i = blockIdx.x * 256 + threadIdx.x;
  float v;
  if (i < WOFFO1)       v = w1[i];
  else if (i < WOFFL)   v = wo1[i - WOFFO1];
  else if (i < WOFF2)   v = wl[i - WOFFL];
  else if (i < WOFFO2)  v = w2[i - WOFF2];
  else                  v = wo2[i - WOFFO2];
  dst[i] = pack_hl(v);
}

// ---------------------------------------------------------------------------
// Transpose: fp32 (b, C, L) -> packed u32 (b*L, C)
// ---------------------------------------------------------------------------
__global__ __launch_bounds__(256) void tpose_kernel(
    const float* __restrict__ in, u32* __restrict__ out, int C, int L)
{
  __shared__ float t[32][33];
  const int l0 = blockIdx.x * 32, c0 = blockIdx.y * 32, b = blockIdx.z;
  const int tx = threadIdx.x & 31, ty = threadIdx.x >> 5;
  const float* src = in + ((long)b * C + c0) * L + l0;
  #pragma unroll
  for (int r = 0; r < 32; r += 8) t[ty + r][tx] = src[(long)(ty + r) * L + tx];
  __syncthreads();
  u32* dst = out + ((long)b * L + l0) * C + c0;
  #pragma unroll
  for (int r = 0; r < 32; r += 8) dst[(long)(ty + r) * C + tx] = pack_hl(t[tx][ty + r]);
}

// ---------------------------------------------------------------------------
// MFMA GEMM (bf16x3 split): C[m,n] = sum_k A[m,k]*W[n,k] (+bias)
// ---------------------------------------------------------------------------
template<int EPI>
__global__ __launch_bounds__(256) void mgemm_kernel(
    const u32* __restrict__ Ap, const u32* __restrict__ Wp,
    const float* __restrict__ bias, int M, int N, int K,
    float* __restrict__ out0, float* __restrict__ out1,
    u32* __restrict__ outp, int di, int L)
{
  __shared__ u16 Ah[128][40], Al[128][40], Bh[128][40], Bl[128][40];
  const int tid = threadIdx.x;
  const int wid = tid >> 6, lane = tid & 63;
  const int lm = lane & 15, lq = lane >> 4;
  const int m0 = blockIdx.y * 128, n0 = blockIdx.x * 128;
  const int wr = (wid >> 1) * 64, wn = (wid & 1) * 64;
  const int sr = tid >> 1;
  const int sc = (tid & 1) * 2;
  const int o0 = (((sc + 0) ^ (sr & 3)) * 8);
  const int o1 = (((sc + 1) ^ (sr & 3)) * 8);

  f32x4 acc[4][4];
  #pragma unroll
  for (int i = 0; i < 4; ++i)
    #pragma unroll
    for (int j = 0; j < 4; ++j)
      #pragma unroll
      for (int r = 0; r < 4; ++r) acc[i][j][r] = 0.0f;

  const u32* ga = Ap + (long)(m0 + sr) * K + sc * 8;
  const u32* gb = Wp + (long)(n0 + sr) * K + sc * 8;
  const int co = (lq ^ (lm & 3)) * 8;

  for (int k0 = 0; k0 < K; k0 += 32) {
    uint4 a0 = *(const uint4*)(ga + k0);
    uint4 a1 = *(const uint4*)(ga + k0 + 4);
    uint4 a2 = *(const uint4*)(ga + k0 + 8);
    uint4 a3 = *(const uint4*)(ga + k0 + 12);
    uint4 b0 = *(const uint4*)(gb + k0);
    uint4 b1 = *(const uint4*)(gb + k0 + 4);
    uint4 b2 = *(const uint4*)(gb + k0 + 8);
    uint4 b3 = *(const uint4*)(gb + k0 + 12);
    stage_chunk(&Ah[sr][o0], &Al[sr][o0], a0, a1);
    stage_chunk(&Ah[sr][o1], &Al[sr][o1], a2, a3);
    stage_chunk(&Bh[sr][o0], &Bl[sr][o0], b0, b1);
    stage_chunk(&Bh[sr][o1], &Bl[sr][o1], b2, b3);
    __syncthreads();

    bf16x8 fah[4], fal[4];
    #pragma unroll
    for (int i = 0; i < 4; ++i) {
      fah[i] = *(const bf16x8*)&Ah[wr + 16 * i + lm][co];
      fal[i] = *(const bf16x8*)&Al[wr + 16 * i + lm][co];
    }
    #pragma unroll
    for (int j = 0; j < 4; ++j) {
      bf16x8 fbh = *(const bf16x8*)&Bh[wn + 16 * j + lm][co];
      bf16x8 fbl = *(const bf16x8*)&Bl[wn + 16 * j + lm][co];
      #pragma unroll
      for (int i = 0; i < 4; ++i) {
        acc[i][j] = __builtin_amdgcn_mfma_f32_16x16x32_bf16(fah[i], fbh, acc[i][j], 0, 0, 0);
        acc[i][j] = __builtin_amdgcn_mfma_f32_16x16x32_bf16(fah[i], fbl, acc[i][j], 0, 0, 0);
        acc[i][j] = __builtin_amdgcn_mfma_f32_16x16x32_bf16(fal[i], fbh, acc[i][j], 0, 0, 0);
      }
    }
    __syncthreads();
  }

  if constexpr (EPI == 0) {
    const int b = m0 >> 12;
    const int lb = (m0 & 4095) + wr;
    #pragma unroll
    for (int j = 0; j < 4; ++j) {
      const int n = n0 + wn + 16 * j + lm;
      const float bv = bias[n];
      float* base = (n < di) ? out0 + ((long)b * di + n) * L
                             : out1 + ((long)b * di + (n - di)) * L;
      #pragma unroll
      for (int i = 0; i < 4; ++i) {
        const int l = lb + 16 * i + lq * 4;
        *(float4*)(base + l) = make_float4(acc[i][j][0] + bv, acc[i][j][1] + bv,
                                           acc[i][j][2] + bv, acc[i][j][3] + bv);
      }
    }
  } else {
    #pragma unroll
    for (int j = 0; j < 4; ++j) {
      const int n = n0 + wn + 16 * j + lm;
      const float bv = bias[n];
      #pragma unroll
      for (int i = 0; i < 4; ++i) {
        const long mg = m0 + wr + 16 * i + lq * 4;
        #pragma unroll
        for (int r = 0; r < 4; ++r)
          outp[(mg + r) * N + n] = pack_hl(silu_f(acc[i][j][r] + bv));
      }
    }
  }
}

// ---------------------------------------------------------------------------
// MFMA GEMM + fused LayerNorm over full width BN.
// ---------------------------------------------------------------------------
template<int BN, int EPI>
__global__ __launch_bounds__(256) void lgemm_kernel(
    const u32* __restrict__ Ap, const u32* __restrict__ Wp,
    const float* __restrict__ lnw, const float* __restrict__ lnb,
    int M, int K, u32* __restrict__ outp, float* __restrict__ outf, int L)
{
  constexpr int NT = BN / 64;
  __shared__ u16 Ah[64][40], Al[64][40], Bh[BN][40], Bl[BN][40];
  __shared__ float red[4][64];
  __shared__ float muS[64], rsS[64];

  const int tid = threadIdx.x;
  const int wid = tid >> 6, lane = tid & 63;
  const int lm = lane & 15, lq = lane >> 4;
  const int m0 = blockIdx.x * 64;
  const int wn = wid * (BN / 4);
  const int sa_r = tid >> 2, sa_c = tid & 3;
  const int sa_o = ((sa_c ^ (sa_r & 3)) * 8);
  const int co = (lq ^ (lm & 3)) * 8;

  f32x4 acc[4][NT];
  #pragma unroll
  for (int i = 0; i < 4; ++i)
    #pragma unroll
    for (int j = 0; j < NT; ++j)
      #pragma unroll
      for (int r = 0; r < 4; ++r) acc[i][j][r] = 0.0f;

  const u32* ga = Ap + (long)(m0 + sa_r) * K + sa_c * 8;

  for (int k0 = 0; k0 < K; k0 += 32) {
    uint4 a0 = *(const uint4*)(ga + k0);
    uint4 a1 = *(const uint4*)(ga + k0 + 4);
    stage_chunk(&Ah[sa_r][sa_o], &Al[sa_r][sa_o], a0, a1);
    #pragma unroll
    for (int it = 0; it < NT; ++it) {
      const int idx = tid + it * 256;
      const int n = idx >> 2, c = idx & 3;
      const u32* gw = Wp + (long)n * K + k0 + c * 8;
      uint4 b0 = *(const uint4*)gw;
      uint4 b1 = *(const uint4*)(gw + 4);
      const int o = ((c ^ (n & 3)) * 8);
      stage_chunk(&Bh[n][o], &Bl[n][o], b0, b1);
    }
    __syncthreads();

    bf16x8 fah[4], fal[4];
    #pragma unroll
    for (int i = 0; i < 4; ++i) {
      fah[i] = *(const bf16x8*)&Ah[16 * i + lm][co];
      fal[i] = *(const bf16x8*)&Al[16 * i + lm][co];
    }
    #pragma unroll
    for (int j = 0; j < NT; ++j) {
      bf16x8 fbh = *(const bf16x8*)&Bh[wn + 16 * j + lm][co];
      bf16x8 fbl = *(const bf16x8*)&Bl[wn + 16 * j + lm][co];
      #pragma unroll
      for (int i = 0; i < 4; ++i) {
        acc[i][j] = __builtin_amdgcn_mfma_f32_16x16x32_bf16(fah[i], fbh, acc[i][j], 0, 0, 0);
        acc[i][j] = __builtin_amdgcn_mfma_f32_16x16x32_bf16(fah[i], fbl, acc[i][j], 0, 0, 0);
        acc[i][j] = __builtin_amdgcn_mfma_f32_16x16x32_bf16(fal[i], fbh, acc[i][j], 0, 0, 0);
      }
    }
    __syncthreads();
  }

  // ---- fused LayerNorm over BN ----
  float part[4][4];
  #pragma unroll
  for (int i = 0; i < 4; ++i)
    #pragma unroll
    for (int r = 0; r < 4; ++r) {
      float s = 0.0f;
      #pragma unroll
      for (int j = 0; j < NT; ++j) s += acc[i][j][r];
      part[i][r] = s;
    }
  #pragma unroll
  for (int off = 1; off < 16; off <<= 1)
    #pragma unroll
    for (int i = 0; i < 4; ++i)
      #pragma unroll
      for (int r = 0; r < 4; ++r) part[i][r] += __shfl_xor(part[i][r], off);
  if (lm == 0) {
    #pragma unroll
    for (int i = 0; i < 4; ++i)
      #pragma unroll
      for (int r = 0; r < 4; ++r) red[wid][16 * i + 4 * lq + r] = part[i][r];
  }
  __syncthreads();
  if (tid < 64)
    muS[tid] = (red[0][tid] + red[1][tid] + red[2][tid] + red[3][tid]) * (1.0f / BN);
  __syncthreads();
  float mu_l[4][4];
  #pragma unroll
  for (int i = 0; i < 4; ++i)
    #pragma unroll
    for (int r = 0; r < 4; ++r) mu_l[i][r] = muS[16 * i + 4 * lq + r];
  #pragma unroll
  for (int i = 0; i < 4; ++i)
    #pragma unroll
    for (int r = 0; r < 4; ++r) {
      float s = 0.0f;
      #pragma unroll
      for (int j = 0; j < NT; ++j) {
        float d = acc[i][j][r] - mu_l[i][r];
        s = fmaf(d, d, s);
      }
      part[i][r] = s;
    }
  #pragma unroll
  for (int off = 1; off < 16; off <<= 1)
    #pragma unroll
    for (int i = 0; i < 4; ++i)
      #pragma unroll
      for (int r = 0; r < 4; ++r) part[i][r] += __shfl_xor(part[i][r], off);
  if (lm == 0) {
    #pragma unroll
    for (int i = 0; i < 4; ++i)
      #pragma unroll
      for (int r = 0; r < 4; ++r) red[wid][16 * i + 4 * lq + r] = part[i][r];
  }
  __syncthreads();
  if (tid < 64)
    rsS[tid] = rsqrtf((red[0][tid] + red[1][tid] + red[2][tid] + red[3][tid]) * (1.0f / BN)
                      + 1e-5f);
  __syncthreads();
  float rs_l[4][4];
  #pragma unroll
  for (int i = 0; i < 4; ++i)
    #pragma unroll
    for (int r = 0; r < 4; ++r) rs_l[i][r] = rsS[16 * i + 4 * lq + r];

  if constexpr (EPI == 2) {
    #pragma unroll
    for (int j = 0; j < NT; ++j) {
      const int n = wn + 16 * j + lm;
      const float g = lnw[n], bb = lnb[n];
      #pragma unroll
      for (int i = 0; i < 4; ++i) {
        #pragma unroll
        for (int r = 0; r < 4; ++r) {
          const long mg = m0 + 16 * i + 4 * lq + r;
          outp[mg * BN + n] =
              pack_hl((acc[i][j][r] - mu_l[i][r]) * rs_l[i][r] * g + bb);
        }
      }
    }
  } else {
    const int b = m0 >> 12;
    const int lb = m0 & 4095;
    #pragma unroll
    for (int j = 0; j < NT; ++j) {
      const int n = wn + 16 * j + lm;
      const float g = lnw[n], bb = lnb[n];
      #pragma unroll
      for (int i = 0; i < 4; ++i) {
        const int l = lb + 16 * i + 4 * lq;
        float4 v;
        v.x = (acc[i][j][0] - mu_l[i][0]) * rs_l[i][0] * g + bb;
        v.y = (acc[i][j][1] - mu_l[i][1]) * rs_l[i][1] * g + bb;
        v.z = (acc[i][j][2] - mu_l[i][2]) * rs_l[i][2] * g + bb;
        v.w = (acc[i][j][3] - mu_l[i][3]) * rs_l[i][3] * g + bb;
        *(float4*)(outf + ((long)b * BN + n) * L + l) = v;
      }
    }
  }
}

// ---------------------------------------------------------------------------
// Fused: causal depthwise conv(4) + silu -> xc ; xdbl = xc @ wx^T (-> B,C) ;
// dt = softplus(xdbl[:r] @ wdt^T + bdt). All channel-major (b, di, L).
//
// v4: v1 skeleton (LT=16, tid<DI phases, VGPR-light) with surgical edits:
//  - phase 1: identical to v1 except LDS write goes to transposed
//    rotate-swizzled xcT[i][ch'] (same instruction count, <=2-way banks).
//  - phase 2: v1's q->(j,i) loop, but float4 x float4 dot product over the
//    transposed tile (NC=DI/4 iters, 4 independent chains), unroll 4 only.
//  - phase 3: xds read as float4 per 4-position chunk (R reads per chunk),
//    xds padded to 20 floats/row for 16B alignment.
// ---------------------------------------------------------------------------
template<int DI, int R>
__global__ __launch_bounds__(256) void conv_proj_kernel(
    const float* __restrict__ xcpre_t,
    const float* __restrict__ cw, const float* __restrict__ cb,
    const float* __restrict__ wx, const float* __restrict__ wdt,
    const float* __restrict__ bdt,
    float* __restrict__ xc_t, float* __restrict__ dt_t,
    float* __restrict__ bc_t, int L)
{
  constexpr int LT = 16;
  constexpr int NP = R + 4;            // proj rows: R dt-rank + 2 B + 2 C
  constexpr int NC = DI / 4;           // float4 chunks per position row
  __shared__ float xcT[LT][DI];        // [pos][rot-swizzled ch]
  __shared__ float xds[R][20];         // padded: 16B-aligned rows, bank-spread

  const int tid = threadIdx.x;
  const int l0 = blockIdx.x * LT;
  const int bz = blockIdx.y;

  // ---- phase 1: conv + silu -> xc_t global + transposed/swizzled LDS ----
  if (tid < DI) {
    const int ch = tid;
    const long rowb = ((long)bz * DI + ch) * L;
    const float* __restrict__ src = xcpre_t + rowb + l0;
    float pre[LT + 3];
    if (l0 >= 3) {
      #pragma unroll
      for (int i = 0; i < LT + 3; ++i) pre[i] = src[i - 3];
    } else {
      #pragma unroll
      for (int i = 0; i < LT + 3; ++i) {
        const int l = l0 - 3 + i;
        pre[i] = (l >= 0) ? xcpre_t[rowb + l] : 0.0f;
      }
    }
    const float w0 = cw[ch*4+0], w1 = cw[ch*4+1], w2 = cw[ch*4+2], w3 = cw[ch*4+3];
    const float cbc = cb[ch];
    const int g = ch >> 2, c = ch & 3;
    float v[LT];
    #pragma unroll
    for (int i = 0; i < LT; ++i) {
      float s = cbc;
      s = fmaf(pre[i+0], w0, s);
      s = fmaf(pre[i+1], w1, s);
      s = fmaf(pre[i+2], w2, s);
      s = fmaf(pre[i+3], w3, s);
      const float sv = silu_f(s);
      v[i] = sv;
      xcT[i][(((g + i) & (NC - 1)) << 2) + c] = sv;
    }
    store16(xc_t + rowb + l0, v);
  }
  __syncthreads();

  // ---- phase 2: out[j][i] = sum_ch wx[j][ch] * xc[ch][i] (float4 dot) ----
  for (int q = tid; q < NP * LT; q += 256) {
    const int j = q >> 4;
    const int i = q & 15;
    const float* __restrict__ wr = wx + (long)j * DI;
    float a0 = 0.0f, a1 = 0.0f, a2 = 0.0f, a3 = 0.0f;
    #pragma unroll 4
    for (int g = 0; g < NC; ++g) {
      const float4 xv = *(const float4*)&xcT[i][((g + i) & (NC - 1)) << 2];
      const float4 wv = *(const float4*)(wr + (g << 2));
      a0 = fmaf(xv.x, wv.x, a0);
      a1 = fmaf(xv.y, wv.y, a1);
      a2 = fmaf(xv.z, wv.z, a2);
      a3 = fmaf(xv.w, wv.w, a3);
    }
    const float val = (a0 + a1) + (a2 + a3);
    if (j < R) xds[j][i] = val;
    else       bc_t[((long)bz * 4 + (j - R)) * L + l0 + i] = val;
  }
  __syncthreads();

  // ---- phase 3: dt = softplus(xds^T @ wdt^T + bdt) ----
  if (tid < DI) {
    const int ch = tid;
    const long rowb = ((long)bz * DI + ch) * L;
    float wr[R];
    #pragma unroll
    for (int j = 0; j < R; ++j) wr[j] = wdt[ch * R + j];
    const float bv = bdt[ch];
    #pragma unroll
    for (int ic = 0; ic < 4; ++ic) {
      float s0 = bv, s1 = bv, s2 = bv, s3 = bv;
      #pragma unroll
      for (int j = 0; j < R; ++j) {
        const float w = wr[j];
        const float4 xv = *(const float4*)&xds[j][ic * 4];
        s0 = fmaf(xv.x, w, s0);
        s1 = fmaf(xv.y, w, s1);
        s2 = fmaf(xv.z, w, s2);
        s3 = fmaf(xv.w, w, s3);
      }
      float4 o = make_float4(softplus_f(s0), softplus_f(s1),
                             softplus_f(s2), softplus_f(s3));
      *(float4*)(dt_t + rowb + l0 + ic * 4) = o;
    }
  }
}

// ---------------------------------------------------------------------------
// Selective scan (n=2 states), block-parallel affine scan over L.
// ---------------------------------------------------------------------------
__global__ __launch_bounds__(256) void scan_kernel(
    const float* __restrict__ dt_t, const float* __restrict__ xc_t,
    const float* __restrict__ z_t, const float* __restrict__ bc_t,
    const float* __restrict__ alog, const float* __restrict__ dd,
    float* __restrict__ y_t, int di, int L)
{
  const int ch = blockIdx.x;
  const int bz = blockIdx.y;
  const int tid = threadIdx.x;
  const int lane = tid & 63;
  const int w = tid >> 6;
  const long rowb = ((long)bz * di + ch) * L;
  const long bcb = (long)bz * 4 * L;
  const int l0 = tid * 16;

  __shared__ float wsP0[4], wsQ0[4], wsP1[4], wsQ1[4];

  const float A0 = -__expf(alog[ch * 2 + 0]);
  const float A1 = -__expf(alog[ch * 2 + 1]);
  const float ddc = dd[ch];

  float dtv[16], xcv[16], t0[16], t1[16];
  load16(dtv, dt_t + rowb + l0);
  load16(xcv, xc_t + rowb + l0);
  load16(t0, bc_t + bcb + l0);
  load16(t1, bc_t + bcb + L + l0);

  float a0[16], a1[16], u0[16], u1[16];
  float P0 = 1.0f, Q0 = 0.0f, P1 = 1.0f, Q1 = 0.0f;
  #pragma unroll
  for (int i = 0; i < 16; ++i) {
    const float dt = dtv[i];
    const float dx = dt * xcv[i];
    a0[i] = __expf(dt * A0);
    a1[i] = __expf(dt * A1);
    u0[i] = dx * t0[i];
    u1[i] = dx * t1[i];
    Q0 = fmaf(a0[i], Q0, u0[i]); P0 *= a0[i];
    Q1 = fmaf(a1[i], Q1, u1[i]); P1 *= a1[i];
  }

  #pragma unroll
  for (int off = 1; off < 64; off <<= 1) {
    const float pp0 = __shfl_up(P0, off);
    const float qq0 = __shfl_up(Q0, off);
    const float pp1 = __shfl_up(P1, off);
    const float qq1 = __shfl_up(Q1, off);
    if (lane >= off) {
      Q0 = fmaf(P0, qq0, Q0); P0 *= pp0;
      Q1 = fmaf(P1, qq1, Q1); P1 *= pp1;
    }
  }
  if (lane == 63) { wsP0[w] = P0; wsQ0[w] = Q0; wsP1[w] = P1; wsQ1[w] = Q1; }
  __syncthreads();
  float eQ0 = 0.0f, eQ1 = 0.0f;
  for (int ww = 0; ww < w; ++ww) {
    eQ0 = fmaf(wsP0[ww], eQ0, wsQ0[ww]);
    eQ1 = fmaf(wsP1[ww], eQ1, wsQ1[ww]);
  }
  float pP0 = __shfl_up(P0, 1), pQ0 = __shfl_up(Q0, 1);
  float pP1 = __shfl_up(P1, 1), pQ1 = __shfl_up(Q1, 1);
  if (lane == 0) { pP0 = 1.0f; pQ0 = 0.0f; pP1 = 1.0f; pQ1 = 0.0f; }
  float h0 = fmaf(pP0, eQ0, pQ0);
  float h1 = fmaf(pP1, eQ1, pQ1);

  float c0[16], c1[16], zv[16], yv[16];
  load16(c0, bc_t + bcb + 2 * L + l0);
  load16(c1, bc_t + bcb + 3 * L + l0);
  load16(zv, z_t + rowb + l0);
  #pragma unroll
  for (int i = 0; i < 16; ++i) {
    h0 = fmaf(a0[i], h0, u0[i]);
    h1 = fmaf(a1[i], h1, u1[i]);
    const float y = fmaf(h0, c0[i], fmaf(h1, c1[i], ddc * xcv[i]));
    yv[i] = y * silu_f(zv[i]);
  }
  store16(y_t + rowb + l0, yv);
}

// ---------------------------------------------------------------------------
extern "C" void kernel_launch(void* const* d_in, const int* in_sizes, int n_in,
                              void* d_out, int out_size, void* d_ws, size_t ws_size,
                              hipStream_t stream)
{
  const float* x       = (const float*)d_in[0];
  const float* lin_w   = (const float*)d_in[1];
  const float* lin_b   = (const float*)d_in[2];
  const float* s1_win  = (const float*)d_in[3];
  const float* s1_bin  = (const float*)d_in[4];
  const float* s1_cw   = (const float*)d_in[5];
  const float* s1_cb   = (const float*)d_in[6];
  const float* s1_wx   = (const float*)d_in[7];
  const float* s1_wdt  = (const float*)d_in[8];
  const float* s1_bdt  = (const float*)d_in[9];
  const float* s1_alog = (const float*)d_in[10];
  const float* s1_dd   = (const float*)d_in[11];
  const float* s1_wout = (const float*)d_in[12];
  const float* s1_lnw  = (const float*)d_in[13];
  const float* s1_lnb  = (const float*)d_in[14];
  const float* s2_win  = (const float*)d_in[15];
  const float* s2_bin  = (const float*)d_in[16];
  const float* s2_cw   = (const float*)d_in[17];
  const float* s2_cb   = (const float*)d_in[18];
  const float* s2_wx   = (const float*)d_in[19];
  const float* s2_wdt  = (const float*)d_in[20];
  const float* s2_bdt  = (const float*)d_in[21];
  const float* s2_alog = (const float*)d_in[22];
  const float* s2_dd   = (const float*)d_in[23];
  const float* s2_wout = (const float*)d_in[24];
  const float* s2_lnw  = (const float*)d_in[25];
  const float* s2_lnb  = (const float*)d_in[26];
  float* out = (float*)d_out;

  const int B = 8, L = 4096, M = 32768;
  const long SLOT = 8L * 256 * 4096;   // 8388608 elems = 32 MB
  const long HALF = SLOT / 2;          // 16 MB
  float* ws = (float*)d_ws;
  float* S0f = ws;             u32* S0u = (u32*)S0f;
  float* S1f = ws + SLOT;      u32* S1u = (u32*)S1f;
  float* S2f = ws + 2 * SLOT;  u32* S2u = (u32*)S2f;
  float* S3f = ws + 3 * SLOT;
  float* SBf = ws + 4 * SLOT;                       // (B,4,L) = 131072
  u32*   WP  = (u32*)(ws + 4 * SLOT + 131072);      // packed weights

  // 1. pack weights
  wprep_kernel<<<WTOT / 256, 256, 0, stream>>>(s1_win, s1_wout, lin_w, s2_win, s2_wout, WP);
  // 2. x (b,128,L) -> packed xT (M,128) @ S0u
  tpose_kernel<<<dim3(128, 4, B), 256, 0, stream>>>(x, S0u, 128, L);
  // 3. stage1 in-proj: -> xcpre1 @ S1f, z1 @ S1f+HALF
  mgemm_kernel<0><<<dim3(2, 256), 256, 0, stream>>>(
      S0u, WP + WOFF1, s1_bin, M, 256, 128, S1f, S1f + HALF, nullptr, 128, L);
  // 4. conv1 -> xc1 @ S2f, dt1 @ S2f+HALF, B/C @ SBf
  conv_proj_kernel<128, 8><<<dim3(256, B), 256, 0, stream>>>(
      S1f, s1_cw, s1_cb, s1_wx, s1_wdt, s1_bdt, S2f, S2f + HALF, SBf, L);
  // 5. scan1 -> y1 @ S0f
  scan_kernel<<<dim3(128, B), 256, 0, stream>>>(
      S2f + HALF, S2f, S1f + HALF, SBf, s1_alog, s1_dd, S0f, 128, L);
  // 6. y1 -> packed y1T @ S0u+HALF
  tpose_kernel<<<dim3(128, 4, B), 256, 0, stream>>>(S0f, S0u + HALF, 128, L);
  // 7. out-proj1 + LN -> act_mid packed @ S1u
  lgemm_kernel<128, 2><<<dim3(512), 256, 0, stream>>>(
      S0u + HALF, WP + WOFFO1, s1_lnw, s1_lnb, M, 128, S1u, nullptr, L);
  // 8. mid linear + silu -> act_lin packed @ S2u
  mgemm_kernel<1><<<dim3(2, 256), 256, 0, stream>>>(
      S1u, WP + WOFFL, lin_b, M, 256, 128, nullptr, nullptr, S2u, 0, L);
  // 9. stage2 in-proj: -> xcpre2 @ S0f, z2 @ S1f
  mgemm_kernel<0><<<dim3(4, 256), 256, 0, stream>>>(
      S2u, WP + WOFF2, s2_bin, M, 512, 256, S0f, S1f, nullptr, 256, L);
  // 10. conv2 -> xc2 @ S3f, dt2 @ S2f
  conv_proj_kernel<256, 16><<<dim3(256, B), 256, 0, stream>>>(
      S0f, s2_cw, s2_cb, s2_wx, s2_wdt, s2_bdt, S3f, S2f, SBf, L);
  // 11. scan2 -> y2 @ S0f
  scan_kernel<<<dim3(256, B), 256, 0, stream>>>(
      S2f, S3f, S1f, SBf, s2_alog, s2_dd, S0f, 256, L);
  // 12. y2 -> packed y2T @ S1u
  tpose_kernel<<<dim3(128, 8, B), 256, 0, stream>>>(S0f, S1u, 256, L);
  // 13. out-proj2 + LN -> d_out fp32 (b,256,64,64)
  lgemm_kernel<256, 3><<<dim3(512), 256, 0, stream>>>(
      S1u, WP + WOFFO2, s2_lnw, s2_lnb, M, 256, nullptr, out, L);
}

// Round 4
// 405.577 us; speedup vs baseline: 1.2910x; 1.0244x over previous
//
#include <hip/hip_runtime.h>
#include <math.h>

#define DEVI __device__ __forceinline__

typedef unsigned int u32;
typedef unsigned short u16;
typedef __attribute__((ext_vector_type(8))) __bf16 bf16x8;
typedef __attribute__((ext_vector_type(8))) u16 u16x8;
typedef __attribute__((ext_vector_type(4))) float f32x4;

DEVI float silu_f(float x) { return x * (1.0f / (1.0f + __expf(-x))); }
DEVI float softplus_f(float x) {
  return x > 0.0f ? x + log1pf(__expf(-x)) : log1pf(__expf(x));
}

DEVI u32 bf16_rne(float f) {
  u32 u = __float_as_uint(f);
  return (u + 0x7fffu + ((u >> 16) & 1u)) >> 16;
}
// packed split: high 16 bits = bf16(f), low 16 bits = bf16(f - hi)
DEVI u32 pack_hl(float f) {
  u32 h = bf16_rne(f);
  float hf = __uint_as_float(h << 16);
  u32 l = bf16_rne(f - hf);
  return (h << 16) | l;
}

DEVI void load16(float* r, const float* __restrict__ p) {
  const float4* q = (const float4*)p;
  float4 a = q[0], b = q[1], c = q[2], d = q[3];
  r[0]=a.x; r[1]=a.y; r[2]=a.z; r[3]=a.w;
  r[4]=b.x; r[5]=b.y; r[6]=b.z; r[7]=b.w;
  r[8]=c.x; r[9]=c.y; r[10]=c.z; r[11]=c.w;
  r[12]=d.x; r[13]=d.y; r[14]=d.z; r[15]=d.w;
}
DEVI void store16(float* __restrict__ p, const float* r) {
  float4* q = (float4*)p;
  q[0] = make_float4(r[0],r[1],r[2],r[3]);
  q[1] = make_float4(r[4],r[5],r[6],r[7]);
  q[2] = make_float4(r[8],r[9],r[10],r[11]);
  q[3] = make_float4(r[12],r[13],r[14],r[15]);
}

// split 8 packed u32 into hi/lo bf16 chunks and store 16B each to LDS
DEVI void stage_chunk(u16* __restrict__ ph, u16* __restrict__ pl, uint4 a, uint4 b) {
  u16x8 h, l;
  h[0] = (u16)(a.x >> 16); l[0] = (u16)a.x;
  h[1] = (u16)(a.y >> 16); l[1] = (u16)a.y;
  h[2] = (u16)(a.z >> 16); l[2] = (u16)a.z;
  h[3] = (u16)(a.w >> 16); l[3] = (u16)a.w;
  h[4] = (u16)(b.x >> 16); l[4] = (u16)b.x;
  h[5] = (u16)(b.y >> 16); l[5] = (u16)b.y;
  h[6] = (u16)(b.z >> 16); l[6] = (u16)b.z;
  h[7] = (u16)(b.w >> 16); l[7] = (u16)b.w;
  *(u16x8*)ph = h; *(u16x8*)pl = l;
}

// ---------------------------------------------------------------------------
// Weight prep: convert 5 fp32 weight matrices to packed hi/lo bf16 (u32).
// ---------------------------------------------------------------------------
constexpr int WN1 = 32768, WNO1 = 16384, WNL = 32768, WN2 = 131072, WNO2 = 65536;
constexpr int WOFF1 = 0, WOFFO1 = 32768, WOFFL = 49152, WOFF2 = 81920, WOFFO2 = 212992;
constexpr int WTOT = 278528;

__global__ __launch_bounds__(256) void wprep_kernel(
    const float* __restrict__ w1, const float* __restrict__ wo1,
    const float* __restrict__ wl, const float* __restrict__ w2,
    const float* __restrict__ wo2, u32* __restrict__ dst)
{
  int i = blockIdx.x * 256 + threadIdx.x;
  float v;
  if (i < WOFFO1)       v = w1[i];
  else if (i < WOFFL)   v = wo1[i - WOFFO1];
  else if (i < WOFF2)   v = wl[i - WOFFL];
  else if (i < WOFFO2)  v = w2[i - WOFF2];
  else                  v = wo2[i - WOFFO2];
  dst[i] = pack_hl(v);
}

// ---------------------------------------------------------------------------
// Transpose: fp32 (b, C, L) -> packed u32 (b*L, C)
// ---------------------------------------------------------------------------
__global__ __launch_bounds__(256) void tpose_kernel(
    const float* __restrict__ in, u32* __restrict__ out, int C, int L)
{
  __shared__ float t[32][33];
  const int l0 = blockIdx.x * 32, c0 = blockIdx.y * 32, b = blockIdx.z;
  const int tx = threadIdx.x & 31, ty = threadIdx.x >> 5;
  const float* src = in + ((long)b * C + c0) * L + l0;
  #pragma unroll
  for (int r = 0; r < 32; r += 8) t[ty + r][tx] = src[(long)(ty + r) * L + tx];
  __syncthreads();
  u32* dst = out + ((long)b * L + l0) * C + c0;
  #pragma unroll
  for (int r = 0; r < 32; r += 8) dst[(long)(ty + r) * C + tx] = pack_hl(t[tx][ty + r]);
}

// ---------------------------------------------------------------------------
// MFMA GEMM (bf16x3 split): C[m,n] = sum_k A[m,k]*W[n,k] (+bias)
// ---------------------------------------------------------------------------
template<int EPI>
__global__ __launch_bounds__(256) void mgemm_kernel(
    const u32* __restrict__ Ap, const u32* __restrict__ Wp,
    const float* __restrict__ bias, int M, int N, int K,
    float* __restrict__ out0, float* __restrict__ out1,
    u32* __restrict__ outp, int di, int L)
{
  __shared__ u16 Ah[128][40], Al[128][40], Bh[128][40], Bl[128][40];
  const int tid = threadIdx.x;
  const int wid = tid >> 6, lane = tid & 63;
  const int lm = lane & 15, lq = lane >> 4;
  const int m0 = blockIdx.y * 128, n0 = blockIdx.x * 128;
  const int wr = (wid >> 1) * 64, wn = (wid & 1) * 64;
  const int sr = tid >> 1;
  const int sc = (tid & 1) * 2;
  const int o0 = (((sc + 0) ^ (sr & 3)) * 8);
  const int o1 = (((sc + 1) ^ (sr & 3)) * 8);

  f32x4 acc[4][4];
  #pragma unroll
  for (int i = 0; i < 4; ++i)
    #pragma unroll
    for (int j = 0; j < 4; ++j)
      #pragma unroll
      for (int r = 0; r < 4; ++r) acc[i][j][r] = 0.0f;

  const u32* ga = Ap + (long)(m0 + sr) * K + sc * 8;
  const u32* gb = Wp + (long)(n0 + sr) * K + sc * 8;
  const int co = (lq ^ (lm & 3)) * 8;

  for (int k0 = 0; k0 < K; k0 += 32) {
    uint4 a0 = *(const uint4*)(ga + k0);
    uint4 a1 = *(const uint4*)(ga + k0 + 4);
    uint4 a2 = *(const uint4*)(ga + k0 + 8);
    uint4 a3 = *(const uint4*)(ga + k0 + 12);
    uint4 b0 = *(const uint4*)(gb + k0);
    uint4 b1 = *(const uint4*)(gb + k0 + 4);
    uint4 b2 = *(const uint4*)(gb + k0 + 8);
    uint4 b3 = *(const uint4*)(gb + k0 + 12);
    stage_chunk(&Ah[sr][o0], &Al[sr][o0], a0, a1);
    stage_chunk(&Ah[sr][o1], &Al[sr][o1], a2, a3);
    stage_chunk(&Bh[sr][o0], &Bl[sr][o0], b0, b1);
    stage_chunk(&Bh[sr][o1], &Bl[sr][o1], b2, b3);
    __syncthreads();

    bf16x8 fah[4], fal[4];
    #pragma unroll
    for (int i = 0; i < 4; ++i) {
      fah[i] = *(const bf16x8*)&Ah[wr + 16 * i + lm][co];
      fal[i] = *(const bf16x8*)&Al[wr + 16 * i + lm][co];
    }
    #pragma unroll
    for (int j = 0; j < 4; ++j) {
      bf16x8 fbh = *(const bf16x8*)&Bh[wn + 16 * j + lm][co];
      bf16x8 fbl = *(const bf16x8*)&Bl[wn + 16 * j + lm][co];
      #pragma unroll
      for (int i = 0; i < 4; ++i) {
        acc[i][j] = __builtin_amdgcn_mfma_f32_16x16x32_bf16(fah[i], fbh, acc[i][j], 0, 0, 0);
        acc[i][j] = __builtin_amdgcn_mfma_f32_16x16x32_bf16(fah[i], fbl, acc[i][j], 0, 0, 0);
        acc[i][j] = __builtin_amdgcn_mfma_f32_16x16x32_bf16(fal[i], fbh, acc[i][j], 0, 0, 0);
      }
    }
    __syncthreads();
  }

  if constexpr (EPI == 0) {
    const int b = m0 >> 12;
    const int lb = (m0 & 4095) + wr;
    #pragma unroll
    for (int j = 0; j < 4; ++j) {
      const int n = n0 + wn + 16 * j + lm;
      const float bv = bias[n];
      float* base = (n < di) ? out0 + ((long)b * di + n) * L
                             : out1 + ((long)b * di + (n - di)) * L;
      #pragma unroll
      for (int i = 0; i < 4; ++i) {
        const int l = lb + 16 * i + lq * 4;
        *(float4*)(base + l) = make_float4(acc[i][j][0] + bv, acc[i][j][1] + bv,
                                           acc[i][j][2] + bv, acc[i][j][3] + bv);
      }
    }
  } else {
    #pragma unroll
    for (int j = 0; j < 4; ++j) {
      const int n = n0 + wn + 16 * j + lm;
      const float bv = bias[n];
      #pragma unroll
      for (int i = 0; i < 4; ++i) {
        const long mg = m0 + wr + 16 * i + lq * 4;
        #pragma unroll
        for (int r = 0; r < 4; ++r)
          outp[(mg + r) * N + n] = pack_hl(silu_f(acc[i][j][r] + bv));
      }
    }
  }
}

// ---------------------------------------------------------------------------
// MFMA GEMM + fused LayerNorm over full width BN.
// ---------------------------------------------------------------------------
template<int BN, int EPI>
__global__ __launch_bounds__(256) void lgemm_kernel(
    const u32* __restrict__ Ap, const u32* __restrict__ Wp,
    const float* __restrict__ lnw, const float* __restrict__ lnb,
    int M, int K, u32* __restrict__ outp, float* __restrict__ outf, int L)
{
  constexpr int NT = BN / 64;
  __shared__ u16 Ah[64][40], Al[64][40], Bh[BN][40], Bl[BN][40];
  __shared__ float red[4][64];
  __shared__ float muS[64], rsS[64];

  const int tid = threadIdx.x;
  const int wid = tid >> 6, lane = tid & 63;
  const int lm = lane & 15, lq = lane >> 4;
  const int m0 = blockIdx.x * 64;
  const int wn = wid * (BN / 4);
  const int sa_r = tid >> 2, sa_c = tid & 3;
  const int sa_o = ((sa_c ^ (sa_r & 3)) * 8);
  const int co = (lq ^ (lm & 3)) * 8;

  f32x4 acc[4][NT];
  #pragma unroll
  for (int i = 0; i < 4; ++i)
    #pragma unroll
    for (int j = 0; j < NT; ++j)
      #pragma unroll
      for (int r = 0; r < 4; ++r) acc[i][j][r] = 0.0f;

  const u32* ga = Ap + (long)(m0 + sa_r) * K + sa_c * 8;

  for (int k0 = 0; k0 < K; k0 += 32) {
    uint4 a0 = *(const uint4*)(ga + k0);
    uint4 a1 = *(const uint4*)(ga + k0 + 4);
    stage_chunk(&Ah[sa_r][sa_o], &Al[sa_r][sa_o], a0, a1);
    #pragma unroll
    for (int it = 0; it < NT; ++it) {
      const int idx = tid + it * 256;
      const int n = idx >> 2, c = idx & 3;
      const u32* gw = Wp + (long)n * K + k0 + c * 8;
      uint4 b0 = *(const uint4*)gw;
      uint4 b1 = *(const uint4*)(gw + 4);
      const int o = ((c ^ (n & 3)) * 8);
      stage_chunk(&Bh[n][o], &Bl[n][o], b0, b1);
    }
    __syncthreads();

    bf16x8 fah[4], fal[4];
    #pragma unroll
    for (int i = 0; i < 4; ++i) {
      fah[i] = *(const bf16x8*)&Ah[16 * i + lm][co];
      fal[i] = *(const bf16x8*)&Al[16 * i + lm][co];
    }
    #pragma unroll
    for (int j = 0; j < NT; ++j) {
      bf16x8 fbh = *(const bf16x8*)&Bh[wn + 16 * j + lm][co];
      bf16x8 fbl = *(const bf16x8*)&Bl[wn + 16 * j + lm][co];
      #pragma unroll
      for (int i = 0; i < 4; ++i) {
        acc[i][j] = __builtin_amdgcn_mfma_f32_16x16x32_bf16(fah[i], fbh, acc[i][j], 0, 0, 0);
        acc[i][j] = __builtin_amdgcn_mfma_f32_16x16x32_bf16(fah[i], fbl, acc[i][j], 0, 0, 0);
        acc[i][j] = __builtin_amdgcn_mfma_f32_16x16x32_bf16(fal[i], fbh, acc[i][j], 0, 0, 0);
      }
    }
    __syncthreads();
  }

  // ---- fused LayerNorm over BN ----
  float part[4][4];
  #pragma unroll
  for (int i = 0; i < 4; ++i)
    #pragma unroll
    for (int r = 0; r < 4; ++r) {
      float s = 0.0f;
      #pragma unroll
      for (int j = 0; j < NT; ++j) s += acc[i][j][r];
      part[i][r] = s;
    }
  #pragma unroll
  for (int off = 1; off < 16; off <<= 1)
    #pragma unroll
    for (int i = 0; i < 4; ++i)
      #pragma unroll
      for (int r = 0; r < 4; ++r) part[i][r] += __shfl_xor(part[i][r], off);
  if (lm == 0) {
    #pragma unroll
    for (int i = 0; i < 4; ++i)
      #pragma unroll
      for (int r = 0; r < 4; ++r) red[wid][16 * i + 4 * lq + r] = part[i][r];
  }
  __syncthreads();
  if (tid < 64)
    muS[tid] = (red[0][tid] + red[1][tid] + red[2][tid] + red[3][tid]) * (1.0f / BN);
  __syncthreads();
  float mu_l[4][4];
  #pragma unroll
  for (int i = 0; i < 4; ++i)
    #pragma unroll
    for (int r = 0; r < 4; ++r) mu_l[i][r] = muS[16 * i + 4 * lq + r];
  #pragma unroll
  for (int i = 0; i < 4; ++i)
    #pragma unroll
    for (int r = 0; r < 4; ++r) {
      float s = 0.0f;
      #pragma unroll
      for (int j = 0; j < NT; ++j) {
        float d = acc[i][j][r] - mu_l[i][r];
        s = fmaf(d, d, s);
      }
      part[i][r] = s;
    }
  #pragma unroll
  for (int off = 1; off < 16; off <<= 1)
    #pragma unroll
    for (int i = 0; i < 4; ++i)
      #pragma unroll
      for (int r = 0; r < 4; ++r) part[i][r] += __shfl_xor(part[i][r], off);
  if (lm == 0) {
    #pragma unroll
    for (int i = 0; i < 4; ++i)
      #pragma unroll
      for (int r = 0; r < 4; ++r) red[wid][16 * i + 4 * lq + r] = part[i][r];
  }
  __syncthreads();
  if (tid < 64)
    rsS[tid] = rsqrtf((red[0][tid] + red[1][tid] + red[2][tid] + red[3][tid]) * (1.0f / BN)
                      + 1e-5f);
  __syncthreads();
  float rs_l[4][4];
  #pragma unroll
  for (int i = 0; i < 4; ++i)
    #pragma unroll
    for (int r = 0; r < 4; ++r) rs_l[i][r] = rsS[16 * i + 4 * lq + r];

  if constexpr (EPI == 2) {
    #pragma unroll
    for (int j = 0; j < NT; ++j) {
      const int n = wn + 16 * j + lm;
      const float g = lnw[n], bb = lnb[n];
      #pragma unroll
      for (int i = 0; i < 4; ++i) {
        #pragma unroll
        for (int r = 0; r < 4; ++r) {
          const long mg = m0 + 16 * i + 4 * lq + r;
          outp[mg * BN + n] =
              pack_hl((acc[i][j][r] - mu_l[i][r]) * rs_l[i][r] * g + bb);
        }
      }
    }
  } else {
    const int b = m0 >> 12;
    const int lb = m0 & 4095;
    #pragma unroll
    for (int j = 0; j < NT; ++j) {
      const int n = wn + 16 * j + lm;
      const float g = lnw[n], bb = lnb[n];
      #pragma unroll
      for (int i = 0; i < 4; ++i) {
        const int l = lb + 16 * i + 4 * lq;
        float4 v;
        v.x = (acc[i][j][0] - mu_l[i][0]) * rs_l[i][0] * g + bb;
        v.y = (acc[i][j][1] - mu_l[i][1]) * rs_l[i][1] * g + bb;
        v.z = (acc[i][j][2] - mu_l[i][2]) * rs_l[i][2] * g + bb;
        v.w = (acc[i][j][3] - mu_l[i][3]) * rs_l[i][3] * g + bb;
        *(float4*)(outf + ((long)b * BN + n) * L + l) = v;
      }
    }
  }
}

// ---------------------------------------------------------------------------
// Projection only: causal depthwise conv(4)+silu (into LDS, transposed) ->
// xds[j,l] = sum_ch wx[j][ch]*xc[ch][l] for j < R+4. Rows j<R go to xds_g
// (B,R,L), rows R..R+3 (B,C) go to bc_t. NO bulk xc/dt output — the scan
// kernel recomputes conv+silu and dt on the fly (saves 128 MB round trips).
// ---------------------------------------------------------------------------
template<int DI, int R>
__global__ __launch_bounds__(256) void proj_kernel(
    const float* __restrict__ xcpre_t,
    const float* __restrict__ cw, const float* __restrict__ cb,
    const float* __restrict__ wx,
    float* __restrict__ xds_g, float* __restrict__ bc_t, int L)
{
  constexpr int LT = 16;
  constexpr int NP = R + 4;            // proj rows: R dt-rank + 2 B + 2 C
  constexpr int NC = DI / 4;           // float4 chunks per position row
  __shared__ float xcT[LT][DI];        // [pos][rot-swizzled ch]

  const int tid = threadIdx.x;
  const int l0 = blockIdx.x * LT;
  const int bz = blockIdx.y;

  // ---- phase 1: conv + silu -> transposed/swizzled LDS ----
  if (tid < DI) {
    const int ch = tid;
    const long rowb = ((long)bz * DI + ch) * L;
    const float* __restrict__ src = xcpre_t + rowb + l0;
    float pre[LT + 3];
    if (l0 >= 3) {
      #pragma unroll
      for (int i = 0; i < LT + 3; ++i) pre[i] = src[i - 3];
    } else {
      #pragma unroll
      for (int i = 0; i < LT + 3; ++i) {
        const int l = l0 - 3 + i;
        pre[i] = (l >= 0) ? xcpre_t[rowb + l] : 0.0f;
      }
    }
    const float w0 = cw[ch*4+0], w1 = cw[ch*4+1], w2 = cw[ch*4+2], w3 = cw[ch*4+3];
    const float cbc = cb[ch];
    const int g = ch >> 2, c = ch & 3;
    #pragma unroll
    for (int i = 0; i < LT; ++i) {
      float s = cbc;
      s = fmaf(pre[i+0], w0, s);
      s = fmaf(pre[i+1], w1, s);
      s = fmaf(pre[i+2], w2, s);
      s = fmaf(pre[i+3], w3, s);
      xcT[i][(((g + i) & (NC - 1)) << 2) + c] = silu_f(s);
    }
  }
  __syncthreads();

  // ---- phase 2: out[j][i] = sum_ch wx[j][ch] * xc[ch][i] (float4 dot) ----
  for (int q = tid; q < NP * LT; q += 256) {
    const int j = q >> 4;
    const int i = q & 15;
    const float* __restrict__ wr = wx + (long)j * DI;
    float a0 = 0.0f, a1 = 0.0f, a2 = 0.0f, a3 = 0.0f;
    #pragma unroll 4
    for (int g = 0; g < NC; ++g) {
      const float4 xv = *(const float4*)&xcT[i][((g + i) & (NC - 1)) << 2];
      const float4 wv = *(const float4*)(wr + (g << 2));
      a0 = fmaf(xv.x, wv.x, a0);
      a1 = fmaf(xv.y, wv.y, a1);
      a2 = fmaf(xv.z, wv.z, a2);
      a3 = fmaf(xv.w, wv.w, a3);
    }
    const float val = (a0 + a1) + (a2 + a3);
    if (j < R) xds_g[((long)bz * R + j) * L + l0 + i] = val;
    else       bc_t[((long)bz * 4 + (j - R)) * L + l0 + i] = val;
  }
}

// ---------------------------------------------------------------------------
// Fused selective scan: recomputes conv+silu (from xcpre) and
// dt = softplus(xds @ wdt_row + bdt) on the fly (identical op order to the
// old conv_proj -> bit-identical), then block-parallel affine scan over L.
// One block per (ch, bz) row; 256 threads x 16 positions.
// ---------------------------------------------------------------------------
template<int R>
__global__ __launch_bounds__(256) void scan_kernel(
    const float* __restrict__ xcpre_t,
    const float* __restrict__ cw, const float* __restrict__ cb,
    const float* __restrict__ xds_g, const float* __restrict__ wdt,
    const float* __restrict__ bdt,
    const float* __restrict__ z_t, const float* __restrict__ bc_t,
    const float* __restrict__ alog, const float* __restrict__ dd,
    float* __restrict__ y_t, int di, int L)
{
  const int ch = blockIdx.x;
  const int bz = blockIdx.y;
  const int tid = threadIdx.x;
  const int lane = tid & 63;
  const int w = tid >> 6;
  const long rowb = ((long)bz * di + ch) * L;
  const long bcb = (long)bz * 4 * L;
  const int l0 = tid * 16;

  __shared__ float wsP0[4], wsQ0[4], wsP1[4], wsQ1[4];

  const float A0 = -__expf(alog[ch * 2 + 0]);
  const float A1 = -__expf(alog[ch * 2 + 1]);
  const float ddc = dd[ch];

  // ---- conv + silu -> xcv (identical order to proj phase 1) ----
  const float w0 = cw[ch*4+0], w1 = cw[ch*4+1], w2 = cw[ch*4+2], w3 = cw[ch*4+3];
  const float cbc = cb[ch];
  float cur[16];
  load16(cur, xcpre_t + rowb + l0);
  float p0 = 0.0f, p1 = 0.0f, p2 = 0.0f;
  if (tid > 0) {
    const float4 h = *(const float4*)(xcpre_t + rowb + l0 - 4);
    p0 = h.y; p1 = h.z; p2 = h.w;
  }
  float xcv[16];
  {
    float s;
    s = cbc; s = fmaf(p0, w0, s); s = fmaf(p1, w1, s); s = fmaf(p2, w2, s);
    s = fmaf(cur[0], w3, s); xcv[0] = silu_f(s);
    s = cbc; s = fmaf(p1, w0, s); s = fmaf(p2, w1, s); s = fmaf(cur[0], w2, s);
    s = fmaf(cur[1], w3, s); xcv[1] = silu_f(s);
    s = cbc; s = fmaf(p2, w0, s); s = fmaf(cur[0], w1, s); s = fmaf(cur[1], w2, s);
    s = fmaf(cur[2], w3, s); xcv[2] = silu_f(s);
    #pragma unroll
    for (int i = 3; i < 16; ++i) {
      s = cbc;
      s = fmaf(cur[i-3], w0, s);
      s = fmaf(cur[i-2], w1, s);
      s = fmaf(cur[i-1], w2, s);
      s = fmaf(cur[i],   w3, s);
      xcv[i] = silu_f(s);
    }
  }

  // ---- dt pre-activation: sd[i] = bdt + sum_j xds[j][l0+i]*wdt[ch][j] ----
  float wr[R];
  #pragma unroll
  for (int j = 0; j < R; ++j) wr[j] = wdt[ch * R + j];
  const float bv = bdt[ch];
  float sd[16];
  #pragma unroll
  for (int i = 0; i < 16; ++i) sd[i] = bv;
  const float* __restrict__ xp = xds_g + (long)bz * R * L + l0;
  #pragma unroll 2
  for (int j = 0; j < R; ++j) {
    const float wj = wr[j];
    const float4 x0 = *(const float4*)(xp + (long)j * L + 0);
    const float4 x1 = *(const float4*)(xp + (long)j * L + 4);
    const float4 x2 = *(const float4*)(xp + (long)j * L + 8);
    const float4 x3 = *(const float4*)(xp + (long)j * L + 12);
    sd[0]  = fmaf(x0.x, wj, sd[0]);  sd[1]  = fmaf(x0.y, wj, sd[1]);
    sd[2]  = fmaf(x0.z, wj, sd[2]);  sd[3]  = fmaf(x0.w, wj, sd[3]);
    sd[4]  = fmaf(x1.x, wj, sd[4]);  sd[5]  = fmaf(x1.y, wj, sd[5]);
    sd[6]  = fmaf(x1.z, wj, sd[6]);  sd[7]  = fmaf(x1.w, wj, sd[7]);
    sd[8]  = fmaf(x2.x, wj, sd[8]);  sd[9]  = fmaf(x2.y, wj, sd[9]);
    sd[10] = fmaf(x2.z, wj, sd[10]); sd[11] = fmaf(x2.w, wj, sd[11]);
    sd[12] = fmaf(x3.x, wj, sd[12]); sd[13] = fmaf(x3.y, wj, sd[13]);
    sd[14] = fmaf(x3.z, wj, sd[14]); sd[15] = fmaf(x3.w, wj, sd[15]);
  }

  // ---- local scan coefficients ----
  float t0[16], t1[16];
  load16(t0, bc_t + bcb + l0);
  load16(t1, bc_t + bcb + L + l0);

  float a0[16], a1[16], u0[16], u1[16];
  float P0 = 1.0f, Q0 = 0.0f, P1 = 1.0f, Q1 = 0.0f;
  #pragma unroll
  for (int i = 0; i < 16; ++i) {
    const float dt = softplus_f(sd[i]);
    const float dx = dt * xcv[i];
    a0[i] = __expf(dt * A0);
    a1[i] = __expf(dt * A1);
    u0[i] = dx * t0[i];
    u1[i] = dx * t1[i];
    Q0 = fmaf(a0[i], Q0, u0[i]); P0 *= a0[i];
    Q1 = fmaf(a1[i], Q1, u1[i]); P1 *= a1[i];
  }

  #pragma unroll
  for (int off = 1; off < 64; off <<= 1) {
    const float pp0 = __shfl_up(P0, off);
    const float qq0 = __shfl_up(Q0, off);
    const float pp1 = __shfl_up(P1, off);
    const float qq1 = __shfl_up(Q1, off);
    if (lane >= off) {
      Q0 = fmaf(P0, qq0, Q0); P0 *= pp0;
      Q1 = fmaf(P1, qq1, Q1); P1 *= pp1;
    }
  }
  if (lane == 63) { wsP0[w] = P0; wsQ0[w] = Q0; wsP1[w] = P1; wsQ1[w] = Q1; }
  __syncthreads();
  float eQ0 = 0.0f, eQ1 = 0.0f;
  for (int ww = 0; ww < w; ++ww) {
    eQ0 = fmaf(wsP0[ww], eQ0, wsQ0[ww]);
    eQ1 = fmaf(wsP1[ww], eQ1, wsQ1[ww]);
  }
  float pP0 = __shfl_up(P0, 1), pQ0 = __shfl_up(Q0, 1);
  float pP1 = __shfl_up(P1, 1), pQ1 = __shfl_up(Q1, 1);
  if (lane == 0) { pP0 = 1.0f; pQ0 = 0.0f; pP1 = 1.0f; pQ1 = 0.0f; }
  float h0 = fmaf(pP0, eQ0, pQ0);
  float h1 = fmaf(pP1, eQ1, pQ1);

  float c0[16], c1[16], zv[16], yv[16];
  load16(c0, bc_t + bcb + 2 * L + l0);
  load16(c1, bc_t + bcb + 3 * L + l0);
  load16(zv, z_t + rowb + l0);
  #pragma unroll
  for (int i = 0; i < 16; ++i) {
    h0 = fmaf(a0[i], h0, u0[i]);
    h1 = fmaf(a1[i], h1, u1[i]);
    const float y = fmaf(h0, c0[i], fmaf(h1, c1[i], ddc * xcv[i]));
    yv[i] = y * silu_f(zv[i]);
  }
  store16(y_t + rowb + l0, yv);
}

// ---------------------------------------------------------------------------
extern "C" void kernel_launch(void* const* d_in, const int* in_sizes, int n_in,
                              void* d_out, int out_size, void* d_ws, size_t ws_size,
                              hipStream_t stream)
{
  const float* x       = (const float*)d_in[0];
  const float* lin_w   = (const float*)d_in[1];
  const float* lin_b   = (const float*)d_in[2];
  const float* s1_win  = (const float*)d_in[3];
  const float* s1_bin  = (const float*)d_in[4];
  const float* s1_cw   = (const float*)d_in[5];
  const float* s1_cb   = (const float*)d_in[6];
  const float* s1_wx   = (const float*)d_in[7];
  const float* s1_wdt  = (const float*)d_in[8];
  const float* s1_bdt  = (const float*)d_in[9];
  const float* s1_alog = (const float*)d_in[10];
  const float* s1_dd   = (const float*)d_in[11];
  const float* s1_wout = (const float*)d_in[12];
  const float* s1_lnw  = (const float*)d_in[13];
  const float* s1_lnb  = (const float*)d_in[14];
  const float* s2_win  = (const float*)d_in[15];
  const float* s2_bin  = (const float*)d_in[16];
  const float* s2_cw   = (const float*)d_in[17];
  const float* s2_cb   = (const float*)d_in[18];
  const float* s2_wx   = (const float*)d_in[19];
  const float* s2_wdt  = (const float*)d_in[20];
  const float* s2_bdt  = (const float*)d_in[21];
  const float* s2_alog = (const float*)d_in[22];
  const float* s2_dd   = (const float*)d_in[23];
  const float* s2_wout = (const float*)d_in[24];
  const float* s2_lnw  = (const float*)d_in[25];
  const float* s2_lnb  = (const float*)d_in[26];
  float* out = (float*)d_out;

  const int B = 8, L = 4096, M = 32768;
  const long SLOT = 8L * 256 * 4096;   // 8388608 elems = 32 MB
  const long HALF = SLOT / 2;          // 16 MB
  float* ws = (float*)d_ws;
  float* S0f = ws;             u32* S0u = (u32*)S0f;
  float* S1f = ws + SLOT;      u32* S1u = (u32*)S1f;
  float* S2f = ws + 2 * SLOT;  u32* S2u = (u32*)S2f;
  float* SBf = ws + 3 * SLOT;                        // (B,4,L) = 131072
  float* XDS = ws + 3 * SLOT + 131072;               // (B,16,L) = 524288
  u32*   WP  = (u32*)(ws + 3 * SLOT + 131072 + 524288);  // packed weights

  // 1. pack weights
  wprep_kernel<<<WTOT / 256, 256, 0, stream>>>(s1_win, s1_wout, lin_w, s2_win, s2_wout, WP);
  // 2. x (b,128,L) -> packed xT (M,128) @ S0u
  tpose_kernel<<<dim3(128, 4, B), 256, 0, stream>>>(x, S0u, 128, L);
  // 3. stage1 in-proj: -> xcpre1 @ S1f, z1 @ S1f+HALF
  mgemm_kernel<0><<<dim3(2, 256), 256, 0, stream>>>(
      S0u, WP + WOFF1, s1_bin, M, 256, 128, S1f, S1f + HALF, nullptr, 128, L);
  // 4. proj1: xcpre1 -> xds @ XDS, B/C @ SBf
  proj_kernel<128, 8><<<dim3(256, B), 256, 0, stream>>>(
      S1f, s1_cw, s1_cb, s1_wx, XDS, SBf, L);
  // 5. fused scan1 (conv+dt recompute) -> y1 @ S0f
  scan_kernel<8><<<dim3(128, B), 256, 0, stream>>>(
      S1f, s1_cw, s1_cb, XDS, s1_wdt, s1_bdt, S1f + HALF, SBf,
      s1_alog, s1_dd, S0f, 128, L);
  // 6. y1 -> packed y1T @ S0u+HALF
  tpose_kernel<<<dim3(128, 4, B), 256, 0, stream>>>(S0f, S0u + HALF, 128, L);
  // 7. out-proj1 + LN -> act_mid packed @ S1u
  lgemm_kernel<128, 2><<<dim3(512), 256, 0, stream>>>(
      S0u + HALF, WP + WOFFO1, s1_lnw, s1_lnb, M, 128, S1u, nullptr, L);
  // 8. mid linear + silu -> act_lin packed @ S2u
  mgemm_kernel<1><<<dim3(2, 256), 256, 0, stream>>>(
      S1u, WP + WOFFL, lin_b, M, 256, 128, nullptr, nullptr, S2u, 0, L);
  // 9. stage2 in-proj: -> xcpre2 @ S0f, z2 @ S1f
  mgemm_kernel<0><<<dim3(4, 256), 256, 0, stream>>>(
      S2u, WP + WOFF2, s2_bin, M, 512, 256, S0f, S1f, nullptr, 256, L);
  // 10. proj2: xcpre2 -> xds @ XDS, B/C @ SBf
  proj_kernel<256, 16><<<dim3(256, B), 256, 0, stream>>>(
      S0f, s2_cw, s2_cb, s2_wx, XDS, SBf, L);
  // 11. fused scan2 -> y2 @ S2f
  scan_kernel<16><<<dim3(256, B), 256, 0, stream>>>(
      S0f, s2_cw, s2_cb, XDS, s2_wdt, s2_bdt, S1f, SBf,
      s2_alog, s2_dd, S2f, 256, L);
  // 12. y2 -> packed y2T @ S1u
  tpose_kernel<<<dim3(128, 8, B), 256, 0, stream>>>(S2f, S1u, 256, L);
  // 13. out-proj2 + LN -> d_out fp32 (b,256,64,64)
  lgemm_kernel<256, 3><<<dim3(512), 256, 0, stream>>>(
      S1u, WP + WOFFO2, s2_lnw, s2_lnb, M, 256, nullptr, out, L);
}

// Round 5
// 383.211 us; speedup vs baseline: 1.3663x; 1.0584x over previous
//
#include <hip/hip_runtime.h>
#include <math.h>

#define DEVI __device__ __forceinline__

typedef unsigned int u32;
typedef unsigned short u16;
typedef __attribute__((ext_vector_type(8))) __bf16 bf16x8;
typedef __attribute__((ext_vector_type(8))) u16 u16x8;
typedef __attribute__((ext_vector_type(4))) float f32x4;

DEVI float rcp_f(float x) { return __builtin_amdgcn_rcpf(x); }
DEVI float silu_f(float x) { return x * rcp_f(1.0f + __expf(-x)); }
// fast softplus: max(x,0) + log(1+exp(-|x|)); abs err < 1e-7, no libm log1pf,
// no divergent ternary (old version emitted both branches: 2 exp + 2 log1p).
DEVI float softplus_f(float x) {
  return fmaxf(x, 0.0f) + __logf(1.0f + __expf(-fabsf(x)));
}

DEVI u32 bf16_rne(float f) {
  u32 u = __float_as_uint(f);
  return (u + 0x7fffu + ((u >> 16) & 1u)) >> 16;
}
// packed split: high 16 bits = bf16(f), low 16 bits = bf16(f - hi)
DEVI u32 pack_hl(float f) {
  u32 h = bf16_rne(f);
  float hf = __uint_as_float(h << 16);
  u32 l = bf16_rne(f - hf);
  return (h << 16) | l;
}

DEVI void load16(float* r, const float* __restrict__ p) {
  const float4* q = (const float4*)p;
  float4 a = q[0], b = q[1], c = q[2], d = q[3];
  r[0]=a.x; r[1]=a.y; r[2]=a.z; r[3]=a.w;
  r[4]=b.x; r[5]=b.y; r[6]=b.z; r[7]=b.w;
  r[8]=c.x; r[9]=c.y; r[10]=c.z; r[11]=c.w;
  r[12]=d.x; r[13]=d.y; r[14]=d.z; r[15]=d.w;
}
DEVI void store16(float* __restrict__ p, const float* r) {
  float4* q = (float4*)p;
  q[0] = make_float4(r[0],r[1],r[2],r[3]);
  q[1] = make_float4(r[4],r[5],r[6],r[7]);
  q[2] = make_float4(r[8],r[9],r[10],r[11]);
  q[3] = make_float4(r[12],r[13],r[14],r[15]);
}

// split 8 packed u32 into hi/lo bf16 chunks and store 16B each to LDS
DEVI void stage_chunk(u16* __restrict__ ph, u16* __restrict__ pl, uint4 a, uint4 b) {
  u16x8 h, l;
  h[0] = (u16)(a.x >> 16); l[0] = (u16)a.x;
  h[1] = (u16)(a.y >> 16); l[1] = (u16)a.y;
  h[2] = (u16)(a.z >> 16); l[2] = (u16)a.z;
  h[3] = (u16)(a.w >> 16); l[3] = (u16)a.w;
  h[4] = (u16)(b.x >> 16); l[4] = (u16)b.x;
  h[5] = (u16)(b.y >> 16); l[5] = (u16)b.y;
  h[6] = (u16)(b.z >> 16); l[6] = (u16)b.z;
  h[7] = (u16)(b.w >> 16); l[7] = (u16)b.w;
  *(u16x8*)ph = h; *(u16x8*)pl = l;
}

// ---------------------------------------------------------------------------
// Weight prep: convert 5 fp32 weight matrices to packed hi/lo bf16 (u32).
// ---------------------------------------------------------------------------
constexpr int WN1 = 32768, WNO1 = 16384, WNL = 32768, WN2 = 131072, WNO2 = 65536;
constexpr int WOFF1 = 0, WOFFO1 = 32768, WOFFL = 49152, WOFF2 = 81920, WOFFO2 = 212992;
constexpr int WTOT = 278528;

__global__ __launch_bounds__(256) void wprep_kernel(
    const float* __restrict__ w1, const float* __restrict__ wo1,
    const float* __restrict__ wl, const float* __restrict__ w2,
    const float* __restrict__ wo2, u32* __restrict__ dst)
{
  int i = blockIdx.x * 256 + threadIdx.x;
  float v;
  if (i < WOFFO1)       v = w1[i];
  else if (i < WOFFL)   v = wo1[i - WOFFO1];
  else if (i < WOFF2)   v = wl[i - WOFFL];
  else if (i < WOFFO2)  v = w2[i - WOFF2];
  else                  v = wo2[i - WOFFO2];
  dst[i] = pack_hl(v);
}

// ---------------------------------------------------------------------------
// Transpose: fp32 (b, C, L) -> packed u32 (b*L, C)
// ---------------------------------------------------------------------------
__global__ __launch_bounds__(256) void tpose_kernel(
    const float* __restrict__ in, u32* __restrict__ out, int C, int L)
{
  __shared__ float t[32][33];
  const int l0 = blockIdx.x * 32, c0 = blockIdx.y * 32, b = blockIdx.z;
  const int tx = threadIdx.x & 31, ty = threadIdx.x >> 5;
  const float* src = in + ((long)b * C + c0) * L + l0;
  #pragma unroll
  for (int r = 0; r < 32; r += 8) t[ty + r][tx] = src[(long)(ty + r) * L + tx];
  __syncthreads();
  u32* dst = out + ((long)b * L + l0) * C + c0;
  #pragma unroll
  for (int r = 0; r < 32; r += 8) dst[(long)(ty + r) * C + tx] = pack_hl(t[tx][ty + r]);
}

// ---------------------------------------------------------------------------
// MFMA GEMM (bf16x3 split): C[m,n] = sum_k A[m,k]*W[n,k] (+bias)
// ---------------------------------------------------------------------------
template<int EPI>
__global__ __launch_bounds__(256) void mgemm_kernel(
    const u32* __restrict__ Ap, const u32* __restrict__ Wp,
    const float* __restrict__ bias, int M, int N, int K,
    float* __restrict__ out0, float* __restrict__ out1,
    u32* __restrict__ outp, int di, int L)
{
  __shared__ u16 Ah[128][40], Al[128][40], Bh[128][40], Bl[128][40];
  const int tid = threadIdx.x;
  const int wid = tid >> 6, lane = tid & 63;
  const int lm = lane & 15, lq = lane >> 4;
  const int m0 = blockIdx.y * 128, n0 = blockIdx.x * 128;
  const int wr = (wid >> 1) * 64, wn = (wid & 1) * 64;
  const int sr = tid >> 1;
  const int sc = (tid & 1) * 2;
  const int o0 = (((sc + 0) ^ (sr & 3)) * 8);
  const int o1 = (((sc + 1) ^ (sr & 3)) * 8);

  f32x4 acc[4][4];
  #pragma unroll
  for (int i = 0; i < 4; ++i)
    #pragma unroll
    for (int j = 0; j < 4; ++j)
      #pragma unroll
      for (int r = 0; r < 4; ++r) acc[i][j][r] = 0.0f;

  const u32* ga = Ap + (long)(m0 + sr) * K + sc * 8;
  const u32* gb = Wp + (long)(n0 + sr) * K + sc * 8;
  const int co = (lq ^ (lm & 3)) * 8;

  for (int k0 = 0; k0 < K; k0 += 32) {
    uint4 a0 = *(const uint4*)(ga + k0);
    uint4 a1 = *(const uint4*)(ga + k0 + 4);
    uint4 a2 = *(const uint4*)(ga + k0 + 8);
    uint4 a3 = *(const uint4*)(ga + k0 + 12);
    uint4 b0 = *(const uint4*)(gb + k0);
    uint4 b1 = *(const uint4*)(gb + k0 + 4);
    uint4 b2 = *(const uint4*)(gb + k0 + 8);
    uint4 b3 = *(const uint4*)(gb + k0 + 12);
    stage_chunk(&Ah[sr][o0], &Al[sr][o0], a0, a1);
    stage_chunk(&Ah[sr][o1], &Al[sr][o1], a2, a3);
    stage_chunk(&Bh[sr][o0], &Bl[sr][o0], b0, b1);
    stage_chunk(&Bh[sr][o1], &Bl[sr][o1], b2, b3);
    __syncthreads();

    bf16x8 fah[4], fal[4];
    #pragma unroll
    for (int i = 0; i < 4; ++i) {
      fah[i] = *(const bf16x8*)&Ah[wr + 16 * i + lm][co];
      fal[i] = *(const bf16x8*)&Al[wr + 16 * i + lm][co];
    }
    #pragma unroll
    for (int j = 0; j < 4; ++j) {
      bf16x8 fbh = *(const bf16x8*)&Bh[wn + 16 * j + lm][co];
      bf16x8 fbl = *(const bf16x8*)&Bl[wn + 16 * j + lm][co];
      #pragma unroll
      for (int i = 0; i < 4; ++i) {
        acc[i][j] = __builtin_amdgcn_mfma_f32_16x16x32_bf16(fah[i], fbh, acc[i][j], 0, 0, 0);
        acc[i][j] = __builtin_amdgcn_mfma_f32_16x16x32_bf16(fah[i], fbl, acc[i][j], 0, 0, 0);
        acc[i][j] = __builtin_amdgcn_mfma_f32_16x16x32_bf16(fal[i], fbh, acc[i][j], 0, 0, 0);
      }
    }
    __syncthreads();
  }

  if constexpr (EPI == 0) {
    const int b = m0 >> 12;
    const int lb = (m0 & 4095) + wr;
    #pragma unroll
    for (int j = 0; j < 4; ++j) {
      const int n = n0 + wn + 16 * j + lm;
      const float bv = bias[n];
      float* base = (n < di) ? out0 + ((long)b * di + n) * L
                             : out1 + ((long)b * di + (n - di)) * L;
      #pragma unroll
      for (int i = 0; i < 4; ++i) {
        const int l = lb + 16 * i + lq * 4;
        *(float4*)(base + l) = make_float4(acc[i][j][0] + bv, acc[i][j][1] + bv,
                                           acc[i][j][2] + bv, acc[i][j][3] + bv);
      }
    }
  } else {
    #pragma unroll
    for (int j = 0; j < 4; ++j) {
      const int n = n0 + wn + 16 * j + lm;
      const float bv = bias[n];
      #pragma unroll
      for (int i = 0; i < 4; ++i) {
        const long mg = m0 + wr + 16 * i + lq * 4;
        #pragma unroll
        for (int r = 0; r < 4; ++r)
          outp[(mg + r) * N + n] = pack_hl(silu_f(acc[i][j][r] + bv));
      }
    }
  }
}

// ---------------------------------------------------------------------------
// MFMA GEMM + fused LayerNorm over full width BN.
// ---------------------------------------------------------------------------
template<int BN, int EPI>
__global__ __launch_bounds__(256) void lgemm_kernel(
    const u32* __restrict__ Ap, const u32* __restrict__ Wp,
    const float* __restrict__ lnw, const float* __restrict__ lnb,
    int M, int K, u32* __restrict__ outp, float* __restrict__ outf, int L)
{
  constexpr int NT = BN / 64;
  __shared__ u16 Ah[64][40], Al[64][40], Bh[BN][40], Bl[BN][40];
  __shared__ float red[4][64];
  __shared__ float muS[64], rsS[64];

  const int tid = threadIdx.x;
  const int wid = tid >> 6, lane = tid & 63;
  const int lm = lane & 15, lq = lane >> 4;
  const int m0 = blockIdx.x * 64;
  const int wn = wid * (BN / 4);
  const int sa_r = tid >> 2, sa_c = tid & 3;
  const int sa_o = ((sa_c ^ (sa_r & 3)) * 8);
  const int co = (lq ^ (lm & 3)) * 8;

  f32x4 acc[4][NT];
  #pragma unroll
  for (int i = 0; i < 4; ++i)
    #pragma unroll
    for (int j = 0; j < NT; ++j)
      #pragma unroll
      for (int r = 0; r < 4; ++r) acc[i][j][r] = 0.0f;

  const u32* ga = Ap + (long)(m0 + sa_r) * K + sa_c * 8;

  for (int k0 = 0; k0 < K; k0 += 32) {
    uint4 a0 = *(const uint4*)(ga + k0);
    uint4 a1 = *(const uint4*)(ga + k0 + 4);
    stage_chunk(&Ah[sa_r][sa_o], &Al[sa_r][sa_o], a0, a1);
    #pragma unroll
    for (int it = 0; it < NT; ++it) {
      const int idx = tid + it * 256;
      const int n = idx >> 2, c = idx & 3;
      const u32* gw = Wp + (long)n * K + k0 + c * 8;
      uint4 b0 = *(const uint4*)gw;
      uint4 b1 = *(const uint4*)(gw + 4);
      const int o = ((c ^ (n & 3)) * 8);
      stage_chunk(&Bh[n][o], &Bl[n][o], b0, b1);
    }
    __syncthreads();

    bf16x8 fah[4], fal[4];
    #pragma unroll
    for (int i = 0; i < 4; ++i) {
      fah[i] = *(const bf16x8*)&Ah[16 * i + lm][co];
      fal[i] = *(const bf16x8*)&Al[16 * i + lm][co];
    }
    #pragma unroll
    for (int j = 0; j < NT; ++j) {
      bf16x8 fbh = *(const bf16x8*)&Bh[wn + 16 * j + lm][co];
      bf16x8 fbl = *(const bf16x8*)&Bl[wn + 16 * j + lm][co];
      #pragma unroll
      for (int i = 0; i < 4; ++i) {
        acc[i][j] = __builtin_amdgcn_mfma_f32_16x16x32_bf16(fah[i], fbh, acc[i][j], 0, 0, 0);
        acc[i][j] = __builtin_amdgcn_mfma_f32_16x16x32_bf16(fah[i], fbl, acc[i][j], 0, 0, 0);
        acc[i][j] = __builtin_amdgcn_mfma_f32_16x16x32_bf16(fal[i], fbh, acc[i][j], 0, 0, 0);
      }
    }
    __syncthreads();
  }

  // ---- fused LayerNorm over BN ----
  float part[4][4];
  #pragma unroll
  for (int i = 0; i < 4; ++i)
    #pragma unroll
    for (int r = 0; r < 4; ++r) {
      float s = 0.0f;
      #pragma unroll
      for (int j = 0; j < NT; ++j) s += acc[i][j][r];
      part[i][r] = s;
    }
  #pragma unroll
  for (int off = 1; off < 16; off <<= 1)
    #pragma unroll
    for (int i = 0; i < 4; ++i)
      #pragma unroll
      for (int r = 0; r < 4; ++r) part[i][r] += __shfl_xor(part[i][r], off);
  if (lm == 0) {
    #pragma unroll
    for (int i = 0; i < 4; ++i)
      #pragma unroll
      for (int r = 0; r < 4; ++r) red[wid][16 * i + 4 * lq + r] = part[i][r];
  }
  __syncthreads();
  if (tid < 64)
    muS[tid] = (red[0][tid] + red[1][tid] + red[2][tid] + red[3][tid]) * (1.0f / BN);
  __syncthreads();
  float mu_l[4][4];
  #pragma unroll
  for (int i = 0; i < 4; ++i)
    #pragma unroll
    for (int r = 0; r < 4; ++r) mu_l[i][r] = muS[16 * i + 4 * lq + r];
  #pragma unroll
  for (int i = 0; i < 4; ++i)
    #pragma unroll
    for (int r = 0; r < 4; ++r) {
      float s = 0.0f;
      #pragma unroll
      for (int j = 0; j < NT; ++j) {
        float d = acc[i][j][r] - mu_l[i][r];
        s = fmaf(d, d, s);
      }
      part[i][r] = s;
    }
  #pragma unroll
  for (int off = 1; off < 16; off <<= 1)
    #pragma unroll
    for (int i = 0; i < 4; ++i)
      #pragma unroll
      for (int r = 0; r < 4; ++r) part[i][r] += __shfl_xor(part[i][r], off);
  if (lm == 0) {
    #pragma unroll
    for (int i = 0; i < 4; ++i)
      #pragma unroll
      for (int r = 0; r < 4; ++r) red[wid][16 * i + 4 * lq + r] = part[i][r];
  }
  __syncthreads();
  if (tid < 64)
    rsS[tid] = rsqrtf((red[0][tid] + red[1][tid] + red[2][tid] + red[3][tid]) * (1.0f / BN)
                      + 1e-5f);
  __syncthreads();
  float rs_l[4][4];
  #pragma unroll
  for (int i = 0; i < 4; ++i)
    #pragma unroll
    for (int r = 0; r < 4; ++r) rs_l[i][r] = rsS[16 * i + 4 * lq + r];

  if constexpr (EPI == 2) {
    #pragma unroll
    for (int j = 0; j < NT; ++j) {
      const int n = wn + 16 * j + lm;
      const float g = lnw[n], bb = lnb[n];
      #pragma unroll
      for (int i = 0; i < 4; ++i) {
        #pragma unroll
        for (int r = 0; r < 4; ++r) {
          const long mg = m0 + 16 * i + 4 * lq + r;
          outp[mg * BN + n] =
              pack_hl((acc[i][j][r] - mu_l[i][r]) * rs_l[i][r] * g + bb);
        }
      }
    }
  } else {
    const int b = m0 >> 12;
    const int lb = m0 & 4095;
    #pragma unroll
    for (int j = 0; j < NT; ++j) {
      const int n = wn + 16 * j + lm;
      const float g = lnw[n], bb = lnb[n];
      #pragma unroll
      for (int i = 0; i < 4; ++i) {
        const int l = lb + 16 * i + 4 * lq;
        float4 v;
        v.x = (acc[i][j][0] - mu_l[i][0]) * rs_l[i][0] * g + bb;
        v.y = (acc[i][j][1] - mu_l[i][1]) * rs_l[i][1] * g + bb;
        v.z = (acc[i][j][2] - mu_l[i][2]) * rs_l[i][2] * g + bb;
        v.w = (acc[i][j][3] - mu_l[i][3]) * rs_l[i][3] * g + bb;
        *(float4*)(outf + ((long)b * BN + n) * L + l) = v;
      }
    }
  }
}

// ---------------------------------------------------------------------------
// Projection only: causal depthwise conv(4)+silu (into LDS, transposed) ->
// xds[j,l] = sum_ch wx[j][ch]*xc[ch][l] for j < R+4. Rows j<R go to xds_g
// (B,R,L), rows R..R+3 (B,C) go to bc_t. NO bulk xc/dt output — the scan
// kernel recomputes conv+silu and dt on the fly (saves 128 MB round trips).
// ---------------------------------------------------------------------------
template<int DI, int R>
__global__ __launch_bounds__(256) void proj_kernel(
    const float* __restrict__ xcpre_t,
    const float* __restrict__ cw, const float* __restrict__ cb,
    const float* __restrict__ wx,
    float* __restrict__ xds_g, float* __restrict__ bc_t, int L)
{
  constexpr int LT = 16;
  constexpr int NP = R + 4;            // proj rows: R dt-rank + 2 B + 2 C
  constexpr int NC = DI / 4;           // float4 chunks per position row
  __shared__ float xcT[LT][DI];        // [pos][rot-swizzled ch]

  const int tid = threadIdx.x;
  const int l0 = blockIdx.x * LT;
  const int bz = blockIdx.y;

  // ---- phase 1: conv + silu -> transposed/swizzled LDS ----
  if (tid < DI) {
    const int ch = tid;
    const long rowb = ((long)bz * DI + ch) * L;
    const float* __restrict__ src = xcpre_t + rowb + l0;
    float pre[LT + 3];
    if (l0 >= 3) {
      #pragma unroll
      for (int i = 0; i < LT + 3; ++i) pre[i] = src[i - 3];
    } else {
      #pragma unroll
      for (int i = 0; i < LT + 3; ++i) {
        const int l = l0 - 3 + i;
        pre[i] = (l >= 0) ? xcpre_t[rowb + l] : 0.0f;
      }
    }
    const float w0 = cw[ch*4+0], w1 = cw[ch*4+1], w2 = cw[ch*4+2], w3 = cw[ch*4+3];
    const float cbc = cb[ch];
    const int g = ch >> 2, c = ch & 3;
    #pragma unroll
    for (int i = 0; i < LT; ++i) {
      float s = cbc;
      s = fmaf(pre[i+0], w0, s);
      s = fmaf(pre[i+1], w1, s);
      s = fmaf(pre[i+2], w2, s);
      s = fmaf(pre[i+3], w3, s);
      xcT[i][(((g + i) & (NC - 1)) << 2) + c] = silu_f(s);
    }
  }
  __syncthreads();

  // ---- phase 2: out[j][i] = sum_ch wx[j][ch] * xc[ch][i] (float4 dot) ----
  for (int q = tid; q < NP * LT; q += 256) {
    const int j = q >> 4;
    const int i = q & 15;
    const float* __restrict__ wr = wx + (long)j * DI;
    float a0 = 0.0f, a1 = 0.0f, a2 = 0.0f, a3 = 0.0f;
    #pragma unroll 4
    for (int g = 0; g < NC; ++g) {
      const float4 xv = *(const float4*)&xcT[i][((g + i) & (NC - 1)) << 2];
      const float4 wv = *(const float4*)(wr + (g << 2));
      a0 = fmaf(xv.x, wv.x, a0);
      a1 = fmaf(xv.y, wv.y, a1);
      a2 = fmaf(xv.z, wv.z, a2);
      a3 = fmaf(xv.w, wv.w, a3);
    }
    const float val = (a0 + a1) + (a2 + a3);
    if (j < R) xds_g[((long)bz * R + j) * L + l0 + i] = val;
    else       bc_t[((long)bz * 4 + (j - R)) * L + l0 + i] = val;
  }
}

// ---------------------------------------------------------------------------
// Fused selective scan: recomputes conv+silu (from xcpre) and
// dt = softplus(xds @ wdt_row + bdt) on the fly (identical op order ->
// bit-identical), then block-parallel affine scan over L.
// v6: __launch_bounds__(256,4) (VGPR headroom, no scratch spills); t/c/z
// consumed in 4-element float4 chunks to cap live registers (~100).
// ---------------------------------------------------------------------------
template<int R>
__global__ __launch_bounds__(256, 4) void scan_kernel(
    const float* __restrict__ xcpre_t,
    const float* __restrict__ cw, const float* __restrict__ cb,
    const float* __restrict__ xds_g, const float* __restrict__ wdt,
    const float* __restrict__ bdt,
    const float* __restrict__ z_t, const float* __restrict__ bc_t,
    const float* __restrict__ alog, const float* __restrict__ dd,
    float* __restrict__ y_t, int di, int L)
{
  const int ch = blockIdx.x;
  const int bz = blockIdx.y;
  const int tid = threadIdx.x;
  const int lane = tid & 63;
  const int w = tid >> 6;
  const long rowb = ((long)bz * di + ch) * L;
  const long bcb = (long)bz * 4 * L;
  const int l0 = tid * 16;

  __shared__ float wsP0[4], wsQ0[4], wsP1[4], wsQ1[4];

  const float A0 = -__expf(alog[ch * 2 + 0]);
  const float A1 = -__expf(alog[ch * 2 + 1]);
  const float ddc = dd[ch];

  // ---- conv + silu -> xcv (identical order to proj phase 1) ----
  const float w0 = cw[ch*4+0], w1 = cw[ch*4+1], w2 = cw[ch*4+2], w3 = cw[ch*4+3];
  const float cbc = cb[ch];
  float cur[16];
  load16(cur, xcpre_t + rowb + l0);
  float p0 = 0.0f, p1 = 0.0f, p2 = 0.0f;
  if (tid > 0) {
    const float4 h = *(const float4*)(xcpre_t + rowb + l0 - 4);
    p0 = h.y; p1 = h.z; p2 = h.w;
  }
  float xcv[16];
  {
    float s;
    s = cbc; s = fmaf(p0, w0, s); s = fmaf(p1, w1, s); s = fmaf(p2, w2, s);
    s = fmaf(cur[0], w3, s); xcv[0] = silu_f(s);
    s = cbc; s = fmaf(p1, w0, s); s = fmaf(p2, w1, s); s = fmaf(cur[0], w2, s);
    s = fmaf(cur[1], w3, s); xcv[1] = silu_f(s);
    s = cbc; s = fmaf(p2, w0, s); s = fmaf(cur[0], w1, s); s = fmaf(cur[1], w2, s);
    s = fmaf(cur[2], w3, s); xcv[2] = silu_f(s);
    #pragma unroll
    for (int i = 3; i < 16; ++i) {
      s = cbc;
      s = fmaf(cur[i-3], w0, s);
      s = fmaf(cur[i-2], w1, s);
      s = fmaf(cur[i-1], w2, s);
      s = fmaf(cur[i],   w3, s);
      xcv[i] = silu_f(s);
    }
  }

  // ---- dt pre-activation: sd[i] = bdt + sum_j xds[j][l0+i]*wdt[ch][j] ----
  float wr[R];
  #pragma unroll
  for (int j = 0; j < R; ++j) wr[j] = wdt[ch * R + j];
  const float bv = bdt[ch];
  float sd[16];
  #pragma unroll
  for (int i = 0; i < 16; ++i) sd[i] = bv;
  const float* __restrict__ xp = xds_g + (long)bz * R * L + l0;
  #pragma unroll 2
  for (int j = 0; j < R; ++j) {
    const float wj = wr[j];
    const float4 x0 = *(const float4*)(xp + (long)j * L + 0);
    const float4 x1 = *(const float4*)(xp + (long)j * L + 4);
    const float4 x2 = *(const float4*)(xp + (long)j * L + 8);
    const float4 x3 = *(const float4*)(xp + (long)j * L + 12);
    sd[0]  = fmaf(x0.x, wj, sd[0]);  sd[1]  = fmaf(x0.y, wj, sd[1]);
    sd[2]  = fmaf(x0.z, wj, sd[2]);  sd[3]  = fmaf(x0.w, wj, sd[3]);
    sd[4]  = fmaf(x1.x, wj, sd[4]);  sd[5]  = fmaf(x1.y, wj, sd[5]);
    sd[6]  = fmaf(x1.z, wj, sd[6]);  sd[7]  = fmaf(x1.w, wj, sd[7]);
    sd[8]  = fmaf(x2.x, wj, sd[8]);  sd[9]  = fmaf(x2.y, wj, sd[9]);
    sd[10] = fmaf(x2.z, wj, sd[10]); sd[11] = fmaf(x2.w, wj, sd[11]);
    sd[12] = fmaf(x3.x, wj, sd[12]); sd[13] = fmaf(x3.y, wj, sd[13]);
    sd[14] = fmaf(x3.z, wj, sd[14]); sd[15] = fmaf(x3.w, wj, sd[15]);
  }

  // ---- local scan coefficients (t0/t1 consumed in float4 chunks) ----
  float a0[16], a1[16], u0[16], u1[16];
  float P0 = 1.0f, Q0 = 0.0f, P1 = 1.0f, Q1 = 0.0f;
  #pragma unroll
  for (int c4 = 0; c4 < 4; ++c4) {
    const float4 t0c = *(const float4*)(bc_t + bcb + l0 + c4 * 4);
    const float4 t1c = *(const float4*)(bc_t + bcb + L + l0 + c4 * 4);
    const float t0a[4] = {t0c.x, t0c.y, t0c.z, t0c.w};
    const float t1a[4] = {t1c.x, t1c.y, t1c.z, t1c.w};
    #pragma unroll
    for (int i2 = 0; i2 < 4; ++i2) {
      const int i = c4 * 4 + i2;
      const float dt = softplus_f(sd[i]);
      const float dx = dt * xcv[i];
      a0[i] = __expf(dt * A0);
      a1[i] = __expf(dt * A1);
      u0[i] = dx * t0a[i2];
      u1[i] = dx * t1a[i2];
      Q0 = fmaf(a0[i], Q0, u0[i]); P0 *= a0[i];
      Q1 = fmaf(a1[i], Q1, u1[i]); P1 *= a1[i];
    }
  }

  #pragma unroll
  for (int off = 1; off < 64; off <<= 1) {
    const float pp0 = __shfl_up(P0, off);
    const float qq0 = __shfl_up(Q0, off);
    const float pp1 = __shfl_up(P1, off);
    const float qq1 = __shfl_up(Q1, off);
    if (lane >= off) {
      Q0 = fmaf(P0, qq0, Q0); P0 *= pp0;
      Q1 = fmaf(P1, qq1, Q1); P1 *= pp1;
    }
  }
  if (lane == 63) { wsP0[w] = P0; wsQ0[w] = Q0; wsP1[w] = P1; wsQ1[w] = Q1; }
  __syncthreads();
  float eQ0 = 0.0f, eQ1 = 0.0f;
  for (int ww = 0; ww < w; ++ww) {
    eQ0 = fmaf(wsP0[ww], eQ0, wsQ0[ww]);
    eQ1 = fmaf(wsP1[ww], eQ1, wsQ1[ww]);
  }
  float pP0 = __shfl_up(P0, 1), pQ0 = __shfl_up(Q0, 1);
  float pP1 = __shfl_up(P1, 1), pQ1 = __shfl_up(Q1, 1);
  if (lane == 0) { pP0 = 1.0f; pQ0 = 0.0f; pP1 = 1.0f; pQ1 = 0.0f; }
  float h0 = fmaf(pP0, eQ0, pQ0);
  float h1 = fmaf(pP1, eQ1, pQ1);

  // ---- epilogue: c0/c1/z consumed in float4 chunks, y stored per chunk ----
  #pragma unroll
  for (int c4 = 0; c4 < 4; ++c4) {
    const float4 c0c = *(const float4*)(bc_t + bcb + 2 * L + l0 + c4 * 4);
    const float4 c1c = *(const float4*)(bc_t + bcb + 3 * L + l0 + c4 * 4);
    const float4 zvc = *(const float4*)(z_t + rowb + l0 + c4 * 4);
    const float c0a[4] = {c0c.x, c0c.y, c0c.z, c0c.w};
    const float c1a[4] = {c1c.x, c1c.y, c1c.z, c1c.w};
    const float zva[4] = {zvc.x, zvc.y, zvc.z, zvc.w};
    float4 yc;
    float yv[4];
    #pragma unroll
    for (int i2 = 0; i2 < 4; ++i2) {
      const int i = c4 * 4 + i2;
      h0 = fmaf(a0[i], h0, u0[i]);
      h1 = fmaf(a1[i], h1, u1[i]);
      const float y = fmaf(h0, c0a[i2], fmaf(h1, c1a[i2], ddc * xcv[i]));
      yv[i2] = y * silu_f(zva[i2]);
    }
    yc = make_float4(yv[0], yv[1], yv[2], yv[3]);
    *(float4*)(y_t + rowb + l0 + c4 * 4) = yc;
  }
}

// ---------------------------------------------------------------------------
extern "C" void kernel_launch(void* const* d_in, const int* in_sizes, int n_in,
                              void* d_out, int out_size, void* d_ws, size_t ws_size,
                              hipStream_t stream)
{
  const float* x       = (const float*)d_in[0];
  const float* lin_w   = (const float*)d_in[1];
  const float* lin_b   = (const float*)d_in[2];
  const float* s1_win  = (const float*)d_in[3];
  const float* s1_bin  = (const float*)d_in[4];
  const float* s1_cw   = (const float*)d_in[5];
  const float* s1_cb   = (const float*)d_in[6];
  const float* s1_wx   = (const float*)d_in[7];
  const float* s1_wdt  = (const float*)d_in[8];
  const float* s1_bdt  = (const float*)d_in[9];
  const float* s1_alog = (const float*)d_in[10];
  const float* s1_dd   = (const float*)d_in[11];
  const float* s1_wout = (const float*)d_in[12];
  const float* s1_lnw  = (const float*)d_in[13];
  const float* s1_lnb  = (const float*)d_in[14];
  const float* s2_win  = (const float*)d_in[15];
  const float* s2_bin  = (const float*)d_in[16];
  const float* s2_cw   = (const float*)d_in[17];
  const float* s2_cb   = (const float*)d_in[18];
  const float* s2_wx   = (const float*)d_in[19];
  const float* s2_wdt  = (const float*)d_in[20];
  const float* s2_bdt  = (const float*)d_in[21];
  const float* s2_alog = (const float*)d_in[22];
  const float* s2_dd   = (const float*)d_in[23];
  const float* s2_wout = (const float*)d_in[24];
  const float* s2_lnw  = (const float*)d_in[25];
  const float* s2_lnb  = (const float*)d_in[26];
  float* out = (float*)d_out;

  const int B = 8, L = 4096, M = 32768;
  const long SLOT = 8L * 256 * 4096;   // 8388608 elems = 32 MB
  const long HALF = SLOT / 2;          // 16 MB
  float* ws = (float*)d_ws;
  float* S0f = ws;             u32* S0u = (u32*)S0f;
  float* S1f = ws + SLOT;      u32* S1u = (u32*)S1f;
  float* S2f = ws + 2 * SLOT;  u32* S2u = (u32*)S2f;
  float* SBf = ws + 3 * SLOT;                        // (B,4,L) = 131072
  float* XDS = ws + 3 * SLOT + 131072;               // (B,16,L) = 524288
  u32*   WP  = (u32*)(ws + 3 * SLOT + 131072 + 524288);  // packed weights

  // 1. pack weights
  wprep_kernel<<<WTOT / 256, 256, 0, stream>>>(s1_win, s1_wout, lin_w, s2_win, s2_wout, WP);
  // 2. x (b,128,L) -> packed xT (M,128) @ S0u
  tpose_kernel<<<dim3(128, 4, B), 256, 0, stream>>>(x, S0u, 128, L);
  // 3. stage1 in-proj: -> xcpre1 @ S1f, z1 @ S1f+HALF
  mgemm_kernel<0><<<dim3(2, 256), 256, 0, stream>>>(
      S0u, WP + WOFF1, s1_bin, M, 256, 128, S1f, S1f + HALF, nullptr, 128, L);
  // 4. proj1: xcpre1 -> xds @ XDS, B/C @ SBf
  proj_kernel<128, 8><<<dim3(256, B), 256, 0, stream>>>(
      S1f, s1_cw, s1_cb, s1_wx, XDS, SBf, L);
  // 5. fused scan1 (conv+dt recompute) -> y1 @ S0f
  scan_kernel<8><<<dim3(128, B), 256, 0, stream>>>(
      S1f, s1_cw, s1_cb, XDS, s1_wdt, s1_bdt, S1f + HALF, SBf,
      s1_alog, s1_dd, S0f, 128, L);
  // 6. y1 -> packed y1T @ S0u+HALF
  tpose_kernel<<<dim3(128, 4, B), 256, 0, stream>>>(S0f, S0u + HALF, 128, L);
  // 7. out-proj1 + LN -> act_mid packed @ S1u
  lgemm_kernel<128, 2><<<dim3(512), 256, 0, stream>>>(
      S0u + HALF, WP + WOFFO1, s1_lnw, s1_lnb, M, 128, S1u, nullptr, L);
  // 8. mid linear + silu -> act_lin packed @ S2u
  mgemm_kernel<1><<<dim3(2, 256), 256, 0, stream>>>(
      S1u, WP + WOFFL, lin_b, M, 256, 128, nullptr, nullptr, S2u, 0, L);
  // 9. stage2 in-proj: -> xcpre2 @ S0f, z2 @ S1f
  mgemm_kernel<0><<<dim3(4, 256), 256, 0, stream>>>(
      S2u, WP + WOFF2, s2_bin, M, 512, 256, S0f, S1f, nullptr, 256, L);
  // 10. proj2: xcpre2 -> xds @ XDS, B/C @ SBf
  proj_kernel<256, 16><<<dim3(256, B), 256, 0, stream>>>(
      S0f, s2_cw, s2_cb, s2_wx, XDS, SBf, L);
  // 11. fused scan2 -> y2 @ S2f
  scan_kernel<16><<<dim3(256, B), 256, 0, stream>>>(
      S0f, s2_cw, s2_cb, XDS, s2_wdt, s2_bdt, S1f, SBf,
      s2_alog, s2_dd, S2f, 256, L);
  // 12. y2 -> packed y2T @ S1u
  tpose_kernel<<<dim3(128, 8, B), 256, 0, stream>>>(S2f, S1u, 256, L);
  // 13. out-proj2 + LN -> d_out fp32 (b,256,64,64)
  lgemm_kernel<256, 3><<<dim3(512), 256, 0, stream>>>(
      S1u, WP + WOFFO2, s2_lnw, s2_lnb, M, 256, nullptr, out, L);
}

// Round 6
// 377.799 us; speedup vs baseline: 1.3859x; 1.0143x over previous
//
#include <hip/hip_runtime.h>
#include <math.h>

#define DEVI __device__ __forceinline__

typedef unsigned int u32;
typedef unsigned short u16;
typedef __attribute__((ext_vector_type(8))) __bf16 bf16x8;
typedef __attribute__((ext_vector_type(8))) u16 u16x8;
typedef __attribute__((ext_vector_type(4))) float f32x4;

DEVI float rcp_f(float x) { return __builtin_amdgcn_rcpf(x); }
DEVI float silu_f(float x) { return x * rcp_f(1.0f + __expf(-x)); }
// fast softplus: max(x,0) + log(1+exp(-|x|)); abs err < 1e-7, no libm log1pf,
// no divergent ternary (old version emitted both branches: 2 exp + 2 log1p).
DEVI float softplus_f(float x) {
  return fmaxf(x, 0.0f) + __logf(1.0f + __expf(-fabsf(x)));
}

DEVI u32 bf16_rne(float f) {
  u32 u = __float_as_uint(f);
  return (u + 0x7fffu + ((u >> 16) & 1u)) >> 16;
}
// packed split: high 16 bits = bf16(f), low 16 bits = bf16(f - hi)
DEVI u32 pack_hl(float f) {
  u32 h = bf16_rne(f);
  float hf = __uint_as_float(h << 16);
  u32 l = bf16_rne(f - hf);
  return (h << 16) | l;
}

DEVI void load16(float* r, const float* __restrict__ p) {
  const float4* q = (const float4*)p;
  float4 a = q[0], b = q[1], c = q[2], d = q[3];
  r[0]=a.x; r[1]=a.y; r[2]=a.z; r[3]=a.w;
  r[4]=b.x; r[5]=b.y; r[6]=b.z; r[7]=b.w;
  r[8]=c.x; r[9]=c.y; r[10]=c.z; r[11]=c.w;
  r[12]=d.x; r[13]=d.y; r[14]=d.z; r[15]=d.w;
}
DEVI void store16(float* __restrict__ p, const float* r) {
  float4* q = (float4*)p;
  q[0] = make_float4(r[0],r[1],r[2],r[3]);
  q[1] = make_float4(r[4],r[5],r[6],r[7]);
  q[2] = make_float4(r[8],r[9],r[10],r[11]);
  q[3] = make_float4(r[12],r[13],r[14],r[15]);
}

// split 8 packed u32 into hi/lo bf16 chunks and store 16B each to LDS
DEVI void stage_chunk(u16* __restrict__ ph, u16* __restrict__ pl, uint4 a, uint4 b) {
  u16x8 h, l;
  h[0] = (u16)(a.x >> 16); l[0] = (u16)a.x;
  h[1] = (u16)(a.y >> 16); l[1] = (u16)a.y;
  h[2] = (u16)(a.z >> 16); l[2] = (u16)a.z;
  h[3] = (u16)(a.w >> 16); l[3] = (u16)a.w;
  h[4] = (u16)(b.x >> 16); l[4] = (u16)b.x;
  h[5] = (u16)(b.y >> 16); l[5] = (u16)b.y;
  h[6] = (u16)(b.z >> 16); l[6] = (u16)b.z;
  h[7] = (u16)(b.w >> 16); l[7] = (u16)b.w;
  *(u16x8*)ph = h; *(u16x8*)pl = l;
}

// ---------------------------------------------------------------------------
// Weight prep: convert 5 fp32 weight matrices to packed hi/lo bf16 (u32).
// ---------------------------------------------------------------------------
constexpr int WN1 = 32768, WNO1 = 16384, WNL = 32768, WN2 = 131072, WNO2 = 65536;
constexpr int WOFF1 = 0, WOFFO1 = 32768, WOFFL = 49152, WOFF2 = 81920, WOFFO2 = 212992;
constexpr int WTOT = 278528;

__global__ __launch_bounds__(256) void wprep_kernel(
    const float* __restrict__ w1, const float* __restrict__ wo1,
    const float* __restrict__ wl, const float* __restrict__ w2,
    const float* __restrict__ wo2, u32* __restrict__ dst)
{
  int i = blockIdx.x * 256 + threadIdx.x;
  float v;
  if (i < WOFFO1)       v = w1[i];
  else if (i < WOFFL)   v = wo1[i - WOFFO1];
  else if (i < WOFF2)   v = wl[i - WOFFL];
  else if (i < WOFFO2)  v = w2[i - WOFF2];
  else                  v = wo2[i - WOFFO2];
  dst[i] = pack_hl(v);
}

// ---------------------------------------------------------------------------
// Transpose: fp32 (b, C, L) -> packed u32 (b*L, C)
// ---------------------------------------------------------------------------
__global__ __launch_bounds__(256) void tpose_kernel(
    const float* __restrict__ in, u32* __restrict__ out, int C, int L)
{
  __shared__ float t[32][33];
  const int l0 = blockIdx.x * 32, c0 = blockIdx.y * 32, b = blockIdx.z;
  const int tx = threadIdx.x & 31, ty = threadIdx.x >> 5;
  const float* src = in + ((long)b * C + c0) * L + l0;
  #pragma unroll
  for (int r = 0; r < 32; r += 8) t[ty + r][tx] = src[(long)(ty + r) * L + tx];
  __syncthreads();
  u32* dst = out + ((long)b * L + l0) * C + c0;
  #pragma unroll
  for (int r = 0; r < 32; r += 8) dst[(long)(ty + r) * C + tx] = pack_hl(t[tx][ty + r]);
}

// ---------------------------------------------------------------------------
// MFMA GEMM (bf16x3 split): C[m,n] = sum_k A[m,k]*W[n,k] (+bias)
// ---------------------------------------------------------------------------
template<int EPI>
__global__ __launch_bounds__(256) void mgemm_kernel(
    const u32* __restrict__ Ap, const u32* __restrict__ Wp,
    const float* __restrict__ bias, int M, int N, int K,
    float* __restrict__ out0, float* __restrict__ out1,
    u32* __restrict__ outp, int di, int L)
{
  __shared__ u16 Ah[128][40], Al[128][40], Bh[128][40], Bl[128][40];
  const int tid = threadIdx.x;
  const int wid = tid >> 6, lane = tid & 63;
  const int lm = lane & 15, lq = lane >> 4;
  const int m0 = blockIdx.y * 128, n0 = blockIdx.x * 128;
  const int wr = (wid >> 1) * 64, wn = (wid & 1) * 64;
  const int sr = tid >> 1;
  const int sc = (tid & 1) * 2;
  const int o0 = (((sc + 0) ^ (sr & 3)) * 8);
  const int o1 = (((sc + 1) ^ (sr & 3)) * 8);

  f32x4 acc[4][4];
  #pragma unroll
  for (int i = 0; i < 4; ++i)
    #pragma unroll
    for (int j = 0; j < 4; ++j)
      #pragma unroll
      for (int r = 0; r < 4; ++r) acc[i][j][r] = 0.0f;

  const u32* ga = Ap + (long)(m0 + sr) * K + sc * 8;
  const u32* gb = Wp + (long)(n0 + sr) * K + sc * 8;
  const int co = (lq ^ (lm & 3)) * 8;

  for (int k0 = 0; k0 < K; k0 += 32) {
    uint4 a0 = *(const uint4*)(ga + k0);
    uint4 a1 = *(const uint4*)(ga + k0 + 4);
    uint4 a2 = *(const uint4*)(ga + k0 + 8);
    uint4 a3 = *(const uint4*)(ga + k0 + 12);
    uint4 b0 = *(const uint4*)(gb + k0);
    uint4 b1 = *(const uint4*)(gb + k0 + 4);
    uint4 b2 = *(const uint4*)(gb + k0 + 8);
    uint4 b3 = *(const uint4*)(gb + k0 + 12);
    stage_chunk(&Ah[sr][o0], &Al[sr][o0], a0, a1);
    stage_chunk(&Ah[sr][o1], &Al[sr][o1], a2, a3);
    stage_chunk(&Bh[sr][o0], &Bl[sr][o0], b0, b1);
    stage_chunk(&Bh[sr][o1], &Bl[sr][o1], b2, b3);
    __syncthreads();

    bf16x8 fah[4], fal[4];
    #pragma unroll
    for (int i = 0; i < 4; ++i) {
      fah[i] = *(const bf16x8*)&Ah[wr + 16 * i + lm][co];
      fal[i] = *(const bf16x8*)&Al[wr + 16 * i + lm][co];
    }
    #pragma unroll
    for (int j = 0; j < 4; ++j) {
      bf16x8 fbh = *(const bf16x8*)&Bh[wn + 16 * j + lm][co];
      bf16x8 fbl = *(const bf16x8*)&Bl[wn + 16 * j + lm][co];
      #pragma unroll
      for (int i = 0; i < 4; ++i) {
        acc[i][j] = __builtin_amdgcn_mfma_f32_16x16x32_bf16(fah[i], fbh, acc[i][j], 0, 0, 0);
        acc[i][j] = __builtin_amdgcn_mfma_f32_16x16x32_bf16(fah[i], fbl, acc[i][j], 0, 0, 0);
        acc[i][j] = __builtin_amdgcn_mfma_f32_16x16x32_bf16(fal[i], fbh, acc[i][j], 0, 0, 0);
      }
    }
    __syncthreads();
  }

  if constexpr (EPI == 0) {
    const int b = m0 >> 12;
    const int lb = (m0 & 4095) + wr;
    #pragma unroll
    for (int j = 0; j < 4; ++j) {
      const int n = n0 + wn + 16 * j + lm;
      const float bv = bias[n];
      float* base = (n < di) ? out0 + ((long)b * di + n) * L
                             : out1 + ((long)b * di + (n - di)) * L;
      #pragma unroll
      for (int i = 0; i < 4; ++i) {
        const int l = lb + 16 * i + lq * 4;
        *(float4*)(base + l) = make_float4(acc[i][j][0] + bv, acc[i][j][1] + bv,
                                           acc[i][j][2] + bv, acc[i][j][3] + bv);
      }
    }
  } else {
    #pragma unroll
    for (int j = 0; j < 4; ++j) {
      const int n = n0 + wn + 16 * j + lm;
      const float bv = bias[n];
      #pragma unroll
      for (int i = 0; i < 4; ++i) {
        const long mg = m0 + wr + 16 * i + lq * 4;
        #pragma unroll
        for (int r = 0; r < 4; ++r)
          outp[(mg + r) * N + n] = pack_hl(silu_f(acc[i][j][r] + bv));
      }
    }
  }
}

// ---------------------------------------------------------------------------
// MFMA GEMM + fused LayerNorm over full width BN.
// ---------------------------------------------------------------------------
template<int BN, int EPI>
__global__ __launch_bounds__(256) void lgemm_kernel(
    const u32* __restrict__ Ap, const u32* __restrict__ Wp,
    const float* __restrict__ lnw, const float* __restrict__ lnb,
    int M, int K, u32* __restrict__ outp, float* __restrict__ outf, int L)
{
  constexpr int NT = BN / 64;
  __shared__ u16 Ah[64][40], Al[64][40], Bh[BN][40], Bl[BN][40];
  __shared__ float red[4][64];
  __shared__ float muS[64], rsS[64];

  const int tid = threadIdx.x;
  const int wid = tid >> 6, lane = tid & 63;
  const int lm = lane & 15, lq = lane >> 4;
  const int m0 = blockIdx.x * 64;
  const int wn = wid * (BN / 4);
  const int sa_r = tid >> 2, sa_c = tid & 3;
  const int sa_o = ((sa_c ^ (sa_r & 3)) * 8);
  const int co = (lq ^ (lm & 3)) * 8;

  f32x4 acc[4][NT];
  #pragma unroll
  for (int i = 0; i < 4; ++i)
    #pragma unroll
    for (int j = 0; j < NT; ++j)
      #pragma unroll
      for (int r = 0; r < 4; ++r) acc[i][j][r] = 0.0f;

  const u32* ga = Ap + (long)(m0 + sa_r) * K + sa_c * 8;

  for (int k0 = 0; k0 < K; k0 += 32) {
    uint4 a0 = *(const uint4*)(ga + k0);
    uint4 a1 = *(const uint4*)(ga + k0 + 4);
    stage_chunk(&Ah[sa_r][sa_o], &Al[sa_r][sa_o], a0, a1);
    #pragma unroll
    for (int it = 0; it < NT; ++it) {
      const int idx = tid + it * 256;
      const int n = idx >> 2, c = idx & 3;
      const u32* gw = Wp + (long)n * K + k0 + c * 8;
      uint4 b0 = *(const uint4*)gw;
      uint4 b1 = *(const uint4*)(gw + 4);
      const int o = ((c ^ (n & 3)) * 8);
      stage_chunk(&Bh[n][o], &Bl[n][o], b0, b1);
    }
    __syncthreads();

    bf16x8 fah[4], fal[4];
    #pragma unroll
    for (int i = 0; i < 4; ++i) {
      fah[i] = *(const bf16x8*)&Ah[16 * i + lm][co];
      fal[i] = *(const bf16x8*)&Al[16 * i + lm][co];
    }
    #pragma unroll
    for (int j = 0; j < NT; ++j) {
      bf16x8 fbh = *(const bf16x8*)&Bh[wn + 16 * j + lm][co];
      bf16x8 fbl = *(const bf16x8*)&Bl[wn + 16 * j + lm][co];
      #pragma unroll
      for (int i = 0; i < 4; ++i) {
        acc[i][j] = __builtin_amdgcn_mfma_f32_16x16x32_bf16(fah[i], fbh, acc[i][j], 0, 0, 0);
        acc[i][j] = __builtin_amdgcn_mfma_f32_16x16x32_bf16(fah[i], fbl, acc[i][j], 0, 0, 0);
        acc[i][j] = __builtin_amdgcn_mfma_f32_16x16x32_bf16(fal[i], fbh, acc[i][j], 0, 0, 0);
      }
    }
    __syncthreads();
  }

  // ---- fused LayerNorm over BN ----
  float part[4][4];
  #pragma unroll
  for (int i = 0; i < 4; ++i)
    #pragma unroll
    for (int r = 0; r < 4; ++r) {
      float s = 0.0f;
      #pragma unroll
      for (int j = 0; j < NT; ++j) s += acc[i][j][r];
      part[i][r] = s;
    }
  #pragma unroll
  for (int off = 1; off < 16; off <<= 1)
    #pragma unroll
    for (int i = 0; i < 4; ++i)
      #pragma unroll
      for (int r = 0; r < 4; ++r) part[i][r] += __shfl_xor(part[i][r], off);
  if (lm == 0) {
    #pragma unroll
    for (int i = 0; i < 4; ++i)
      #pragma unroll
      for (int r = 0; r < 4; ++r) red[wid][16 * i + 4 * lq + r] = part[i][r];
  }
  __syncthreads();
  if (tid < 64)
    muS[tid] = (red[0][tid] + red[1][tid] + red[2][tid] + red[3][tid]) * (1.0f / BN);
  __syncthreads();
  float mu_l[4][4];
  #pragma unroll
  for (int i = 0; i < 4; ++i)
    #pragma unroll
    for (int r = 0; r < 4; ++r) mu_l[i][r] = muS[16 * i + 4 * lq + r];
  #pragma unroll
  for (int i = 0; i < 4; ++i)
    #pragma unroll
    for (int r = 0; r < 4; ++r) {
      float s = 0.0f;
      #pragma unroll
      for (int j = 0; j < NT; ++j) {
        float d = acc[i][j][r] - mu_l[i][r];
        s = fmaf(d, d, s);
      }
      part[i][r] = s;
    }
  #pragma unroll
  for (int off = 1; off < 16; off <<= 1)
    #pragma unroll
    for (int i = 0; i < 4; ++i)
      #pragma unroll
      for (int r = 0; r < 4; ++r) part[i][r] += __shfl_xor(part[i][r], off);
  if (lm == 0) {
    #pragma unroll
    for (int i = 0; i < 4; ++i)
      #pragma unroll
      for (int r = 0; r < 4; ++r) red[wid][16 * i + 4 * lq + r] = part[i][r];
  }
  __syncthreads();
  if (tid < 64)
    rsS[tid] = rsqrtf((red[0][tid] + red[1][tid] + red[2][tid] + red[3][tid]) * (1.0f / BN)
                      + 1e-5f);
  __syncthreads();
  float rs_l[4][4];
  #pragma unroll
  for (int i = 0; i < 4; ++i)
    #pragma unroll
    for (int r = 0; r < 4; ++r) rs_l[i][r] = rsS[16 * i + 4 * lq + r];

  if constexpr (EPI == 2) {
    #pragma unroll
    for (int j = 0; j < NT; ++j) {
      const int n = wn + 16 * j + lm;
      const float g = lnw[n], bb = lnb[n];
      #pragma unroll
      for (int i = 0; i < 4; ++i) {
        #pragma unroll
        for (int r = 0; r < 4; ++r) {
          const long mg = m0 + 16 * i + 4 * lq + r;
          outp[mg * BN + n] =
              pack_hl((acc[i][j][r] - mu_l[i][r]) * rs_l[i][r] * g + bb);
        }
      }
    }
  } else {
    const int b = m0 >> 12;
    const int lb = m0 & 4095;
    #pragma unroll
    for (int j = 0; j < NT; ++j) {
      const int n = wn + 16 * j + lm;
      const float g = lnw[n], bb = lnb[n];
      #pragma unroll
      for (int i = 0; i < 4; ++i) {
        const int l = lb + 16 * i + 4 * lq;
        float4 v;
        v.x = (acc[i][j][0] - mu_l[i][0]) * rs_l[i][0] * g + bb;
        v.y = (acc[i][j][1] - mu_l[i][1]) * rs_l[i][1] * g + bb;
        v.z = (acc[i][j][2] - mu_l[i][2]) * rs_l[i][2] * g + bb;
        v.w = (acc[i][j][3] - mu_l[i][3]) * rs_l[i][3] * g + bb;
        *(float4*)(outf + ((long)b * BN + n) * L + l) = v;
      }
    }
  }
}

// ---------------------------------------------------------------------------
// Projection only: causal depthwise conv(4)+silu (into LDS, transposed) ->
// xds[j,l] = sum_ch wx[j][ch]*xc[ch][l] for j < R+4. Rows j<R go to xds_g
// (B,R,L), rows R..R+3 (B,C) go to bc_t. NO bulk xc/dt output — the scan
// kernel recomputes conv+silu and dt on the fly (saves 128 MB round trips).
// ---------------------------------------------------------------------------
template<int DI, int R>
__global__ __launch_bounds__(256) void proj_kernel(
    const float* __restrict__ xcpre_t,
    const float* __restrict__ cw, const float* __restrict__ cb,
    const float* __restrict__ wx,
    float* __restrict__ xds_g, float* __restrict__ bc_t, int L)
{
  constexpr int LT = 16;
  constexpr int NP = R + 4;            // proj rows: R dt-rank + 2 B + 2 C
  constexpr int NC = DI / 4;           // float4 chunks per position row
  __shared__ float xcT[LT][DI];        // [pos][rot-swizzled ch]

  const int tid = threadIdx.x;
  const int l0 = blockIdx.x * LT;
  const int bz = blockIdx.y;

  // ---- phase 1: conv + silu -> transposed/swizzled LDS ----
  if (tid < DI) {
    const int ch = tid;
    const long rowb = ((long)bz * DI + ch) * L;
    const float* __restrict__ src = xcpre_t + rowb + l0;
    float pre[LT + 3];
    if (l0 >= 3) {
      #pragma unroll
      for (int i = 0; i < LT + 3; ++i) pre[i] = src[i - 3];
    } else {
      #pragma unroll
      for (int i = 0; i < LT + 3; ++i) {
        const int l = l0 - 3 + i;
        pre[i] = (l >= 0) ? xcpre_t[rowb + l] : 0.0f;
      }
    }
    const float w0 = cw[ch*4+0], w1 = cw[ch*4+1], w2 = cw[ch*4+2], w3 = cw[ch*4+3];
    const float cbc = cb[ch];
    const int g = ch >> 2, c = ch & 3;
    #pragma unroll
    for (int i = 0; i < LT; ++i) {
      float s = cbc;
      s = fmaf(pre[i+0], w0, s);
      s = fmaf(pre[i+1], w1, s);
      s = fmaf(pre[i+2], w2, s);
      s = fmaf(pre[i+3], w3, s);
      xcT[i][(((g + i) & (NC - 1)) << 2) + c] = silu_f(s);
    }
  }
  __syncthreads();

  // ---- phase 2: out[j][i] = sum_ch wx[j][ch] * xc[ch][i] (float4 dot) ----
  for (int q = tid; q < NP * LT; q += 256) {
    const int j = q >> 4;
    const int i = q & 15;
    const float* __restrict__ wr = wx + (long)j * DI;
    float a0 = 0.0f, a1 = 0.0f, a2 = 0.0f, a3 = 0.0f;
    #pragma unroll 4
    for (int g = 0; g < NC; ++g) {
      const float4 xv = *(const float4*)&xcT[i][((g + i) & (NC - 1)) << 2];
      const float4 wv = *(const float4*)(wr + (g << 2));
      a0 = fmaf(xv.x, wv.x, a0);
      a1 = fmaf(xv.y, wv.y, a1);
      a2 = fmaf(xv.z, wv.z, a2);
      a3 = fmaf(xv.w, wv.w, a3);
    }
    const float val = (a0 + a1) + (a2 + a3);
    if (j < R) xds_g[((long)bz * R + j) * L + l0 + i] = val;
    else       bc_t[((long)bz * 4 + (j - R)) * L + l0 + i] = val;
  }
}

// ---------------------------------------------------------------------------
// Fused selective scan: recomputes conv+silu (from xcpre) and
// dt = softplus(xds @ wdt_row + bdt) on the fly (identical op order ->
// bit-identical), then block-parallel affine scan over L.
// v7: __launch_bounds__(256,2) (up to 256 VGPR) + ALL row-local inputs
// (cur/prev, t0/t1, c0/c1, z) front-loaded into registers before any
// compute; epilogue is register-only — no global loads after the barrier.
// ---------------------------------------------------------------------------
template<int R>
__global__ __launch_bounds__(256, 2) void scan_kernel(
    const float* __restrict__ xcpre_t,
    const float* __restrict__ cw, const float* __restrict__ cb,
    const float* __restrict__ xds_g, const float* __restrict__ wdt,
    const float* __restrict__ bdt,
    const float* __restrict__ z_t, const float* __restrict__ bc_t,
    const float* __restrict__ alog, const float* __restrict__ dd,
    float* __restrict__ y_t, int di, int L)
{
  const int ch = blockIdx.x;
  const int bz = blockIdx.y;
  const int tid = threadIdx.x;
  const int lane = tid & 63;
  const int w = tid >> 6;
  const long rowb = ((long)bz * di + ch) * L;
  const long bcb = (long)bz * 4 * L;
  const int l0 = tid * 16;

  __shared__ float wsP0[4], wsQ0[4], wsP1[4], wsQ1[4];

  // ---- front-load ALL row-local inputs (45 loads in flight) ----
  float cur[16];
  load16(cur, xcpre_t + rowb + l0);
  float p0 = 0.0f, p1 = 0.0f, p2 = 0.0f;
  if (tid > 0) {
    const float4 h = *(const float4*)(xcpre_t + rowb + l0 - 4);
    p0 = h.y; p1 = h.z; p2 = h.w;
  }
  float t0[16], t1[16];
  load16(t0, bc_t + bcb + l0);
  load16(t1, bc_t + bcb + L + l0);
  float c0[16], c1[16], zv[16];
  load16(c0, bc_t + bcb + 2 * L + l0);
  load16(c1, bc_t + bcb + 3 * L + l0);
  load16(zv, z_t + rowb + l0);

  const float A0 = -__expf(alog[ch * 2 + 0]);
  const float A1 = -__expf(alog[ch * 2 + 1]);
  const float ddc = dd[ch];

  // ---- dt pre-activation: sd[i] = bdt + sum_j xds[j][l0+i]*wdt[ch][j] ----
  float wr[R];
  #pragma unroll
  for (int j = 0; j < R; ++j) wr[j] = wdt[ch * R + j];
  const float bv = bdt[ch];
  float sd[16];
  #pragma unroll
  for (int i = 0; i < 16; ++i) sd[i] = bv;
  const float* __restrict__ xp = xds_g + (long)bz * R * L + l0;
  #pragma unroll 2
  for (int j = 0; j < R; ++j) {
    const float wj = wr[j];
    const float4 x0 = *(const float4*)(xp + (long)j * L + 0);
    const float4 x1 = *(const float4*)(xp + (long)j * L + 4);
    const float4 x2 = *(const float4*)(xp + (long)j * L + 8);
    const float4 x3 = *(const float4*)(xp + (long)j * L + 12);
    sd[0]  = fmaf(x0.x, wj, sd[0]);  sd[1]  = fmaf(x0.y, wj, sd[1]);
    sd[2]  = fmaf(x0.z, wj, sd[2]);  sd[3]  = fmaf(x0.w, wj, sd[3]);
    sd[4]  = fmaf(x1.x, wj, sd[4]);  sd[5]  = fmaf(x1.y, wj, sd[5]);
    sd[6]  = fmaf(x1.z, wj, sd[6]);  sd[7]  = fmaf(x1.w, wj, sd[7]);
    sd[8]  = fmaf(x2.x, wj, sd[8]);  sd[9]  = fmaf(x2.y, wj, sd[9]);
    sd[10] = fmaf(x2.z, wj, sd[10]); sd[11] = fmaf(x2.w, wj, sd[11]);
    sd[12] = fmaf(x3.x, wj, sd[12]); sd[13] = fmaf(x3.y, wj, sd[13]);
    sd[14] = fmaf(x3.z, wj, sd[14]); sd[15] = fmaf(x3.w, wj, sd[15]);
  }

  // ---- conv + silu -> xcv (identical order to proj phase 1) ----
  const float w0 = cw[ch*4+0], w1 = cw[ch*4+1], w2 = cw[ch*4+2], w3 = cw[ch*4+3];
  const float cbc = cb[ch];
  float xcv[16];
  {
    float s;
    s = cbc; s = fmaf(p0, w0, s); s = fmaf(p1, w1, s); s = fmaf(p2, w2, s);
    s = fmaf(cur[0], w3, s); xcv[0] = silu_f(s);
    s = cbc; s = fmaf(p1, w0, s); s = fmaf(p2, w1, s); s = fmaf(cur[0], w2, s);
    s = fmaf(cur[1], w3, s); xcv[1] = silu_f(s);
    s = cbc; s = fmaf(p2, w0, s); s = fmaf(cur[0], w1, s); s = fmaf(cur[1], w2, s);
    s = fmaf(cur[2], w3, s); xcv[2] = silu_f(s);
    #pragma unroll
    for (int i = 3; i < 16; ++i) {
      s = cbc;
      s = fmaf(cur[i-3], w0, s);
      s = fmaf(cur[i-2], w1, s);
      s = fmaf(cur[i-1], w2, s);
      s = fmaf(cur[i],   w3, s);
      xcv[i] = silu_f(s);
    }
  }

  // ---- local scan coefficients (all inputs already in registers) ----
  float a0[16], a1[16], u0[16], u1[16];
  float P0 = 1.0f, Q0 = 0.0f, P1 = 1.0f, Q1 = 0.0f;
  #pragma unroll
  for (int i = 0; i < 16; ++i) {
    const float dt = softplus_f(sd[i]);
    const float dx = dt * xcv[i];
    a0[i] = __expf(dt * A0);
    a1[i] = __expf(dt * A1);
    u0[i] = dx * t0[i];
    u1[i] = dx * t1[i];
    Q0 = fmaf(a0[i], Q0, u0[i]); P0 *= a0[i];
    Q1 = fmaf(a1[i], Q1, u1[i]); P1 *= a1[i];
  }

  #pragma unroll
  for (int off = 1; off < 64; off <<= 1) {
    const float pp0 = __shfl_up(P0, off);
    const float qq0 = __shfl_up(Q0, off);
    const float pp1 = __shfl_up(P1, off);
    const float qq1 = __shfl_up(Q1, off);
    if (lane >= off) {
      Q0 = fmaf(P0, qq0, Q0); P0 *= pp0;
      Q1 = fmaf(P1, qq1, Q1); P1 *= pp1;
    }
  }
  if (lane == 63) { wsP0[w] = P0; wsQ0[w] = Q0; wsP1[w] = P1; wsQ1[w] = Q1; }
  __syncthreads();
  float eQ0 = 0.0f, eQ1 = 0.0f;
  for (int ww = 0; ww < w; ++ww) {
    eQ0 = fmaf(wsP0[ww], eQ0, wsQ0[ww]);
    eQ1 = fmaf(wsP1[ww], eQ1, wsQ1[ww]);
  }
  float pP0 = __shfl_up(P0, 1), pQ0 = __shfl_up(Q0, 1);
  float pP1 = __shfl_up(P1, 1), pQ1 = __shfl_up(Q1, 1);
  if (lane == 0) { pP0 = 1.0f; pQ0 = 0.0f; pP1 = 1.0f; pQ1 = 0.0f; }
  float h0 = fmaf(pP0, eQ0, pQ0);
  float h1 = fmaf(pP1, eQ1, pQ1);

  // ---- epilogue: register-only, no global loads after the barrier ----
  float yv[16];
  #pragma unroll
  for (int i = 0; i < 16; ++i) {
    h0 = fmaf(a0[i], h0, u0[i]);
    h1 = fmaf(a1[i], h1, u1[i]);
    const float y = fmaf(h0, c0[i], fmaf(h1, c1[i], ddc * xcv[i]));
    yv[i] = y * silu_f(zv[i]);
  }
  store16(y_t + rowb + l0, yv);
}

// ---------------------------------------------------------------------------
extern "C" void kernel_launch(void* const* d_in, const int* in_sizes, int n_in,
                              void* d_out, int out_size, void* d_ws, size_t ws_size,
                              hipStream_t stream)
{
  const float* x       = (const float*)d_in[0];
  const float* lin_w   = (const float*)d_in[1];
  const float* lin_b   = (const float*)d_in[2];
  const float* s1_win  = (const float*)d_in[3];
  const float* s1_bin  = (const float*)d_in[4];
  const float* s1_cw   = (const float*)d_in[5];
  const float* s1_cb   = (const float*)d_in[6];
  const float* s1_wx   = (const float*)d_in[7];
  const float* s1_wdt  = (const float*)d_in[8];
  const float* s1_bdt  = (const float*)d_in[9];
  const float* s1_alog = (const float*)d_in[10];
  const float* s1_dd   = (const float*)d_in[11];
  const float* s1_wout = (const float*)d_in[12];
  const float* s1_lnw  = (const float*)d_in[13];
  const float* s1_lnb  = (const float*)d_in[14];
  const float* s2_win  = (const float*)d_in[15];
  const float* s2_bin  = (const float*)d_in[16];
  const float* s2_cw   = (const float*)d_in[17];
  const float* s2_cb   = (const float*)d_in[18];
  const float* s2_wx   = (const float*)d_in[19];
  const float* s2_wdt  = (const float*)d_in[20];
  const float* s2_bdt  = (const float*)d_in[21];
  const float* s2_alog = (const float*)d_in[22];
  const float* s2_dd   = (const float*)d_in[23];
  const float* s2_wout = (const float*)d_in[24];
  const float* s2_lnw  = (const float*)d_in[25];
  const float* s2_lnb  = (const float*)d_in[26];
  float* out = (float*)d_out;

  const int B = 8, L = 4096, M = 32768;
  const long SLOT = 8L * 256 * 4096;   // 8388608 elems = 32 MB
  const long HALF = SLOT / 2;          // 16 MB
  float* ws = (float*)d_ws;
  float* S0f = ws;             u32* S0u = (u32*)S0f;
  float* S1f = ws + SLOT;      u32* S1u = (u32*)S1f;
  float* S2f = ws + 2 * SLOT;  u32* S2u = (u32*)S2f;
  float* SBf = ws + 3 * SLOT;                        // (B,4,L) = 131072
  float* XDS = ws + 3 * SLOT + 131072;               // (B,16,L) = 524288
  u32*   WP  = (u32*)(ws + 3 * SLOT + 131072 + 524288);  // packed weights

  // 1. pack weights
  wprep_kernel<<<WTOT / 256, 256, 0, stream>>>(s1_win, s1_wout, lin_w, s2_win, s2_wout, WP);
  // 2. x (b,128,L) -> packed xT (M,128) @ S0u
  tpose_kernel<<<dim3(128, 4, B), 256, 0, stream>>>(x, S0u, 128, L);
  // 3. stage1 in-proj: -> xcpre1 @ S1f, z1 @ S1f+HALF
  mgemm_kernel<0><<<dim3(2, 256), 256, 0, stream>>>(
      S0u, WP + WOFF1, s1_bin, M, 256, 128, S1f, S1f + HALF, nullptr, 128, L);
  // 4. proj1: xcpre1 -> xds @ XDS, B/C @ SBf
  proj_kernel<128, 8><<<dim3(256, B), 256, 0, stream>>>(
      S1f, s1_cw, s1_cb, s1_wx, XDS, SBf, L);
  // 5. fused scan1 (conv+dt recompute) -> y1 @ S0f
  scan_kernel<8><<<dim3(128, B), 256, 0, stream>>>(
      S1f, s1_cw, s1_cb, XDS, s1_wdt, s1_bdt, S1f + HALF, SBf,
      s1_alog, s1_dd, S0f, 128, L);
  // 6. y1 -> packed y1T @ S0u+HALF
  tpose_kernel<<<dim3(128, 4, B), 256, 0, stream>>>(S0f, S0u + HALF, 128, L);
  // 7. out-proj1 + LN -> act_mid packed @ S1u
  lgemm_kernel<128, 2><<<dim3(512), 256, 0, stream>>>(
      S0u + HALF, WP + WOFFO1, s1_lnw, s1_lnb, M, 128, S1u, nullptr, L);
  // 8. mid linear + silu -> act_lin packed @ S2u
  mgemm_kernel<1><<<dim3(2, 256), 256, 0, stream>>>(
      S1u, WP + WOFFL, lin_b, M, 256, 128, nullptr, nullptr, S2u, 0, L);
  // 9. stage2 in-proj: -> xcpre2 @ S0f, z2 @ S1f
  mgemm_kernel<0><<<dim3(4, 256), 256, 0, stream>>>(
      S2u, WP + WOFF2, s2_bin, M, 512, 256, S0f, S1f, nullptr, 256, L);
  // 10. proj2: xcpre2 -> xds @ XDS, B/C @ SBf
  proj_kernel<256, 16><<<dim3(256, B), 256, 0, stream>>>(
      S0f, s2_cw, s2_cb, s2_wx, XDS, SBf, L);
  // 11. fused scan2 -> y2 @ S2f
  scan_kernel<16><<<dim3(256, B), 256, 0, stream>>>(
      S0f, s2_cw, s2_cb, XDS, s2_wdt, s2_bdt, S1f, SBf,
      s2_alog, s2_dd, S2f, 256, L);
  // 12. y2 -> packed y2T @ S1u
  tpose_kernel<<<dim3(128, 8, B), 256, 0, stream>>>(S2f, S1u, 256, L);
  // 13. out-proj2 + LN -> d_out fp32 (b,256,64,64)
  lgemm_kernel<256, 3><<<dim3(512), 256, 0, stream>>>(
      S1u, WP + WOFFO2, s2_lnw, s2_lnb, M, 256, nullptr, out, L);
}

// Round 7
// 358.753 us; speedup vs baseline: 1.4594x; 1.0531x over previous
//
#include <hip/hip_runtime.h>
#include <math.h>

#define DEVI __device__ __forceinline__

typedef unsigned int u32;
typedef unsigned short u16;
typedef __attribute__((ext_vector_type(8))) __bf16 bf16x8;
typedef __attribute__((ext_vector_type(8))) u16 u16x8;
typedef __attribute__((ext_vector_type(4))) float f32x4;

DEVI float rcp_f(float x) { return __builtin_amdgcn_rcpf(x); }
DEVI float silu_f(float x) { return x * rcp_f(1.0f + __expf(-x)); }
// fast softplus: max(x,0) + log(1+exp(-|x|)); abs err < 1e-7, no libm log1pf,
// no divergent ternary (old version emitted both branches: 2 exp + 2 log1p).
DEVI float softplus_f(float x) {
  return fmaxf(x, 0.0f) + __logf(1.0f + __expf(-fabsf(x)));
}

DEVI u32 bf16_rne(float f) {
  u32 u = __float_as_uint(f);
  return (u + 0x7fffu + ((u >> 16) & 1u)) >> 16;
}
// packed split: high 16 bits = bf16(f), low 16 bits = bf16(f - hi)
DEVI u32 pack_hl(float f) {
  u32 h = bf16_rne(f);
  float hf = __uint_as_float(h << 16);
  u32 l = bf16_rne(f - hf);
  return (h << 16) | l;
}

DEVI void load16(float* r, const float* __restrict__ p) {
  const float4* q = (const float4*)p;
  float4 a = q[0], b = q[1], c = q[2], d = q[3];
  r[0]=a.x; r[1]=a.y; r[2]=a.z; r[3]=a.w;
  r[4]=b.x; r[5]=b.y; r[6]=b.z; r[7]=b.w;
  r[8]=c.x; r[9]=c.y; r[10]=c.z; r[11]=c.w;
  r[12]=d.x; r[13]=d.y; r[14]=d.z; r[15]=d.w;
}
DEVI void store16(float* __restrict__ p, const float* r) {
  float4* q = (float4*)p;
  q[0] = make_float4(r[0],r[1],r[2],r[3]);
  q[1] = make_float4(r[4],r[5],r[6],r[7]);
  q[2] = make_float4(r[8],r[9],r[10],r[11]);
  q[3] = make_float4(r[12],r[13],r[14],r[15]);
}
DEVI void load8(float* r, const float* __restrict__ p) {
  const float4* q = (const float4*)p;
  float4 a = q[0], b = q[1];
  r[0]=a.x; r[1]=a.y; r[2]=a.z; r[3]=a.w;
  r[4]=b.x; r[5]=b.y; r[6]=b.z; r[7]=b.w;
}

// split 8 packed u32 into hi/lo bf16 chunks and store 16B each to LDS
DEVI void stage_chunk(u16* __restrict__ ph, u16* __restrict__ pl, uint4 a, uint4 b) {
  u16x8 h, l;
  h[0] = (u16)(a.x >> 16); l[0] = (u16)a.x;
  h[1] = (u16)(a.y >> 16); l[1] = (u16)a.y;
  h[2] = (u16)(a.z >> 16); l[2] = (u16)a.z;
  h[3] = (u16)(a.w >> 16); l[3] = (u16)a.w;
  h[4] = (u16)(b.x >> 16); l[4] = (u16)b.x;
  h[5] = (u16)(b.y >> 16); l[5] = (u16)b.y;
  h[6] = (u16)(b.z >> 16); l[6] = (u16)b.z;
  h[7] = (u16)(b.w >> 16); l[7] = (u16)b.w;
  *(u16x8*)ph = h; *(u16x8*)pl = l;
}

// ---------------------------------------------------------------------------
// Weight prep: convert 5 fp32 weight matrices to packed hi/lo bf16 (u32).
// ---------------------------------------------------------------------------
constexpr int WN1 = 32768, WNO1 = 16384, WNL = 32768, WN2 = 131072, WNO2 = 65536;
constexpr int WOFF1 = 0, WOFFO1 = 32768, WOFFL = 49152, WOFF2 = 81920, WOFFO2 = 212992;
constexpr int WTOT = 278528;

__global__ __launch_bounds__(256) void wprep_kernel(
    const float* __restrict__ w1, const float* __restrict__ wo1,
    const float* __restrict__ wl, const float* __restrict__ w2,
    const float* __restrict__ wo2, u32* __restrict__ dst)
{
  int i = blockIdx.x * 256 + threadIdx.x;
  float v;
  if (i < WOFFO1)       v = w1[i];
  else if (i < WOFFL)   v = wo1[i - WOFFO1];
  else if (i < WOFF2)   v = wl[i - WOFFL];
  else if (i < WOFFO2)  v = w2[i - WOFF2];
  else                  v = wo2[i - WOFFO2];
  dst[i] = pack_hl(v);
}

// ---------------------------------------------------------------------------
// Transpose: fp32 (b, C, L) -> packed u32 (b*L, C)
// ---------------------------------------------------------------------------
__global__ __launch_bounds__(256) void tpose_kernel(
    const float* __restrict__ in, u32* __restrict__ out, int C, int L)
{
  __shared__ float t[32][33];
  const int l0 = blockIdx.x * 32, c0 = blockIdx.y * 32, b = blockIdx.z;
  const int tx = threadIdx.x & 31, ty = threadIdx.x >> 5;
  const float* src = in + ((long)b * C + c0) * L + l0;
  #pragma unroll
  for (int r = 0; r < 32; r += 8) t[ty + r][tx] = src[(long)(ty + r) * L + tx];
  __syncthreads();
  u32* dst = out + ((long)b * L + l0) * C + c0;
  #pragma unroll
  for (int r = 0; r < 32; r += 8) dst[(long)(ty + r) * C + tx] = pack_hl(t[tx][ty + r]);
}

// ---------------------------------------------------------------------------
// MFMA GEMM (bf16x3 split): C[m,n] = sum_k A[m,k]*W[n,k] (+bias)
// ---------------------------------------------------------------------------
template<int EPI>
__global__ __launch_bounds__(256) void mgemm_kernel(
    const u32* __restrict__ Ap, const u32* __restrict__ Wp,
    const float* __restrict__ bias, int M, int N, int K,
    float* __restrict__ out0, float* __restrict__ out1,
    u32* __restrict__ outp, int di, int L)
{
  __shared__ u16 Ah[128][40], Al[128][40], Bh[128][40], Bl[128][40];
  const int tid = threadIdx.x;
  const int wid = tid >> 6, lane = tid & 63;
  const int lm = lane & 15, lq = lane >> 4;
  const int m0 = blockIdx.y * 128, n0 = blockIdx.x * 128;
  const int wr = (wid >> 1) * 64, wn = (wid & 1) * 64;
  const int sr = tid >> 1;
  const int sc = (tid & 1) * 2;
  const int o0 = (((sc + 0) ^ (sr & 3)) * 8);
  const int o1 = (((sc + 1) ^ (sr & 3)) * 8);

  f32x4 acc[4][4];
  #pragma unroll
  for (int i = 0; i < 4; ++i)
    #pragma unroll
    for (int j = 0; j < 4; ++j)
      #pragma unroll
      for (int r = 0; r < 4; ++r) acc[i][j][r] = 0.0f;

  const u32* ga = Ap + (long)(m0 + sr) * K + sc * 8;
  const u32* gb = Wp + (long)(n0 + sr) * K + sc * 8;
  const int co = (lq ^ (lm & 3)) * 8;

  for (int k0 = 0; k0 < K; k0 += 32) {
    uint4 a0 = *(const uint4*)(ga + k0);
    uint4 a1 = *(const uint4*)(ga + k0 + 4);
    uint4 a2 = *(const uint4*)(ga + k0 + 8);
    uint4 a3 = *(const uint4*)(ga + k0 + 12);
    uint4 b0 = *(const uint4*)(gb + k0);
    uint4 b1 = *(const uint4*)(gb + k0 + 4);
    uint4 b2 = *(const uint4*)(gb + k0 + 8);
    uint4 b3 = *(const uint4*)(gb + k0 + 12);
    stage_chunk(&Ah[sr][o0], &Al[sr][o0], a0, a1);
    stage_chunk(&Ah[sr][o1], &Al[sr][o1], a2, a3);
    stage_chunk(&Bh[sr][o0], &Bl[sr][o0], b0, b1);
    stage_chunk(&Bh[sr][o1], &Bl[sr][o1], b2, b3);
    __syncthreads();

    bf16x8 fah[4], fal[4];
    #pragma unroll
    for (int i = 0; i < 4; ++i) {
      fah[i] = *(const bf16x8*)&Ah[wr + 16 * i + lm][co];
      fal[i] = *(const bf16x8*)&Al[wr + 16 * i + lm][co];
    }
    #pragma unroll
    for (int j = 0; j < 4; ++j) {
      bf16x8 fbh = *(const bf16x8*)&Bh[wn + 16 * j + lm][co];
      bf16x8 fbl = *(const bf16x8*)&Bl[wn + 16 * j + lm][co];
      #pragma unroll
      for (int i = 0; i < 4; ++i) {
        acc[i][j] = __builtin_amdgcn_mfma_f32_16x16x32_bf16(fah[i], fbh, acc[i][j], 0, 0, 0);
        acc[i][j] = __builtin_amdgcn_mfma_f32_16x16x32_bf16(fah[i], fbl, acc[i][j], 0, 0, 0);
        acc[i][j] = __builtin_amdgcn_mfma_f32_16x16x32_bf16(fal[i], fbh, acc[i][j], 0, 0, 0);
      }
    }
    __syncthreads();
  }

  if constexpr (EPI == 0) {
    const int b = m0 >> 12;
    const int lb = (m0 & 4095) + wr;
    #pragma unroll
    for (int j = 0; j < 4; ++j) {
      const int n = n0 + wn + 16 * j + lm;
      const float bv = bias[n];
      float* base = (n < di) ? out0 + ((long)b * di + n) * L
                             : out1 + ((long)b * di + (n - di)) * L;
      #pragma unroll
      for (int i = 0; i < 4; ++i) {
        const int l = lb + 16 * i + lq * 4;
        *(float4*)(base + l) = make_float4(acc[i][j][0] + bv, acc[i][j][1] + bv,
                                           acc[i][j][2] + bv, acc[i][j][3] + bv);
      }
    }
  } else {
    #pragma unroll
    for (int j = 0; j < 4; ++j) {
      const int n = n0 + wn + 16 * j + lm;
      const float bv = bias[n];
      #pragma unroll
      for (int i = 0; i < 4; ++i) {
        const long mg = m0 + wr + 16 * i + lq * 4;
        #pragma unroll
        for (int r = 0; r < 4; ++r)
          outp[(mg + r) * N + n] = pack_hl(silu_f(acc[i][j][r] + bv));
      }
    }
  }
}

// ---------------------------------------------------------------------------
// MFMA GEMM + fused LayerNorm over full width BN.
// ---------------------------------------------------------------------------
template<int BN, int EPI>
__global__ __launch_bounds__(256) void lgemm_kernel(
    const u32* __restrict__ Ap, const u32* __restrict__ Wp,
    const float* __restrict__ lnw, const float* __restrict__ lnb,
    int M, int K, u32* __restrict__ outp, float* __restrict__ outf, int L)
{
  constexpr int NT = BN / 64;
  __shared__ u16 Ah[64][40], Al[64][40], Bh[BN][40], Bl[BN][40];
  __shared__ float red[4][64];
  __shared__ float muS[64], rsS[64];

  const int tid = threadIdx.x;
  const int wid = tid >> 6, lane = tid & 63;
  const int lm = lane & 15, lq = lane >> 4;
  const int m0 = blockIdx.x * 64;
  const int wn = wid * (BN / 4);
  const int sa_r = tid >> 2, sa_c = tid & 3;
  const int sa_o = ((sa_c ^ (sa_r & 3)) * 8);
  const int co = (lq ^ (lm & 3)) * 8;

  f32x4 acc[4][NT];
  #pragma unroll
  for (int i = 0; i < 4; ++i)
    #pragma unroll
    for (int j = 0; j < NT; ++j)
      #pragma unroll
      for (int r = 0; r < 4; ++r) acc[i][j][r] = 0.0f;

  const u32* ga = Ap + (long)(m0 + sa_r) * K + sa_c * 8;

  for (int k0 = 0; k0 < K; k0 += 32) {
    uint4 a0 = *(const uint4*)(ga + k0);
    uint4 a1 = *(const uint4*)(ga + k0 + 4);
    stage_chunk(&Ah[sa_r][sa_o], &Al[sa_r][sa_o], a0, a1);
    #pragma unroll
    for (int it = 0; it < NT; ++it) {
      const int idx = tid + it * 256;
      const int n = idx >> 2, c = idx & 3;
      const u32* gw = Wp + (long)n * K + k0 + c * 8;
      uint4 b0 = *(const uint4*)gw;
      uint4 b1 = *(const uint4*)(gw + 4);
      const int o = ((c ^ (n & 3)) * 8);
      stage_chunk(&Bh[n][o], &Bl[n][o], b0, b1);
    }
    __syncthreads();

    bf16x8 fah[4], fal[4];
    #pragma unroll
    for (int i = 0; i < 4; ++i) {
      fah[i] = *(const bf16x8*)&Ah[16 * i + lm][co];
      fal[i] = *(const bf16x8*)&Al[16 * i + lm][co];
    }
    #pragma unroll
    for (int j = 0; j < NT; ++j) {
      bf16x8 fbh = *(const bf16x8*)&Bh[wn + 16 * j + lm][co];
      bf16x8 fbl = *(const bf16x8*)&Bl[wn + 16 * j + lm][co];
      #pragma unroll
      for (int i = 0; i < 4; ++i) {
        acc[i][j] = __builtin_amdgcn_mfma_f32_16x16x32_bf16(fah[i], fbh, acc[i][j], 0, 0, 0);
        acc[i][j] = __builtin_amdgcn_mfma_f32_16x16x32_bf16(fah[i], fbl, acc[i][j], 0, 0, 0);
        acc[i][j] = __builtin_amdgcn_mfma_f32_16x16x32_bf16(fal[i], fbh, acc[i][j], 0, 0, 0);
      }
    }
    __syncthreads();
  }

  // ---- fused LayerNorm over BN ----
  float part[4][4];
  #pragma unroll
  for (int i = 0; i < 4; ++i)
    #pragma unroll
    for (int r = 0; r < 4; ++r) {
      float s = 0.0f;
      #pragma unroll
      for (int j = 0; j < NT; ++j) s += acc[i][j][r];
      part[i][r] = s;
    }
  #pragma unroll
  for (int off = 1; off < 16; off <<= 1)
    #pragma unroll
    for (int i = 0; i < 4; ++i)
      #pragma unroll
      for (int r = 0; r < 4; ++r) part[i][r] += __shfl_xor(part[i][r], off);
  if (lm == 0) {
    #pragma unroll
    for (int i = 0; i < 4; ++i)
      #pragma unroll
      for (int r = 0; r < 4; ++r) red[wid][16 * i + 4 * lq + r] = part[i][r];
  }
  __syncthreads();
  if (tid < 64)
    muS[tid] = (red[0][tid] + red[1][tid] + red[2][tid] + red[3][tid]) * (1.0f / BN);
  __syncthreads();
  float mu_l[4][4];
  #pragma unroll
  for (int i = 0; i < 4; ++i)
    #pragma unroll
    for (int r = 0; r < 4; ++r) mu_l[i][r] = muS[16 * i + 4 * lq + r];
  #pragma unroll
  for (int i = 0; i < 4; ++i)
    #pragma unroll
    for (int r = 0; r < 4; ++r) {
      float s = 0.0f;
      #pragma unroll
      for (int j = 0; j < NT; ++j) {
        float d = acc[i][j][r] - mu_l[i][r];
        s = fmaf(d, d, s);
      }
      part[i][r] = s;
    }
  #pragma unroll
  for (int off = 1; off < 16; off <<= 1)
    #pragma unroll
    for (int i = 0; i < 4; ++i)
      #pragma unroll
      for (int r = 0; r < 4; ++r) part[i][r] += __shfl_xor(part[i][r], off);
  if (lm == 0) {
    #pragma unroll
    for (int i = 0; i < 4; ++i)
      #pragma unroll
      for (int r = 0; r < 4; ++r) red[wid][16 * i + 4 * lq + r] = part[i][r];
  }
  __syncthreads();
  if (tid < 64)
    rsS[tid] = rsqrtf((red[0][tid] + red[1][tid] + red[2][tid] + red[3][tid]) * (1.0f / BN)
                      + 1e-5f);
  __syncthreads();
  float rs_l[4][4];
  #pragma unroll
  for (int i = 0; i < 4; ++i)
    #pragma unroll
    for (int r = 0; r < 4; ++r) rs_l[i][r] = rsS[16 * i + 4 * lq + r];

  if constexpr (EPI == 2) {
    #pragma unroll
    for (int j = 0; j < NT; ++j) {
      const int n = wn + 16 * j + lm;
      const float g = lnw[n], bb = lnb[n];
      #pragma unroll
      for (int i = 0; i < 4; ++i) {
        #pragma unroll
        for (int r = 0; r < 4; ++r) {
          const long mg = m0 + 16 * i + 4 * lq + r;
          outp[mg * BN + n] =
              pack_hl((acc[i][j][r] - mu_l[i][r]) * rs_l[i][r] * g + bb);
        }
      }
    }
  } else {
    const int b = m0 >> 12;
    const int lb = m0 & 4095;
    #pragma unroll
    for (int j = 0; j < NT; ++j) {
      const int n = wn + 16 * j + lm;
      const float g = lnw[n], bb = lnb[n];
      #pragma unroll
      for (int i = 0; i < 4; ++i) {
        const int l = lb + 16 * i + 4 * lq;
        float4 v;
        v.x = (acc[i][j][0] - mu_l[i][0]) * rs_l[i][0] * g + bb;
        v.y = (acc[i][j][1] - mu_l[i][1]) * rs_l[i][1] * g + bb;
        v.z = (acc[i][j][2] - mu_l[i][2]) * rs_l[i][2] * g + bb;
        v.w = (acc[i][j][3] - mu_l[i][3]) * rs_l[i][3] * g + bb;
        *(float4*)(outf + ((long)b * BN + n) * L + l) = v;
      }
    }
  }
}

// ---------------------------------------------------------------------------
// Projection only: causal depthwise conv(4)+silu (into LDS, transposed) ->
// xds[j,l] = sum_ch wx[j][ch]*xc[ch][l] for j < R+4. Rows j<R go to xds_g
// (B,R,L), rows R..R+3 (B,C) go to bc_t. NO bulk xc/dt output — the scan
// kernel recomputes conv+silu and dt on the fly (saves 128 MB round trips).
// ---------------------------------------------------------------------------
template<int DI, int R>
__global__ __launch_bounds__(256) void proj_kernel(
    const float* __restrict__ xcpre_t,
    const float* __restrict__ cw, const float* __restrict__ cb,
    const float* __restrict__ wx,
    float* __restrict__ xds_g, float* __restrict__ bc_t, int L)
{
  constexpr int LT = 16;
  constexpr int NP = R + 4;            // proj rows: R dt-rank + 2 B + 2 C
  constexpr int NC = DI / 4;           // float4 chunks per position row
  __shared__ float xcT[LT][DI];        // [pos][rot-swizzled ch]

  const int tid = threadIdx.x;
  const int l0 = blockIdx.x * LT;
  const int bz = blockIdx.y;

  // ---- phase 1: conv + silu -> transposed/swizzled LDS ----
  if (tid < DI) {
    const int ch = tid;
    const long rowb = ((long)bz * DI + ch) * L;
    const float* __restrict__ src = xcpre_t + rowb + l0;
    float pre[LT + 3];
    if (l0 >= 3) {
      #pragma unroll
      for (int i = 0; i < LT + 3; ++i) pre[i] = src[i - 3];
    } else {
      #pragma unroll
      for (int i = 0; i < LT + 3; ++i) {
        const int l = l0 - 3 + i;
        pre[i] = (l >= 0) ? xcpre_t[rowb + l] : 0.0f;
      }
    }
    const float w0 = cw[ch*4+0], w1 = cw[ch*4+1], w2 = cw[ch*4+2], w3 = cw[ch*4+3];
    const float cbc = cb[ch];
    const int g = ch >> 2, c = ch & 3;
    #pragma unroll
    for (int i = 0; i < LT; ++i) {
      float s = cbc;
      s = fmaf(pre[i+0], w0, s);
      s = fmaf(pre[i+1], w1, s);
      s = fmaf(pre[i+2], w2, s);
      s = fmaf(pre[i+3], w3, s);
      xcT[i][(((g + i) & (NC - 1)) << 2) + c] = silu_f(s);
    }
  }
  __syncthreads();

  // ---- phase 2: out[j][i] = sum_ch wx[j][ch] * xc[ch][i] (float4 dot) ----
  for (int q = tid; q < NP * LT; q += 256) {
    const int j = q >> 4;
    const int i = q & 15;
    const float* __restrict__ wr = wx + (long)j * DI;
    float a0 = 0.0f, a1 = 0.0f, a2 = 0.0f, a3 = 0.0f;
    #pragma unroll 4
    for (int g = 0; g < NC; ++g) {
      const float4 xv = *(const float4*)&xcT[i][((g + i) & (NC - 1)) << 2];
      const float4 wv = *(const float4*)(wr + (g << 2));
      a0 = fmaf(xv.x, wv.x, a0);
      a1 = fmaf(xv.y, wv.y, a1);
      a2 = fmaf(xv.z, wv.z, a2);
      a3 = fmaf(xv.w, wv.w, a3);
    }
    const float val = (a0 + a1) + (a2 + a3);
    if (j < R) xds_g[((long)bz * R + j) * L + l0 + i] = val;
    else       bc_t[((long)bz * 4 + (j - R)) * L + l0 + i] = val;
  }
}

// ---------------------------------------------------------------------------
// Fused selective scan: recomputes conv+silu (from xcpre) and
// dt = softplus(xds @ wdt_row + bdt) on the fly (identical op order ->
// bit-identical), then block-parallel affine scan over L.
// v8: 512 threads x 8 positions (was 256x16) — halves per-thread loads and
// register arrays (a/u = 32 regs) so waves/SIMD rises; v6's chunked t/c/z
// consumption kept (proven best structure).
// ---------------------------------------------------------------------------
template<int R>
__global__ __launch_bounds__(512, 2) void scan_kernel(
    const float* __restrict__ xcpre_t,
    const float* __restrict__ cw, const float* __restrict__ cb,
    const float* __restrict__ xds_g, const float* __restrict__ wdt,
    const float* __restrict__ bdt,
    const float* __restrict__ z_t, const float* __restrict__ bc_t,
    const float* __restrict__ alog, const float* __restrict__ dd,
    float* __restrict__ y_t, int di, int L)
{
  const int ch = blockIdx.x;
  const int bz = blockIdx.y;
  const int tid = threadIdx.x;
  const int lane = tid & 63;
  const int w = tid >> 6;              // 0..7
  const long rowb = ((long)bz * di + ch) * L;
  const long bcb = (long)bz * 4 * L;
  const int l0 = tid * 8;

  __shared__ float wsP0[8], wsQ0[8], wsP1[8], wsQ1[8];

  const float A0 = -__expf(alog[ch * 2 + 0]);
  const float A1 = -__expf(alog[ch * 2 + 1]);
  const float ddc = dd[ch];

  // ---- conv + silu -> xcv (identical op order to proj phase 1) ----
  const float w0 = cw[ch*4+0], w1 = cw[ch*4+1], w2 = cw[ch*4+2], w3 = cw[ch*4+3];
  const float cbc = cb[ch];
  float cur[8];
  load8(cur, xcpre_t + rowb + l0);
  float p0 = 0.0f, p1 = 0.0f, p2 = 0.0f;
  if (tid > 0) {
    const float4 h = *(const float4*)(xcpre_t + rowb + l0 - 4);
    p0 = h.y; p1 = h.z; p2 = h.w;
  }
  float xcv[8];
  {
    float s;
    s = cbc; s = fmaf(p0, w0, s); s = fmaf(p1, w1, s); s = fmaf(p2, w2, s);
    s = fmaf(cur[0], w3, s); xcv[0] = silu_f(s);
    s = cbc; s = fmaf(p1, w0, s); s = fmaf(p2, w1, s); s = fmaf(cur[0], w2, s);
    s = fmaf(cur[1], w3, s); xcv[1] = silu_f(s);
    s = cbc; s = fmaf(p2, w0, s); s = fmaf(cur[0], w1, s); s = fmaf(cur[1], w2, s);
    s = fmaf(cur[2], w3, s); xcv[2] = silu_f(s);
    #pragma unroll
    for (int i = 3; i < 8; ++i) {
      s = cbc;
      s = fmaf(cur[i-3], w0, s);
      s = fmaf(cur[i-2], w1, s);
      s = fmaf(cur[i-1], w2, s);
      s = fmaf(cur[i],   w3, s);
      xcv[i] = silu_f(s);
    }
  }

  // ---- dt pre-activation: sd[i] = bdt + sum_j xds[j][l0+i]*wdt[ch][j] ----
  float wr[R];
  #pragma unroll
  for (int j = 0; j < R; ++j) wr[j] = wdt[ch * R + j];
  const float bv = bdt[ch];
  float sd[8];
  #pragma unroll
  for (int i = 0; i < 8; ++i) sd[i] = bv;
  const float* __restrict__ xp = xds_g + (long)bz * R * L + l0;
  #pragma unroll 2
  for (int j = 0; j < R; ++j) {
    const float wj = wr[j];
    const float4 x0 = *(const float4*)(xp + (long)j * L + 0);
    const float4 x1 = *(const float4*)(xp + (long)j * L + 4);
    sd[0] = fmaf(x0.x, wj, sd[0]); sd[1] = fmaf(x0.y, wj, sd[1]);
    sd[2] = fmaf(x0.z, wj, sd[2]); sd[3] = fmaf(x0.w, wj, sd[3]);
    sd[4] = fmaf(x1.x, wj, sd[4]); sd[5] = fmaf(x1.y, wj, sd[5]);
    sd[6] = fmaf(x1.z, wj, sd[6]); sd[7] = fmaf(x1.w, wj, sd[7]);
  }

  // ---- local scan coefficients (t0/t1 consumed in float4 chunks) ----
  float a0[8], a1[8], u0[8], u1[8];
  float P0 = 1.0f, Q0 = 0.0f, P1 = 1.0f, Q1 = 0.0f;
  #pragma unroll
  for (int c4 = 0; c4 < 2; ++c4) {
    const float4 t0c = *(const float4*)(bc_t + bcb + l0 + c4 * 4);
    const float4 t1c = *(const float4*)(bc_t + bcb + L + l0 + c4 * 4);
    const float t0a[4] = {t0c.x, t0c.y, t0c.z, t0c.w};
    const float t1a[4] = {t1c.x, t1c.y, t1c.z, t1c.w};
    #pragma unroll
    for (int i2 = 0; i2 < 4; ++i2) {
      const int i = c4 * 4 + i2;
      const float dt = softplus_f(sd[i]);
      const float dx = dt * xcv[i];
      a0[i] = __expf(dt * A0);
      a1[i] = __expf(dt * A1);
      u0[i] = dx * t0a[i2];
      u1[i] = dx * t1a[i2];
      Q0 = fmaf(a0[i], Q0, u0[i]); P0 *= a0[i];
      Q1 = fmaf(a1[i], Q1, u1[i]); P1 *= a1[i];
    }
  }

  #pragma unroll
  for (int off = 1; off < 64; off <<= 1) {
    const float pp0 = __shfl_up(P0, off);
    const float qq0 = __shfl_up(Q0, off);
    const float pp1 = __shfl_up(P1, off);
    const float qq1 = __shfl_up(Q1, off);
    if (lane >= off) {
      Q0 = fmaf(P0, qq0, Q0); P0 *= pp0;
      Q1 = fmaf(P1, qq1, Q1); P1 *= pp1;
    }
  }
  if (lane == 63) { wsP0[w] = P0; wsQ0[w] = Q0; wsP1[w] = P1; wsQ1[w] = Q1; }
  __syncthreads();
  float eQ0 = 0.0f, eQ1 = 0.0f;
  for (int ww = 0; ww < w; ++ww) {
    eQ0 = fmaf(wsP0[ww], eQ0, wsQ0[ww]);
    eQ1 = fmaf(wsP1[ww], eQ1, wsQ1[ww]);
  }
  float pP0 = __shfl_up(P0, 1), pQ0 = __shfl_up(Q0, 1);
  float pP1 = __shfl_up(P1, 1), pQ1 = __shfl_up(Q1, 1);
  if (lane == 0) { pP0 = 1.0f; pQ0 = 0.0f; pP1 = 1.0f; pQ1 = 0.0f; }
  float h0 = fmaf(pP0, eQ0, pQ0);
  float h1 = fmaf(pP1, eQ1, pQ1);

  // ---- epilogue: c0/c1/z consumed in float4 chunks, y stored per chunk ----
  #pragma unroll
  for (int c4 = 0; c4 < 2; ++c4) {
    const float4 c0c = *(const float4*)(bc_t + bcb + 2 * L + l0 + c4 * 4);
    const float4 c1c = *(const float4*)(bc_t + bcb + 3 * L + l0 + c4 * 4);
    const float4 zvc = *(const float4*)(z_t + rowb + l0 + c4 * 4);
    const float c0a[4] = {c0c.x, c0c.y, c0c.z, c0c.w};
    const float c1a[4] = {c1c.x, c1c.y, c1c.z, c1c.w};
    const float zva[4] = {zvc.x, zvc.y, zvc.z, zvc.w};
    float yv[4];
    #pragma unroll
    for (int i2 = 0; i2 < 4; ++i2) {
      const int i = c4 * 4 + i2;
      h0 = fmaf(a0[i], h0, u0[i]);
      h1 = fmaf(a1[i], h1, u1[i]);
      const float y = fmaf(h0, c0a[i2], fmaf(h1, c1a[i2], ddc * xcv[i]));
      yv[i2] = y * silu_f(zva[i2]);
    }
    *(float4*)(y_t + rowb + l0 + c4 * 4) = make_float4(yv[0], yv[1], yv[2], yv[3]);
  }
}

// ---------------------------------------------------------------------------
extern "C" void kernel_launch(void* const* d_in, const int* in_sizes, int n_in,
                              void* d_out, int out_size, void* d_ws, size_t ws_size,
                              hipStream_t stream)
{
  const float* x       = (const float*)d_in[0];
  const float* lin_w   = (const float*)d_in[1];
  const float* lin_b   = (const float*)d_in[2];
  const float* s1_win  = (const float*)d_in[3];
  const float* s1_bin  = (const float*)d_in[4];
  const float* s1_cw   = (const float*)d_in[5];
  const float* s1_cb   = (const float*)d_in[6];
  const float* s1_wx   = (const float*)d_in[7];
  const float* s1_wdt  = (const float*)d_in[8];
  const float* s1_bdt  = (const float*)d_in[9];
  const float* s1_alog = (const float*)d_in[10];
  const float* s1_dd   = (const float*)d_in[11];
  const float* s1_wout = (const float*)d_in[12];
  const float* s1_lnw  = (const float*)d_in[13];
  const float* s1_lnb  = (const float*)d_in[14];
  const float* s2_win  = (const float*)d_in[15];
  const float* s2_bin  = (const float*)d_in[16];
  const float* s2_cw   = (const float*)d_in[17];
  const float* s2_cb   = (const float*)d_in[18];
  const float* s2_wx   = (const float*)d_in[19];
  const float* s2_wdt  = (const float*)d_in[20];
  const float* s2_bdt  = (const float*)d_in[21];
  const float* s2_alog = (const float*)d_in[22];
  const float* s2_dd   = (const float*)d_in[23];
  const float* s2_wout = (const float*)d_in[24];
  const float* s2_lnw  = (const float*)d_in[25];
  const float* s2_lnb  = (const float*)d_in[26];
  float* out = (float*)d_out;

  const int B = 8, L = 4096, M = 32768;
  const long SLOT = 8L * 256 * 4096;   // 8388608 elems = 32 MB
  const long HALF = SLOT / 2;          // 16 MB
  float* ws = (float*)d_ws;
  float* S0f = ws;             u32* S0u = (u32*)S0f;
  float* S1f = ws + SLOT;      u32* S1u = (u32*)S1f;
  float* S2f = ws + 2 * SLOT;  u32* S2u = (u32*)S2f;
  float* SBf = ws + 3 * SLOT;                        // (B,4,L) = 131072
  float* XDS = ws + 3 * SLOT + 131072;               // (B,16,L) = 524288
  u32*   WP  = (u32*)(ws + 3 * SLOT + 131072 + 524288);  // packed weights

  // 1. pack weights
  wprep_kernel<<<WTOT / 256, 256, 0, stream>>>(s1_win, s1_wout, lin_w, s2_win, s2_wout, WP);
  // 2. x (b,128,L) -> packed xT (M,128) @ S0u
  tpose_kernel<<<dim3(128, 4, B), 256, 0, stream>>>(x, S0u, 128, L);
  // 3. stage1 in-proj: -> xcpre1 @ S1f, z1 @ S1f+HALF
  mgemm_kernel<0><<<dim3(2, 256), 256, 0, stream>>>(
      S0u, WP + WOFF1, s1_bin, M, 256, 128, S1f, S1f + HALF, nullptr, 128, L);
  // 4. proj1: xcpre1 -> xds @ XDS, B/C @ SBf
  proj_kernel<128, 8><<<dim3(256, B), 256, 0, stream>>>(
      S1f, s1_cw, s1_cb, s1_wx, XDS, SBf, L);
  // 5. fused scan1 (conv+dt recompute) -> y1 @ S0f
  scan_kernel<8><<<dim3(128, B), 512, 0, stream>>>(
      S1f, s1_cw, s1_cb, XDS, s1_wdt, s1_bdt, S1f + HALF, SBf,
      s1_alog, s1_dd, S0f, 128, L);
  // 6. y1 -> packed y1T @ S0u+HALF
  tpose_kernel<<<dim3(128, 4, B), 256, 0, stream>>>(S0f, S0u + HALF, 128, L);
  // 7. out-proj1 + LN -> act_mid packed @ S1u
  lgemm_kernel<128, 2><<<dim3(512), 256, 0, stream>>>(
      S0u + HALF, WP + WOFFO1, s1_lnw, s1_lnb, M, 128, S1u, nullptr, L);
  // 8. mid linear + silu -> act_lin packed @ S2u
  mgemm_kernel<1><<<dim3(2, 256), 256, 0, stream>>>(
      S1u, WP + WOFFL, lin_b, M, 256, 128, nullptr, nullptr, S2u, 0, L);
  // 9. stage2 in-proj: -> xcpre2 @ S0f, z2 @ S1f
  mgemm_kernel<0><<<dim3(4, 256), 256, 0, stream>>>(
      S2u, WP + WOFF2, s2_bin, M, 512, 256, S0f, S1f, nullptr, 256, L);
  // 10. proj2: xcpre2 -> xds @ XDS, B/C @ SBf
  proj_kernel<256, 16><<<dim3(256, B), 256, 0, stream>>>(
      S0f, s2_cw, s2_cb, s2_wx, XDS, SBf, L);
  // 11. fused scan2 -> y2 @ S2f
  scan_kernel<16><<<dim3(256, B), 512, 0, stream>>>(
      S0f, s2_cw, s2_cb, XDS, s2_wdt, s2_bdt, S1f, SBf,
      s2_alog, s2_dd, S2f, 256, L);
  // 12. y2 -> packed y2T @ S1u
  tpose_kernel<<<dim3(128, 8, B), 256, 0, stream>>>(S2f, S1u, 256, L);
  // 13. out-proj2 + LN -> d_out fp32 (b,256,64,64)
  lgemm_kernel<256, 3><<<dim3(512), 256, 0, stream>>>(
      S1u, WP + WOFFO2, s2_lnw, s2_lnb, M, 256, nullptr, out, L);
}